// Round 8
// baseline (2017.420 us; speedup 1.0000x reference)
//
#include <hip/hip_runtime.h>
#include <math.h>

#define NB 32
#define L  1024
#define CH 256                 // timesteps per chunk
#define NCH (L / CH)           // 4 chunks
#define RC (NB * CH)           // 8192 rows per chunk
#define DM 256
#define DI 512
#define DS 16
#define SCT 16                 // sub-chunk timesteps (scan)
#define NSC (CH / SCT)         // 16 sub-chunks
#define LOG2E 1.44269504f

typedef short short8 __attribute__((ext_vector_type(8)));
typedef float f32x4 __attribute__((ext_vector_type(4)));

// bf16 split helpers: x ~= hi + lo, both bf16 (rne). pair = hi | (lo<<16).
__device__ inline unsigned f2bf_u(float x) {
    unsigned u = __float_as_uint(x);
    return (u + 0x7fffu + ((u >> 16) & 1u)) >> 16;
}
__device__ inline unsigned packpair(float v) {
    unsigned h = f2bf_u(v);
    float hf = __uint_as_float(h << 16);
    unsigned l = f2bf_u(v - hf);
    return h | (l << 16);
}

// Layout: per-chunk activations use (t_local, b, feat): row r = t_local*32 + b.

// ---------------------------------------------------------------------------
// p1 (K=4) + bias + LayerNorm; emits bf16 hi/lo pairs for the MFMA in_proj.
// ---------------------------------------------------------------------------
__global__ __launch_bounds__(256) void k_p1_ln(
    const float* __restrict__ xseq, const float* __restrict__ w,
    const float* __restrict__ bias, const float* __restrict__ g,
    const float* __restrict__ bb, unsigned* __restrict__ out, int t0)
{
    int r  = blockIdx.x;
    int b  = r & 31;
    int tl = r >> 5;
    int m  = threadIdx.x;
    const float* xr = xseq + ((size_t)b * L + t0 + tl) * 4;
    float x0 = xr[0], x1 = xr[1], x2 = xr[2], x3 = xr[3];
    const float* wr = w + m * 4;
    float v = bias[m] + x0 * wr[0] + x1 * wr[1] + x2 * wr[2] + x3 * wr[3];

    __shared__ float s1[4], s2[4];
    float a = v, bq = v * v;
    for (int o = 32; o > 0; o >>= 1) { a += __shfl_down(a, o); bq += __shfl_down(bq, o); }
    int wid = m >> 6, lane = m & 63;
    if (lane == 0) { s1[wid] = a; s2[wid] = bq; }
    __syncthreads();
    if (m == 0) {
        s1[0] = s1[0] + s1[1] + s1[2] + s1[3];
        s2[0] = s2[0] + s2[1] + s2[2] + s2[3];
    }
    __syncthreads();
    float mu  = s1[0] * (1.f / 256.f);
    float var = s2[0] * (1.f / 256.f) - mu * mu;
    float o2 = (v - mu) * rsqrtf(var + 1e-5f) * g[m] + bb[m];
    out[(size_t)r * 256 + m] = packpair(o2);
}

// ---------------------------------------------------------------------------
// LayerNorm over 256; fp32 in, bf16-pair out.
// ---------------------------------------------------------------------------
__global__ __launch_bounds__(256) void k_ln(
    const float* __restrict__ in, const float* __restrict__ g,
    const float* __restrict__ bb, unsigned* __restrict__ out)
{
    int r = blockIdx.x;
    int m = threadIdx.x;
    float v = in[(size_t)r * 256 + m];

    __shared__ float s1[4], s2[4];
    float a = v, bq = v * v;
    for (int o = 32; o > 0; o >>= 1) { a += __shfl_down(a, o); bq += __shfl_down(bq, o); }
    int wid = m >> 6, lane = m & 63;
    if (lane == 0) { s1[wid] = a; s2[wid] = bq; }
    __syncthreads();
    if (m == 0) {
        s1[0] = s1[0] + s1[1] + s1[2] + s1[3];
        s2[0] = s2[0] + s2[1] + s2[2] + s2[3];
    }
    __syncthreads();
    float mu  = s1[0] * (1.f / 256.f);
    float var = s2[0] * (1.f / 256.f) - mu * mu;
    float o2 = (v - mu) * rsqrtf(var + 1e-5f) * g[m] + bb[m];
    out[(size_t)r * 256 + m] = packpair(o2);
}

__global__ __launch_bounds__(256) void k_wcvt(
    const float* __restrict__ w, unsigned* __restrict__ o, int n)
{
    int i = blockIdx.x * 256 + threadIdx.x;
    if (i < n) o[i] = packpair(w[i]);
}

// ---------------------------------------------------------------------------
// split-bf16 MFMA GEMM (3-term): C[M,N] = A[M,K]*W[N,K]^T (+bias).
// 128x128 tile, BK=32, 4 waves x 64x64 quadrant of 4x4 16x16x32 frags.
// ---------------------------------------------------------------------------
template <int OUTK, bool BIAS>
__global__ __launch_bounds__(256) void k_gmfma(
    const unsigned* __restrict__ Ap, int lda,
    const unsigned* __restrict__ Wp,
    const float* __restrict__ bias, void* __restrict__ Cv,
    int N, int K)
{
    __shared__ unsigned short Ah[128 * 40], Al[128 * 40];
    __shared__ unsigned short Wh[128 * 40], Wl[128 * 40];

    int tid = threadIdx.x;
    int wv = tid >> 6, ln = tid & 63;
    int wr = wv >> 1, wc = wv & 1;
    int m0 = blockIdx.x * 128, n0 = blockIdx.y * 128;
    int sr = tid >> 1, sk = (tid & 1) << 4;
    int frow = ln & 15, fk = (ln >> 4) << 3;

    f32x4 acc[4][4] = {};

    for (int k0 = 0; k0 < K; k0 += 32) {
        const unsigned* ap = Ap + (size_t)(m0 + sr) * lda + k0 + sk;
        const unsigned* wp = Wp + (size_t)(n0 + sr) * K + k0 + sk;
        uint4 qa[4], qw[4];
#pragma unroll
        for (int i = 0; i < 4; i++) qa[i] = *(const uint4*)(ap + i * 4);
#pragma unroll
        for (int i = 0; i < 4; i++) qw[i] = *(const uint4*)(wp + i * 4);

        __syncthreads();

        unsigned short th[16], tl[16];
#pragma unroll
        for (int i = 0; i < 4; i++) {
            th[i*4+0] = (unsigned short)qa[i].x; tl[i*4+0] = (unsigned short)(qa[i].x >> 16);
            th[i*4+1] = (unsigned short)qa[i].y; tl[i*4+1] = (unsigned short)(qa[i].y >> 16);
            th[i*4+2] = (unsigned short)qa[i].z; tl[i*4+2] = (unsigned short)(qa[i].z >> 16);
            th[i*4+3] = (unsigned short)qa[i].w; tl[i*4+3] = (unsigned short)(qa[i].w >> 16);
        }
        *(short8*)&Ah[sr * 40 + sk]     = *(short8*)&th[0];
        *(short8*)&Ah[sr * 40 + sk + 8] = *(short8*)&th[8];
        *(short8*)&Al[sr * 40 + sk]     = *(short8*)&tl[0];
        *(short8*)&Al[sr * 40 + sk + 8] = *(short8*)&tl[8];
#pragma unroll
        for (int i = 0; i < 4; i++) {
            th[i*4+0] = (unsigned short)qw[i].x; tl[i*4+0] = (unsigned short)(qw[i].x >> 16);
            th[i*4+1] = (unsigned short)qw[i].y; tl[i*4+1] = (unsigned short)(qw[i].y >> 16);
            th[i*4+2] = (unsigned short)qw[i].z; tl[i*4+2] = (unsigned short)(qw[i].z >> 16);
            th[i*4+3] = (unsigned short)qw[i].w; tl[i*4+3] = (unsigned short)(qw[i].w >> 16);
        }
        *(short8*)&Wh[sr * 40 + sk]     = *(short8*)&th[0];
        *(short8*)&Wh[sr * 40 + sk + 8] = *(short8*)&th[8];
        *(short8*)&Wl[sr * 40 + sk]     = *(short8*)&tl[0];
        *(short8*)&Wl[sr * 40 + sk + 8] = *(short8*)&tl[8];

        __syncthreads();

        short8 afh[4], afl[4], wfh[4], wfl[4];
#pragma unroll
        for (int g = 0; g < 4; g++) {
            int ra = (wr * 64 + g * 16 + frow) * 40 + fk;
            int rw = (wc * 64 + g * 16 + frow) * 40 + fk;
            afh[g] = *(const short8*)&Ah[ra];
            afl[g] = *(const short8*)&Al[ra];
            wfh[g] = *(const short8*)&Wh[rw];
            wfl[g] = *(const short8*)&Wl[rw];
        }
#pragma unroll
        for (int mg = 0; mg < 4; mg++)
#pragma unroll
            for (int ng = 0; ng < 4; ng++) {
                acc[mg][ng] = __builtin_amdgcn_mfma_f32_16x16x32_bf16(afh[mg], wfh[ng], acc[mg][ng], 0, 0, 0);
                acc[mg][ng] = __builtin_amdgcn_mfma_f32_16x16x32_bf16(afh[mg], wfl[ng], acc[mg][ng], 0, 0, 0);
                acc[mg][ng] = __builtin_amdgcn_mfma_f32_16x16x32_bf16(afl[mg], wfh[ng], acc[mg][ng], 0, 0, 0);
            }
    }

    // C layout: col=lane&15, row=(lane>>4)*4+reg  [verified m89]
#pragma unroll
    for (int ng = 0; ng < 4; ng++) {
        int col = n0 + wc * 64 + ng * 16 + frow;
        float bv = BIAS ? bias[col] : 0.f;
#pragma unroll
        for (int mg = 0; mg < 4; mg++)
#pragma unroll
            for (int r = 0; r < 4; r++) {
                int row = m0 + wr * 64 + mg * 16 + (ln >> 4) * 4 + r;
                float v = acc[mg][ng][r] + bv;
                if (OUTK == 0) ((float*)Cv)[(size_t)row * N + col] = v;
                else           ((unsigned*)Cv)[(size_t)row * N + col] = packpair(v);
            }
    }
}

// ---------------------------------------------------------------------------
// xproj: dbc[RC,48] = xc[RC,512] @ xpw[48,512]^T.
// BM=16 rows/block -> 512 blocks. A staged in LDS (pitch 516 vs 512 to
// spread rows across banks). 3 outputs/thread, full-K fp32 dot; W from L2.
// ---------------------------------------------------------------------------
__global__ __launch_bounds__(256) void k_xproj(
    const float* __restrict__ xc, const float* __restrict__ xpw,
    float* __restrict__ dbc)
{
    __shared__ float As[16 * 516];
    int blk = blockIdx.x;
    int tid = threadIdx.x;
    const float* src = xc + (size_t)blk * 16 * 512;
#pragma unroll
    for (int e = 0; e < 8; e++) {
        int idx = e * 1024 + tid * 4;
        int row = idx >> 9, col = idx & 511;
        float4 v = *(const float4*)(src + idx);
        *(float4*)&As[row * 516 + col] = v;
    }
    __syncthreads();
#pragma unroll
    for (int e = 0; e < 3; e++) {
        int o = e * 256 + tid;
        int row = o / 48, col = o - row * 48;
        const float* wrow = xpw + (size_t)col * 512;
        const float* ar = &As[row * 516];
        float acc = 0.f;
#pragma unroll 8
        for (int k = 0; k < 512; k += 4) {
            float4 wv = *(const float4*)(wrow + k);
            float4 av = *(const float4*)(ar + k);
            acc = fmaf(wv.x, av.x, acc);
            acc = fmaf(wv.y, av.y, acc);
            acc = fmaf(wv.z, av.z, acc);
            acc = fmaf(wv.w, av.w, acc);
        }
        dbc[(size_t)blk * 16 * 48 + o] = acc;
    }
}

// ---------------------------------------------------------------------------
// depthwise causal conv1d (k=4) + SiLU, chunked with halo [3][32][512].
// ---------------------------------------------------------------------------
__global__ __launch_bounds__(256) void k_conv(
    const float* __restrict__ xz, const float* __restrict__ halo,
    const float* __restrict__ cw, const float* __restrict__ cb,
    float* __restrict__ xc, int t0)
{
    size_t idx = (size_t)blockIdx.x * 256 + threadIdx.x;   // over RC*512
    int d  = (int)(idx & (DI - 1));
    int r  = (int)(idx >> 9);
    int b  = r & 31;
    int tl = r >> 5;

    float4 wv = *(const float4*)(cw + d * 4);
    float wk[4] = { wv.x, wv.y, wv.z, wv.w };
    float acc = cb[d];

    if (tl >= 3) {
        const float* base = xz + ((size_t)(tl - 3) * 32 + b) * 1024 + d;
#pragma unroll
        for (int k = 0; k < 4; k++) acc = fmaf(wk[k], base[(size_t)k * 32 * 1024], acc);
    } else {
#pragma unroll
        for (int k = 0; k < 4; k++) {
            int ts = t0 + tl - 3 + k;
            float v;
            if (ts < 0) continue;
            else if (ts >= t0) v = xz[((size_t)(tl - 3 + k) * 32 + b) * 1024 + d];
            else v = halo[((size_t)(tl - 3 + k + 3) * 32 + b) * 512 + d];
            acc = fmaf(wk[k], v, acc);
        }
    }
    xc[idx] = acc / (1.f + __expf(-acc));      // silu
}

__global__ __launch_bounds__(256) void k_halo(
    const float* __restrict__ xz, float* __restrict__ halo)
{
    int idx = blockIdx.x * 256 + threadIdx.x;  // over 3*32*512
    int d = idx & 511;
    int b = (idx >> 9) & 31;
    int s = idx >> 14;
    halo[idx] = xz[(((size_t)(CH - 3 + s) * 32 + b) << 10) + d];
}

// ---------------------------------------------------------------------------
// scan pass A (fused dt-proj): local scan per sub-chunk (h=0).
// dt = softplus(dtb[d] + dbc[r,0:16].dtw[d,:]) computed inline.
// Writes ONLY hend + sumdt. grid: 32*2*16 = 1024 blocks.
// ---------------------------------------------------------------------------
__global__ __launch_bounds__(256) void k_scanA(
    const float* __restrict__ xc, const float* __restrict__ dbc,
    const float* __restrict__ dtw, const float* __restrict__ dtb,
    const float* __restrict__ A_log,
    float* __restrict__ hend, float* __restrict__ sumdt)
{
    int bx = blockIdx.x;
    int b    = bx >> 5;
    int half = (bx >> 4) & 1;
    int c    = bx & 15;
    int d = (half << 8) + threadIdx.x;

    float A2[DS], h[DS], wdt[DS];
#pragma unroll
    for (int s = 0; s < DS; s++) {
        A2[s] = -__expf(A_log[d * DS + s]) * LOG2E;
        h[s] = 0.f;
        wdt[s] = dtw[d * DS + s];
    }
    float dtbv = dtb[d];

    __shared__ float Bs[SCT][48];
    for (int f = threadIdx.x; f < SCT * 48; f += 256) {
        int tt = f / 48, jj = f - tt * 48;
        Bs[tt][jj] = dbc[((size_t)(c * SCT + tt) * 32 + b) * 48 + jj];
    }
    __syncthreads();

    float cum = 0.f;
    for (int tt = 0; tt < SCT; tt++) {
        size_t idx = ((size_t)(c * SCT + tt) * 32 + b) * DI + d;
        float s0 = dtbv;
#pragma unroll
        for (int k = 0; k < DS; k++) s0 = fmaf(Bs[tt][k], wdt[k], s0);
        float dt = (s0 > 20.f) ? s0 : log1pf(expf(s0));
        cum += dt;
        float dtx = dt * xc[idx];
#pragma unroll
        for (int s = 0; s < DS; s++) {
            float dA = exp2f(dt * A2[s]);
            h[s] = fmaf(dA, h[s], dtx * Bs[tt][16 + s]);
        }
    }
    float* hp = hend + ((size_t)(c * 32 + b) * 512 + d) * DS;
#pragma unroll
    for (int s = 0; s < DS; s++) hp[s] = h[s];
    sumdt[((size_t)c * 32 + b) * 512 + d] = cum;
}

// ---------------------------------------------------------------------------
// scan pass B: carry across 16 sub-chunks; hend -> h_init, carry -> hs.
// ---------------------------------------------------------------------------
__global__ __launch_bounds__(256) void k_scanB(
    const float* __restrict__ sumdt, float* __restrict__ hend,
    const float* __restrict__ A_log, float* __restrict__ hs, int first)
{
    int id = blockIdx.x * 256 + threadIdx.x;   // 32*512*16 = 262144
    int s = id & 15;
    int d = (id >> 4) & 511;
    int b = id >> 13;
    float A2 = -__expf(A_log[d * DS + s]) * LOG2E;
    size_t hsi = ((size_t)(b << 9) + d) * DS + s;
    float hin = first ? 0.f : hs[hsi];
    for (int c = 0; c < NSC; c++) {
        size_t hi = ((size_t)(c * 32 + b) * 512 + d) * DS + s;
        float he = hend[hi];
        float sd = sumdt[((size_t)c * 32 + b) * 512 + d];
        hend[hi] = hin;
        hin = fmaf(exp2f(A2 * sd), hin, he);
    }
    hs[hsi] = hin;
}

// ---------------------------------------------------------------------------
// scan pass C (fused dt-proj): rescan seeded with h_init, y inline, epilogue
// (y+x*D)*silu(z) -> bf16 pair in-place over xz's xi slot. grid 1024.
// ---------------------------------------------------------------------------
__global__ __launch_bounds__(256) void k_scanC(
    const float* __restrict__ xc, const float* __restrict__ dbc,
    const float* __restrict__ dtw, const float* __restrict__ dtb,
    float* __restrict__ xz,
    const float* __restrict__ A_log, const float* __restrict__ Dp,
    const float* __restrict__ hinit)
{
    int bx = blockIdx.x;
    int b    = bx >> 5;
    int half = (bx >> 4) & 1;
    int c    = bx & 15;
    int d = (half << 8) + threadIdx.x;

    float A2[DS], h[DS], wdt[DS];
    const float* hp = hinit + ((size_t)(c * 32 + b) * 512 + d) * DS;
#pragma unroll
    for (int s = 0; s < DS; s++) {
        A2[s] = -__expf(A_log[d * DS + s]) * LOG2E;
        h[s] = hp[s];
        wdt[s] = dtw[d * DS + s];
    }
    float dtbv = dtb[d];
    float Dv = Dp[d];

    __shared__ float BC[SCT][48];
    for (int f = threadIdx.x; f < SCT * 48; f += 256) {
        int tt = f / 48, jj = f - tt * 48;
        BC[tt][jj] = dbc[((size_t)(c * SCT + tt) * 32 + b) * 48 + jj];
    }
    __syncthreads();

    for (int tt = 0; tt < SCT; tt++) {
        size_t row = (size_t)(c * SCT + tt) * 32 + b;
        size_t idx = row * DI + d;
        float s0 = dtbv;
#pragma unroll
        for (int k = 0; k < DS; k++) s0 = fmaf(BC[tt][k], wdt[k], s0);
        float dt = (s0 > 20.f) ? s0 : log1pf(expf(s0));
        float x  = xc[idx];
        float z  = xz[(row << 10) + 512 + d];
        float dtx = dt * x;
        float y = 0.f;
#pragma unroll
        for (int s = 0; s < DS; s++) {
            float dA = exp2f(dt * A2[s]);
            h[s] = fmaf(dA, h[s], dtx * BC[tt][16 + s]);
            y = fmaf(h[s], BC[tt][32 + s], y);
        }
        float yact = (y + x * Dv) * (z / (1.f + __expf(-z)));
        ((unsigned*)xz)[(row << 10) + d] = packpair(yact);
    }
}

// ---------------------------------------------------------------------------
// mean accumulate / head
// ---------------------------------------------------------------------------
__global__ __launch_bounds__(256) void k_meanacc(
    const float* __restrict__ mo, float* __restrict__ meanacc, int first)
{
    int b = blockIdx.x;
    int m = threadIdx.x;
    float s = 0.f;
    for (int tl = 0; tl < CH; tl++)
        s += mo[((size_t)tl * 32 + b) * 256 + m];
    if (first) meanacc[b * 256 + m] = s;
    else       meanacc[b * 256 + m] += s;
}

__global__ __launch_bounds__(128) void k_head(
    const float* __restrict__ meanacc, const float* __restrict__ xst,
    const float* __restrict__ h1w, const float* __restrict__ h1b,
    const float* __restrict__ h2w, const float* __restrict__ h2b,
    float* __restrict__ out)
{
    int b = blockIdx.x;
    int j = threadIdx.x;
    const float* wr = h1w + j * 261;
    const float* mr = meanacc + b * 256;
    float s = h1b[j];
    for (int k = 0; k < 256; k++) s = fmaf(mr[k] * (1.f / 1024.f), wr[k], s);
    for (int k = 0; k < 5; k++) s = fmaf(xst[b * 5 + k], wr[256 + k], s);
    float e = (s > 0.f) ? s : expm1f(s);

    __shared__ float sb[128];
    sb[j] = e * h2w[j];
    __syncthreads();
    for (int o = 64; o > 0; o >>= 1) {
        if (j < o) sb[j] += sb[j + o];
        __syncthreads();
    }
    if (j == 0) out[b] = sb[0] + h2b[0];
}

// ---------------------------------------------------------------------------
// host side
// ---------------------------------------------------------------------------
static void run_mamba_chunk(hipStream_t stream, const unsigned* xinp, void* const* P,
                            const unsigned* winp, const unsigned* woutp, int out_pairs,
                            float* xzc, float* xcc, float* dbcc,
                            float* moc, float* hendb, float* sumdtb, float* halo,
                            float* hstate, int t0)
{
    const float* cw     = (const float*)P[1];
    const float* cb     = (const float*)P[2];
    const float* xpw    = (const float*)P[3];
    const float* dtw    = (const float*)P[4];
    const float* dtbias = (const float*)P[5];
    const float* Alog   = (const float*)P[6];
    const float* Dp     = (const float*)P[7];
    int first = (t0 == 0);

    k_gmfma<0, false><<<dim3(RC / 128, 1024 / 128), 256, 0, stream>>>(
        xinp, 256, winp, nullptr, xzc, 1024, 256);
    k_conv<<<RC * DI / 256, 256, 0, stream>>>(xzc, halo, cw, cb, xcc, t0);
    k_halo<<<3 * 32 * 512 / 256, 256, 0, stream>>>(xzc, halo);
    k_xproj<<<RC / 16, 256, 0, stream>>>(xcc, xpw, dbcc);
    k_scanA<<<32 * 2 * NSC, 256, 0, stream>>>(xcc, dbcc, dtw, dtbias, Alog,
                                              hendb, sumdtb);
    k_scanB<<<32 * 512 * DS / 256, 256, 0, stream>>>(sumdtb, hendb, Alog, hstate, first);
    k_scanC<<<32 * 2 * NSC, 256, 0, stream>>>(xcc, dbcc, dtw, dtbias, xzc,
                                              Alog, Dp, hendb);
    if (out_pairs)
        k_gmfma<1, false><<<dim3(RC / 128, 256 / 128), 256, 0, stream>>>(
            (const unsigned*)xzc, 1024, woutp, nullptr, moc, 256, 512);
    else
        k_gmfma<0, false><<<dim3(RC / 128, 256 / 128), 256, 0, stream>>>(
            (const unsigned*)xzc, 1024, woutp, nullptr, moc, 256, 512);
}

extern "C" void kernel_launch(void* const* d_in, const int* in_sizes, int n_in,
                              void* d_out, int out_size, void* d_ws, size_t ws_size,
                              hipStream_t stream)
{
    const float* xseq = (const float*)d_in[0];
    const float* xst  = (const float*)d_in[1];
    const float* p1w  = (const float*)d_in[2];
    const float* p1b  = (const float*)d_in[3];
    const float* ln1g = (const float*)d_in[4];
    const float* ln1b = (const float*)d_in[5];
    const float* p2w  = (const float*)d_in[6];
    const float* p2b  = (const float*)d_in[7];
    const float* ln2g = (const float*)d_in[8];
    const float* ln2b = (const float*)d_in[9];
    const float* h1w  = (const float*)d_in[10];
    const float* h1b  = (const float*)d_in[11];
    const float* h2w  = (const float*)d_in[12];
    const float* h2b  = (const float*)d_in[13];

    float* ws = (float*)d_ws;
    float*    xzc    = ws;                                  // RC*1024 f32
    float*    xcc    = xzc  + (size_t)RC * 1024;            // RC*512
    float*    dbcc   = xcc  + (size_t)RC * 512;             // RC*48
    float*    moc    = dbcc + (size_t)RC * 48;              // RC*256
    unsigned* x1p    = (unsigned*)(moc + (size_t)RC * 256); // RC*256 pairs
    // hend aliases moc∪x1p (4.19M floats) — both dead during scan phase
    float*    hendb  = moc;                                 // NSC*32*512*DS
    float*    sumdtb = (float*)(x1p + (size_t)RC * 256);    // NSC*32*512
    float*    halo1  = sumdtb + NSC * 32 * 512;             // 3*32*512
    float*    halo2  = halo1 + 3 * 32 * 512;
    float*    hs1    = halo2 + 3 * 32 * 512;                // 32*512*16
    float*    hs2    = hs1  + 32 * 512 * DS;
    float*    macc   = hs2  + 32 * 512 * DS;                // 32*256
    unsigned* wm1i   = (unsigned*)(macc + 32 * 256);        // 1024*256
    unsigned* wm1o   = wm1i + 262144;                       // 256*512
    unsigned* wm2i   = wm1o + 131072;
    unsigned* wm2o   = wm2i + 262144;
    unsigned* wp2    = wm2o + 131072;                       // 256*256
    size_t need = (size_t)((float*)(wp2 + 65536) - ws) * sizeof(float);
    if (ws_size < need) return;   // tripwire: fail cleanly, don't fault

    // weight bf16-pair conversion (once per launch)
    k_wcvt<<<262144 / 256, 256, 0, stream>>>((const float*)d_in[14], wm1i, 262144);
    k_wcvt<<<131072 / 256, 256, 0, stream>>>((const float*)d_in[22], wm1o, 131072);
    k_wcvt<<<262144 / 256, 256, 0, stream>>>((const float*)d_in[23], wm2i, 262144);
    k_wcvt<<<131072 / 256, 256, 0, stream>>>((const float*)d_in[31], wm2o, 131072);
    k_wcvt<<<65536 / 256, 256, 0, stream>>>(p2w, wp2, 65536);

    for (int c = 0; c < NCH; c++) {
        int t0 = c * CH;
        int first = (c == 0);

        k_p1_ln<<<RC, 256, 0, stream>>>(xseq, p1w, p1b, ln1g, ln1b, x1p, t0);

        // mamba 1 (params d_in[14..22]); out_proj emits pairs for p2
        run_mamba_chunk(stream, x1p, d_in + 14, wm1i, wm1o, 1,
                        xzc, xcc, dbcc, moc, hendb, sumdtb, halo1, hs1, t0);

        // p2 + LN2
        k_gmfma<0, true><<<dim3(RC / 128, 256 / 128), 256, 0, stream>>>(
            (const unsigned*)moc, 256, wp2, p2b, xzc, 256, 256);
        k_ln<<<RC, 256, 0, stream>>>(xzc, ln2g, ln2b, x1p);

        // mamba 2 (params d_in[23..31]); out_proj emits f32 for meanacc
        run_mamba_chunk(stream, x1p, d_in + 23, wm2i, wm2o, 0,
                        xzc, xcc, dbcc, moc, hendb, sumdtb, halo2, hs2, t0);

        k_meanacc<<<NB, 256, 0, stream>>>(moc, macc, first);
    }

    k_head<<<NB, 128, 0, stream>>>(macc, xst, h1w, h1b, h2w, h2b, (float*)d_out);
}

// Round 9
// 1574.879 us; speedup vs baseline: 1.2810x; 1.2810x over previous
//
#include <hip/hip_runtime.h>
#include <math.h>

#define NB 32
#define L  1024
#define CH 256                 // timesteps per chunk
#define NCH (L / CH)           // 4 chunks
#define RC (NB * CH)           // 8192 rows per chunk
#define DM 256
#define DI 512
#define DS 16
#define SCT 16                 // sub-chunk timesteps (scan)
#define NSC (CH / SCT)         // 16 sub-chunks
#define LOG2E 1.44269504f

typedef short short8 __attribute__((ext_vector_type(8)));
typedef float f32x4 __attribute__((ext_vector_type(4)));

// bf16 split helpers: x ~= hi + lo, both bf16 (rne). pair = hi | (lo<<16).
__device__ inline unsigned f2bf_u(float x) {
    unsigned u = __float_as_uint(x);
    return (u + 0x7fffu + ((u >> 16) & 1u)) >> 16;
}
__device__ inline unsigned packpair(float v) {
    unsigned h = f2bf_u(v);
    float hf = __uint_as_float(h << 16);
    unsigned l = f2bf_u(v - hf);
    return h | (l << 16);
}

// Layout: per-chunk activations use (t_local, b, feat): row r = t_local*32 + b.

// ---------------------------------------------------------------------------
// p1 (K=4) + bias + LayerNorm; emits bf16 hi/lo pairs for the MFMA in_proj.
// ---------------------------------------------------------------------------
__global__ __launch_bounds__(256) void k_p1_ln(
    const float* __restrict__ xseq, const float* __restrict__ w,
    const float* __restrict__ bias, const float* __restrict__ g,
    const float* __restrict__ bb, unsigned* __restrict__ out, int t0)
{
    int r  = blockIdx.x;
    int b  = r & 31;
    int tl = r >> 5;
    int m  = threadIdx.x;
    const float* xr = xseq + ((size_t)b * L + t0 + tl) * 4;
    float x0 = xr[0], x1 = xr[1], x2 = xr[2], x3 = xr[3];
    const float* wr = w + m * 4;
    float v = bias[m] + x0 * wr[0] + x1 * wr[1] + x2 * wr[2] + x3 * wr[3];

    __shared__ float s1[4], s2[4];
    float a = v, bq = v * v;
    for (int o = 32; o > 0; o >>= 1) { a += __shfl_down(a, o); bq += __shfl_down(bq, o); }
    int wid = m >> 6, lane = m & 63;
    if (lane == 0) { s1[wid] = a; s2[wid] = bq; }
    __syncthreads();
    if (m == 0) {
        s1[0] = s1[0] + s1[1] + s1[2] + s1[3];
        s2[0] = s2[0] + s2[1] + s2[2] + s2[3];
    }
    __syncthreads();
    float mu  = s1[0] * (1.f / 256.f);
    float var = s2[0] * (1.f / 256.f) - mu * mu;
    float o2 = (v - mu) * rsqrtf(var + 1e-5f) * g[m] + bb[m];
    out[(size_t)r * 256 + m] = packpair(o2);
}

// ---------------------------------------------------------------------------
// LayerNorm over 256; fp32 in, bf16-pair out.
// ---------------------------------------------------------------------------
__global__ __launch_bounds__(256) void k_ln(
    const float* __restrict__ in, const float* __restrict__ g,
    const float* __restrict__ bb, unsigned* __restrict__ out)
{
    int r = blockIdx.x;
    int m = threadIdx.x;
    float v = in[(size_t)r * 256 + m];

    __shared__ float s1[4], s2[4];
    float a = v, bq = v * v;
    for (int o = 32; o > 0; o >>= 1) { a += __shfl_down(a, o); bq += __shfl_down(bq, o); }
    int wid = m >> 6, lane = m & 63;
    if (lane == 0) { s1[wid] = a; s2[wid] = bq; }
    __syncthreads();
    if (m == 0) {
        s1[0] = s1[0] + s1[1] + s1[2] + s1[3];
        s2[0] = s2[0] + s2[1] + s2[2] + s2[3];
    }
    __syncthreads();
    float mu  = s1[0] * (1.f / 256.f);
    float var = s2[0] * (1.f / 256.f) - mu * mu;
    float o2 = (v - mu) * rsqrtf(var + 1e-5f) * g[m] + bb[m];
    out[(size_t)r * 256 + m] = packpair(o2);
}

__global__ __launch_bounds__(256) void k_wcvt(
    const float* __restrict__ w, unsigned* __restrict__ o, int n)
{
    int i = blockIdx.x * 256 + threadIdx.x;
    if (i < n) o[i] = packpair(w[i]);
}

// ---------------------------------------------------------------------------
// split-bf16 MFMA GEMM (3-term): C[M,N] = A[M,K]*W[N,K]^T (+bias).
// 128x128 tile, BK=32, 4 waves x 64x64 quadrant of 4x4 16x16x32 frags.
// ---------------------------------------------------------------------------
template <int OUTK, bool BIAS>
__global__ __launch_bounds__(256) void k_gmfma(
    const unsigned* __restrict__ Ap, int lda,
    const unsigned* __restrict__ Wp,
    const float* __restrict__ bias, void* __restrict__ Cv,
    int N, int K)
{
    __shared__ unsigned short Ah[128 * 40], Al[128 * 40];
    __shared__ unsigned short Wh[128 * 40], Wl[128 * 40];

    int tid = threadIdx.x;
    int wv = tid >> 6, ln = tid & 63;
    int wr = wv >> 1, wc = wv & 1;
    int m0 = blockIdx.x * 128, n0 = blockIdx.y * 128;
    int sr = tid >> 1, sk = (tid & 1) << 4;
    int frow = ln & 15, fk = (ln >> 4) << 3;

    f32x4 acc[4][4] = {};

    for (int k0 = 0; k0 < K; k0 += 32) {
        const unsigned* ap = Ap + (size_t)(m0 + sr) * lda + k0 + sk;
        const unsigned* wp = Wp + (size_t)(n0 + sr) * K + k0 + sk;
        uint4 qa[4], qw[4];
#pragma unroll
        for (int i = 0; i < 4; i++) qa[i] = *(const uint4*)(ap + i * 4);
#pragma unroll
        for (int i = 0; i < 4; i++) qw[i] = *(const uint4*)(wp + i * 4);

        __syncthreads();

        unsigned short th[16], tl[16];
#pragma unroll
        for (int i = 0; i < 4; i++) {
            th[i*4+0] = (unsigned short)qa[i].x; tl[i*4+0] = (unsigned short)(qa[i].x >> 16);
            th[i*4+1] = (unsigned short)qa[i].y; tl[i*4+1] = (unsigned short)(qa[i].y >> 16);
            th[i*4+2] = (unsigned short)qa[i].z; tl[i*4+2] = (unsigned short)(qa[i].z >> 16);
            th[i*4+3] = (unsigned short)qa[i].w; tl[i*4+3] = (unsigned short)(qa[i].w >> 16);
        }
        *(short8*)&Ah[sr * 40 + sk]     = *(short8*)&th[0];
        *(short8*)&Ah[sr * 40 + sk + 8] = *(short8*)&th[8];
        *(short8*)&Al[sr * 40 + sk]     = *(short8*)&tl[0];
        *(short8*)&Al[sr * 40 + sk + 8] = *(short8*)&tl[8];
#pragma unroll
        for (int i = 0; i < 4; i++) {
            th[i*4+0] = (unsigned short)qw[i].x; tl[i*4+0] = (unsigned short)(qw[i].x >> 16);
            th[i*4+1] = (unsigned short)qw[i].y; tl[i*4+1] = (unsigned short)(qw[i].y >> 16);
            th[i*4+2] = (unsigned short)qw[i].z; tl[i*4+2] = (unsigned short)(qw[i].z >> 16);
            th[i*4+3] = (unsigned short)qw[i].w; tl[i*4+3] = (unsigned short)(qw[i].w >> 16);
        }
        *(short8*)&Wh[sr * 40 + sk]     = *(short8*)&th[0];
        *(short8*)&Wh[sr * 40 + sk + 8] = *(short8*)&th[8];
        *(short8*)&Wl[sr * 40 + sk]     = *(short8*)&tl[0];
        *(short8*)&Wl[sr * 40 + sk + 8] = *(short8*)&tl[8];

        __syncthreads();

        short8 afh[4], afl[4], wfh[4], wfl[4];
#pragma unroll
        for (int g = 0; g < 4; g++) {
            int ra = (wr * 64 + g * 16 + frow) * 40 + fk;
            int rw = (wc * 64 + g * 16 + frow) * 40 + fk;
            afh[g] = *(const short8*)&Ah[ra];
            afl[g] = *(const short8*)&Al[ra];
            wfh[g] = *(const short8*)&Wh[rw];
            wfl[g] = *(const short8*)&Wl[rw];
        }
#pragma unroll
        for (int mg = 0; mg < 4; mg++)
#pragma unroll
            for (int ng = 0; ng < 4; ng++) {
                acc[mg][ng] = __builtin_amdgcn_mfma_f32_16x16x32_bf16(afh[mg], wfh[ng], acc[mg][ng], 0, 0, 0);
                acc[mg][ng] = __builtin_amdgcn_mfma_f32_16x16x32_bf16(afh[mg], wfl[ng], acc[mg][ng], 0, 0, 0);
                acc[mg][ng] = __builtin_amdgcn_mfma_f32_16x16x32_bf16(afl[mg], wfh[ng], acc[mg][ng], 0, 0, 0);
            }
    }

    // C layout: col=lane&15, row=(lane>>4)*4+reg  [verified m89]
#pragma unroll
    for (int ng = 0; ng < 4; ng++) {
        int col = n0 + wc * 64 + ng * 16 + frow;
        float bv = BIAS ? bias[col] : 0.f;
#pragma unroll
        for (int mg = 0; mg < 4; mg++)
#pragma unroll
            for (int r = 0; r < 4; r++) {
                int row = m0 + wr * 64 + mg * 16 + (ln >> 4) * 4 + r;
                float v = acc[mg][ng][r] + bv;
                if (OUTK == 0) ((float*)Cv)[(size_t)row * N + col] = v;
                else           ((unsigned*)Cv)[(size_t)row * N + col] = packpair(v);
            }
    }
}

// ---------------------------------------------------------------------------
// fp32 tiled GEMM (xproj, N=48): BM=BN=64, BK=16, 4x4/thread.
// Proven at ~25 µs; LDS-tiled W -> coalesced, pipelined.
// ---------------------------------------------------------------------------
template <bool BIAS>
__global__ __launch_bounds__(256) void k_gemm(
    const float* __restrict__ A, const float* __restrict__ W,
    const float* __restrict__ bias, float* __restrict__ C,
    int M, int N, int K)
{
    const int BM = 64, BN = 64, BK = 16;
    __shared__ float As[BK][BM];
    __shared__ float Ws[BK][BN];

    int m0  = blockIdx.x * BM;
    int n0  = blockIdx.y * BN;
    int tid = threadIdx.x;
    int tx  = tid & 15, ty = tid >> 4;
    int lr  = tid >> 2;
    int lc  = (tid & 3) * 4;

    float acc[4][4] = {};

    for (int k0 = 0; k0 < K; k0 += BK) {
        float4 av = *(const float4*)(A + (size_t)(m0 + lr) * K + k0 + lc);
        As[lc + 0][lr] = av.x; As[lc + 1][lr] = av.y;
        As[lc + 2][lr] = av.z; As[lc + 3][lr] = av.w;
        float4 wv = make_float4(0.f, 0.f, 0.f, 0.f);
        if (n0 + lr < N) wv = *(const float4*)(W + (size_t)(n0 + lr) * K + k0 + lc);
        Ws[lc + 0][lr] = wv.x; Ws[lc + 1][lr] = wv.y;
        Ws[lc + 2][lr] = wv.z; Ws[lc + 3][lr] = wv.w;
        __syncthreads();
#pragma unroll
        for (int k = 0; k < BK; k++) {
            float a[4], bv[4];
            *(float4*)a  = *(const float4*)&As[k][ty * 4];
            *(float4*)bv = *(const float4*)&Ws[k][tx * 4];
#pragma unroll
            for (int i = 0; i < 4; i++)
#pragma unroll
                for (int j = 0; j < 4; j++)
                    acc[i][j] = fmaf(a[i], bv[j], acc[i][j]);
        }
        __syncthreads();
    }

    int n = n0 + tx * 4;
    float4 bv = make_float4(0.f, 0.f, 0.f, 0.f);
    if (BIAS && n < N) bv = *(const float4*)(bias + n);
#pragma unroll
    for (int i = 0; i < 4; i++) {
        if (n < N) {
            float4 v = make_float4(acc[i][0] + bv.x, acc[i][1] + bv.y,
                                   acc[i][2] + bv.z, acc[i][3] + bv.w);
            *(float4*)(C + (size_t)(m0 + ty * 4 + i) * N + n) = v;
        }
    }
}

// ---------------------------------------------------------------------------
// depthwise causal conv1d (k=4) + SiLU, chunked with halo [3][32][512].
// ---------------------------------------------------------------------------
__global__ __launch_bounds__(256) void k_conv(
    const float* __restrict__ xz, const float* __restrict__ halo,
    const float* __restrict__ cw, const float* __restrict__ cb,
    float* __restrict__ xc, int t0)
{
    size_t idx = (size_t)blockIdx.x * 256 + threadIdx.x;   // over RC*512
    int d  = (int)(idx & (DI - 1));
    int r  = (int)(idx >> 9);
    int b  = r & 31;
    int tl = r >> 5;

    float4 wv = *(const float4*)(cw + d * 4);
    float wk[4] = { wv.x, wv.y, wv.z, wv.w };
    float acc = cb[d];

    if (tl >= 3) {
        const float* base = xz + ((size_t)(tl - 3) * 32 + b) * 1024 + d;
#pragma unroll
        for (int k = 0; k < 4; k++) acc = fmaf(wk[k], base[(size_t)k * 32 * 1024], acc);
    } else {
#pragma unroll
        for (int k = 0; k < 4; k++) {
            int ts = t0 + tl - 3 + k;
            float v;
            if (ts < 0) continue;
            else if (ts >= t0) v = xz[((size_t)(tl - 3 + k) * 32 + b) * 1024 + d];
            else v = halo[((size_t)(tl - 3 + k + 3) * 32 + b) * 512 + d];
            acc = fmaf(wk[k], v, acc);
        }
    }
    xc[idx] = acc / (1.f + __expf(-acc));      // silu
}

__global__ __launch_bounds__(256) void k_halo(
    const float* __restrict__ xz, float* __restrict__ halo)
{
    int idx = blockIdx.x * 256 + threadIdx.x;  // over 3*32*512
    int d = idx & 511;
    int b = (idx >> 9) & 31;
    int s = idx >> 14;
    halo[idx] = xz[(((size_t)(CH - 3 + s) * 32 + b) << 10) + d];
}

// ---------------------------------------------------------------------------
// scan pass A (fused dt-proj): local scan per sub-chunk (h=0).
// dt = softplus(dtb[d] + dbc[r,0:16].dtw[d,:]) computed inline.
// Writes ONLY hend + sumdt. grid: 32*2*16 = 1024 blocks.
// ---------------------------------------------------------------------------
__global__ __launch_bounds__(256) void k_scanA(
    const float* __restrict__ xc, const float* __restrict__ dbc,
    const float* __restrict__ dtw, const float* __restrict__ dtb,
    const float* __restrict__ A_log,
    float* __restrict__ hend, float* __restrict__ sumdt)
{
    int bx = blockIdx.x;
    int b    = bx >> 5;
    int half = (bx >> 4) & 1;
    int c    = bx & 15;
    int d = (half << 8) + threadIdx.x;

    float A2[DS], h[DS], wdt[DS];
#pragma unroll
    for (int s = 0; s < DS; s++) {
        A2[s] = -__expf(A_log[d * DS + s]) * LOG2E;
        h[s] = 0.f;
        wdt[s] = dtw[d * DS + s];
    }
    float dtbv = dtb[d];

    __shared__ float Bs[SCT][48];
    for (int f = threadIdx.x; f < SCT * 48; f += 256) {
        int tt = f / 48, jj = f - tt * 48;
        Bs[tt][jj] = dbc[((size_t)(c * SCT + tt) * 32 + b) * 48 + jj];
    }
    __syncthreads();

    float cum = 0.f;
    for (int tt = 0; tt < SCT; tt++) {
        size_t idx = ((size_t)(c * SCT + tt) * 32 + b) * DI + d;
        float s0 = dtbv;
#pragma unroll
        for (int k = 0; k < DS; k++) s0 = fmaf(Bs[tt][k], wdt[k], s0);
        float dt = (s0 > 20.f) ? s0 : log1pf(expf(s0));
        cum += dt;
        float dtx = dt * xc[idx];
#pragma unroll
        for (int s = 0; s < DS; s++) {
            float dA = exp2f(dt * A2[s]);
            h[s] = fmaf(dA, h[s], dtx * Bs[tt][16 + s]);
        }
    }
    float* hp = hend + ((size_t)(c * 32 + b) * 512 + d) * DS;
#pragma unroll
    for (int s = 0; s < DS; s++) hp[s] = h[s];
    sumdt[((size_t)c * 32 + b) * 512 + d] = cum;
}

// ---------------------------------------------------------------------------
// scan pass B: carry across 16 sub-chunks; hend -> h_init, carry -> hs.
// ---------------------------------------------------------------------------
__global__ __launch_bounds__(256) void k_scanB(
    const float* __restrict__ sumdt, float* __restrict__ hend,
    const float* __restrict__ A_log, float* __restrict__ hs, int first)
{
    int id = blockIdx.x * 256 + threadIdx.x;   // 32*512*16 = 262144
    int s = id & 15;
    int d = (id >> 4) & 511;
    int b = id >> 13;
    float A2 = -__expf(A_log[d * DS + s]) * LOG2E;
    size_t hsi = ((size_t)(b << 9) + d) * DS + s;
    float hin = first ? 0.f : hs[hsi];
    for (int c = 0; c < NSC; c++) {
        size_t hi = ((size_t)(c * 32 + b) * 512 + d) * DS + s;
        float he = hend[hi];
        float sd = sumdt[((size_t)c * 32 + b) * 512 + d];
        hend[hi] = hin;
        hin = fmaf(exp2f(A2 * sd), hin, he);
    }
    hs[hsi] = hin;
}

// ---------------------------------------------------------------------------
// scan pass C (fused dt-proj): rescan seeded with h_init, y inline, epilogue
// (y+x*D)*silu(z) -> bf16 pair in-place over xz's xi slot. grid 1024.
// ---------------------------------------------------------------------------
__global__ __launch_bounds__(256) void k_scanC(
    const float* __restrict__ xc, const float* __restrict__ dbc,
    const float* __restrict__ dtw, const float* __restrict__ dtb,
    float* __restrict__ xz,
    const float* __restrict__ A_log, const float* __restrict__ Dp,
    const float* __restrict__ hinit)
{
    int bx = blockIdx.x;
    int b    = bx >> 5;
    int half = (bx >> 4) & 1;
    int c    = bx & 15;
    int d = (half << 8) + threadIdx.x;

    float A2[DS], h[DS], wdt[DS];
    const float* hp = hinit + ((size_t)(c * 32 + b) * 512 + d) * DS;
#pragma unroll
    for (int s = 0; s < DS; s++) {
        A2[s] = -__expf(A_log[d * DS + s]) * LOG2E;
        h[s] = hp[s];
        wdt[s] = dtw[d * DS + s];
    }
    float dtbv = dtb[d];
    float Dv = Dp[d];

    __shared__ float BC[SCT][48];
    for (int f = threadIdx.x; f < SCT * 48; f += 256) {
        int tt = f / 48, jj = f - tt * 48;
        BC[tt][jj] = dbc[((size_t)(c * SCT + tt) * 32 + b) * 48 + jj];
    }
    __syncthreads();

    for (int tt = 0; tt < SCT; tt++) {
        size_t row = (size_t)(c * SCT + tt) * 32 + b;
        size_t idx = row * DI + d;
        float s0 = dtbv;
#pragma unroll
        for (int k = 0; k < DS; k++) s0 = fmaf(BC[tt][k], wdt[k], s0);
        float dt = (s0 > 20.f) ? s0 : log1pf(expf(s0));
        float x  = xc[idx];
        float z  = xz[(row << 10) + 512 + d];
        float dtx = dt * x;
        float y = 0.f;
#pragma unroll
        for (int s = 0; s < DS; s++) {
            float dA = exp2f(dt * A2[s]);
            h[s] = fmaf(dA, h[s], dtx * BC[tt][16 + s]);
            y = fmaf(h[s], BC[tt][32 + s], y);
        }
        float yact = (y + x * Dv) * (z / (1.f + __expf(-z)));
        ((unsigned*)xz)[(row << 10) + d] = packpair(yact);
    }
}

// ---------------------------------------------------------------------------
// mean accumulate / head
// ---------------------------------------------------------------------------
__global__ __launch_bounds__(256) void k_meanacc(
    const float* __restrict__ mo, float* __restrict__ meanacc, int first)
{
    int b = blockIdx.x;
    int m = threadIdx.x;
    float s = 0.f;
    for (int tl = 0; tl < CH; tl++)
        s += mo[((size_t)tl * 32 + b) * 256 + m];
    if (first) meanacc[b * 256 + m] = s;
    else       meanacc[b * 256 + m] += s;
}

__global__ __launch_bounds__(128) void k_head(
    const float* __restrict__ meanacc, const float* __restrict__ xst,
    const float* __restrict__ h1w, const float* __restrict__ h1b,
    const float* __restrict__ h2w, const float* __restrict__ h2b,
    float* __restrict__ out)
{
    int b = blockIdx.x;
    int j = threadIdx.x;
    const float* wr = h1w + j * 261;
    const float* mr = meanacc + b * 256;
    float s = h1b[j];
    for (int k = 0; k < 256; k++) s = fmaf(mr[k] * (1.f / 1024.f), wr[k], s);
    for (int k = 0; k < 5; k++) s = fmaf(xst[b * 5 + k], wr[256 + k], s);
    float e = (s > 0.f) ? s : expm1f(s);

    __shared__ float sb[128];
    sb[j] = e * h2w[j];
    __syncthreads();
    for (int o = 64; o > 0; o >>= 1) {
        if (j < o) sb[j] += sb[j + o];
        __syncthreads();
    }
    if (j == 0) out[b] = sb[0] + h2b[0];
}

// ---------------------------------------------------------------------------
// host side
// ---------------------------------------------------------------------------
static void run_mamba_chunk(hipStream_t stream, const unsigned* xinp, void* const* P,
                            const unsigned* winp, const unsigned* woutp, int out_pairs,
                            float* xzc, float* xcc, float* dbcc,
                            float* moc, float* hendb, float* sumdtb, float* halo,
                            float* hstate, int t0)
{
    const float* cw     = (const float*)P[1];
    const float* cb     = (const float*)P[2];
    const float* xpw    = (const float*)P[3];
    const float* dtw    = (const float*)P[4];
    const float* dtbias = (const float*)P[5];
    const float* Alog   = (const float*)P[6];
    const float* Dp     = (const float*)P[7];
    int first = (t0 == 0);

    k_gmfma<0, false><<<dim3(RC / 128, 1024 / 128), 256, 0, stream>>>(
        xinp, 256, winp, nullptr, xzc, 1024, 256);
    k_conv<<<RC * DI / 256, 256, 0, stream>>>(xzc, halo, cw, cb, xcc, t0);
    k_halo<<<3 * 32 * 512 / 256, 256, 0, stream>>>(xzc, halo);
    k_gemm<false><<<dim3(RC / 64, 1), 256, 0, stream>>>(
        xcc, xpw, nullptr, dbcc, RC, 48, 512);
    k_scanA<<<32 * 2 * NSC, 256, 0, stream>>>(xcc, dbcc, dtw, dtbias, Alog,
                                              hendb, sumdtb);
    k_scanB<<<32 * 512 * DS / 256, 256, 0, stream>>>(sumdtb, hendb, Alog, hstate, first);
    k_scanC<<<32 * 2 * NSC, 256, 0, stream>>>(xcc, dbcc, dtw, dtbias, xzc,
                                              Alog, Dp, hendb);
    if (out_pairs)
        k_gmfma<1, false><<<dim3(RC / 128, 256 / 128), 256, 0, stream>>>(
            (const unsigned*)xzc, 1024, woutp, nullptr, moc, 256, 512);
    else
        k_gmfma<0, false><<<dim3(RC / 128, 256 / 128), 256, 0, stream>>>(
            (const unsigned*)xzc, 1024, woutp, nullptr, moc, 256, 512);
}

extern "C" void kernel_launch(void* const* d_in, const int* in_sizes, int n_in,
                              void* d_out, int out_size, void* d_ws, size_t ws_size,
                              hipStream_t stream)
{
    const float* xseq = (const float*)d_in[0];
    const float* xst  = (const float*)d_in[1];
    const float* p1w  = (const float*)d_in[2];
    const float* p1b  = (const float*)d_in[3];
    const float* ln1g = (const float*)d_in[4];
    const float* ln1b = (const float*)d_in[5];
    const float* p2w  = (const float*)d_in[6];
    const float* p2b  = (const float*)d_in[7];
    const float* ln2g = (const float*)d_in[8];
    const float* ln2b = (const float*)d_in[9];
    const float* h1w  = (const float*)d_in[10];
    const float* h1b  = (const float*)d_in[11];
    const float* h2w  = (const float*)d_in[12];
    const float* h2b  = (const float*)d_in[13];

    float* ws = (float*)d_ws;
    float*    xzc    = ws;                                  // RC*1024 f32
    float*    xcc    = xzc  + (size_t)RC * 1024;            // RC*512
    float*    dbcc   = xcc  + (size_t)RC * 512;             // RC*48
    float*    moc    = dbcc + (size_t)RC * 48;              // RC*256
    unsigned* x1p    = (unsigned*)(moc + (size_t)RC * 256); // RC*256 pairs
    // hend aliases moc∪x1p (4.19M floats) — both dead during scan phase
    float*    hendb  = moc;                                 // NSC*32*512*DS
    float*    sumdtb = (float*)(x1p + (size_t)RC * 256);    // NSC*32*512
    float*    halo1  = sumdtb + NSC * 32 * 512;             // 3*32*512
    float*    halo2  = halo1 + 3 * 32 * 512;
    float*    hs1    = halo2 + 3 * 32 * 512;                // 32*512*16
    float*    hs2    = hs1  + 32 * 512 * DS;
    float*    macc   = hs2  + 32 * 512 * DS;                // 32*256
    unsigned* wm1i   = (unsigned*)(macc + 32 * 256);        // 1024*256
    unsigned* wm1o   = wm1i + 262144;                       // 256*512
    unsigned* wm2i   = wm1o + 131072;
    unsigned* wm2o   = wm2i + 262144;
    unsigned* wp2    = wm2o + 131072;                       // 256*256
    size_t need = (size_t)((float*)(wp2 + 65536) - ws) * sizeof(float);
    if (ws_size < need) return;   // tripwire: fail cleanly, don't fault

    // weight bf16-pair conversion (once per launch)
    k_wcvt<<<262144 / 256, 256, 0, stream>>>((const float*)d_in[14], wm1i, 262144);
    k_wcvt<<<131072 / 256, 256, 0, stream>>>((const float*)d_in[22], wm1o, 131072);
    k_wcvt<<<262144 / 256, 256, 0, stream>>>((const float*)d_in[23], wm2i, 262144);
    k_wcvt<<<131072 / 256, 256, 0, stream>>>((const float*)d_in[31], wm2o, 131072);
    k_wcvt<<<65536 / 256, 256, 0, stream>>>(p2w, wp2, 65536);

    for (int c = 0; c < NCH; c++) {
        int t0 = c * CH;
        int first = (c == 0);

        k_p1_ln<<<RC, 256, 0, stream>>>(xseq, p1w, p1b, ln1g, ln1b, x1p, t0);

        // mamba 1 (params d_in[14..22]); out_proj emits pairs for p2
        run_mamba_chunk(stream, x1p, d_in + 14, wm1i, wm1o, 1,
                        xzc, xcc, dbcc, moc, hendb, sumdtb, halo1, hs1, t0);

        // p2 + LN2
        k_gmfma<0, true><<<dim3(RC / 128, 256 / 128), 256, 0, stream>>>(
            (const unsigned*)moc, 256, wp2, p2b, xzc, 256, 256);
        k_ln<<<RC, 256, 0, stream>>>(xzc, ln2g, ln2b, x1p);

        // mamba 2 (params d_in[23..31]); out_proj emits f32 for meanacc
        run_mamba_chunk(stream, x1p, d_in + 23, wm2i, wm2o, 0,
                        xzc, xcc, dbcc, moc, hendb, sumdtb, halo2, hs2, t0);

        k_meanacc<<<NB, 256, 0, stream>>>(moc, macc, first);
    }

    k_head<<<NB, 128, 0, stream>>>(macc, xst, h1w, h1b, h2w, h2b, (float*)d_out);
}

// Round 10
// 1388.115 us; speedup vs baseline: 1.4534x; 1.1345x over previous
//
#include <hip/hip_runtime.h>
#include <math.h>

#define NB 32
#define L  1024
#define CH 256                 // timesteps per chunk
#define NCH (L / CH)           // 4 chunks
#define RC (NB * CH)           // 8192 rows per chunk
#define DM 256
#define DI 512
#define DS 16
#define SCT 16                 // sub-chunk timesteps (scan)
#define NSC (CH / SCT)         // 16 sub-chunks
#define LOG2E 1.44269504f

typedef short short8 __attribute__((ext_vector_type(8)));
typedef float f32x4 __attribute__((ext_vector_type(4)));
typedef unsigned short u16;

// bf16 split helpers: x ~= hi + lo, both bf16 (rne).
__device__ inline unsigned f2bf_u(float x) {
    unsigned u = __float_as_uint(x);
    return (u + 0x7fffu + ((u >> 16) & 1u)) >> 16;
}

// Layout: per-chunk activations use (t_local, b, feat): row r = t_local*32 + b.

// ---------------------------------------------------------------------------
// p1 (K=4) + bias + LayerNorm; emits bf16 hi/lo PLANES for MFMA in_proj.
// ---------------------------------------------------------------------------
__global__ __launch_bounds__(256) void k_p1_ln(
    const float* __restrict__ xseq, const float* __restrict__ w,
    const float* __restrict__ bias, const float* __restrict__ g,
    const float* __restrict__ bb, u16* __restrict__ outh, u16* __restrict__ outl,
    int t0)
{
    int r  = blockIdx.x;
    int b  = r & 31;
    int tl = r >> 5;
    int m  = threadIdx.x;
    const float* xr = xseq + ((size_t)b * L + t0 + tl) * 4;
    float x0 = xr[0], x1 = xr[1], x2 = xr[2], x3 = xr[3];
    const float* wr = w + m * 4;
    float v = bias[m] + x0 * wr[0] + x1 * wr[1] + x2 * wr[2] + x3 * wr[3];

    __shared__ float s1[4], s2[4];
    float a = v, bq = v * v;
    for (int o = 32; o > 0; o >>= 1) { a += __shfl_down(a, o); bq += __shfl_down(bq, o); }
    int wid = m >> 6, lane = m & 63;
    if (lane == 0) { s1[wid] = a; s2[wid] = bq; }
    __syncthreads();
    if (m == 0) {
        s1[0] = s1[0] + s1[1] + s1[2] + s1[3];
        s2[0] = s2[0] + s2[1] + s2[2] + s2[3];
    }
    __syncthreads();
    float mu  = s1[0] * (1.f / 256.f);
    float var = s2[0] * (1.f / 256.f) - mu * mu;
    float o2 = (v - mu) * rsqrtf(var + 1e-5f) * g[m] + bb[m];
    unsigned hb = f2bf_u(o2);
    outh[(size_t)r * 256 + m] = (u16)hb;
    outl[(size_t)r * 256 + m] = (u16)f2bf_u(o2 - __uint_as_float(hb << 16));
}

// ---------------------------------------------------------------------------
// LayerNorm over 256; fp32 in, bf16 hi/lo planes out.
// ---------------------------------------------------------------------------
__global__ __launch_bounds__(256) void k_ln(
    const float* __restrict__ in, const float* __restrict__ g,
    const float* __restrict__ bb, u16* __restrict__ outh, u16* __restrict__ outl)
{
    int r = blockIdx.x;
    int m = threadIdx.x;
    float v = in[(size_t)r * 256 + m];

    __shared__ float s1[4], s2[4];
    float a = v, bq = v * v;
    for (int o = 32; o > 0; o >>= 1) { a += __shfl_down(a, o); bq += __shfl_down(bq, o); }
    int wid = m >> 6, lane = m & 63;
    if (lane == 0) { s1[wid] = a; s2[wid] = bq; }
    __syncthreads();
    if (m == 0) {
        s1[0] = s1[0] + s1[1] + s1[2] + s1[3];
        s2[0] = s2[0] + s2[1] + s2[2] + s2[3];
    }
    __syncthreads();
    float mu  = s1[0] * (1.f / 256.f);
    float var = s2[0] * (1.f / 256.f) - mu * mu;
    float o2 = (v - mu) * rsqrtf(var + 1e-5f) * g[m] + bb[m];
    unsigned hb = f2bf_u(o2);
    outh[(size_t)r * 256 + m] = (u16)hb;
    outl[(size_t)r * 256 + m] = (u16)f2bf_u(o2 - __uint_as_float(hb << 16));
}

__global__ __launch_bounds__(256) void k_wcvt(
    const float* __restrict__ w, u16* __restrict__ oh, u16* __restrict__ ol, int n)
{
    int i = blockIdx.x * 256 + threadIdx.x;
    if (i < n) {
        float v = w[i];
        unsigned hb = f2bf_u(v);
        oh[i] = (u16)hb;
        ol[i] = (u16)f2bf_u(v - __uint_as_float(hb << 16));
    }
}

// ---------------------------------------------------------------------------
// split-bf16 MFMA GEMM (3-term): C[M,N] = A[M,K]*W[N,K]^T (+bias).
// A,W given as separate hi/lo bf16 planes -> staging is pure load/store,
// zero unpack VALU. 128x128 tile, BK=32, 4 waves x 64x64 quadrant.
// OUTK: 0 = fp32 out (C0), 1 = hi/lo plane out (C0=hi, C1=lo).
// ---------------------------------------------------------------------------
template <int OUTK, bool BIAS>
__global__ __launch_bounds__(256) void k_gmfma(
    const u16* __restrict__ Ahg, const u16* __restrict__ Alg, int lda,
    const u16* __restrict__ Whg, const u16* __restrict__ Wlg,
    const float* __restrict__ bias, void* __restrict__ C0, void* __restrict__ C1,
    int N, int K)
{
    __shared__ u16 Ah[128 * 40], Al[128 * 40];
    __shared__ u16 Wh[128 * 40], Wl[128 * 40];

    int tid = threadIdx.x;
    int wv = tid >> 6, ln = tid & 63;
    int wr = wv >> 1, wc = wv & 1;
    int m0 = blockIdx.x * 128, n0 = blockIdx.y * 128;
    int sr = tid >> 1, sk = (tid & 1) << 4;
    int frow = ln & 15, fk = (ln >> 4) << 3;

    f32x4 acc[4][4] = {};

    for (int k0 = 0; k0 < K; k0 += 32) {
        const u16* ah = Ahg + (size_t)(m0 + sr) * lda + k0 + sk;
        const u16* al = Alg + (size_t)(m0 + sr) * lda + k0 + sk;
        const u16* wh = Whg + (size_t)(n0 + sr) * K + k0 + sk;
        const u16* wl = Wlg + (size_t)(n0 + sr) * K + k0 + sk;
        short8 vah0 = *(const short8*)ah, vah1 = *(const short8*)(ah + 8);
        short8 val0 = *(const short8*)al, val1 = *(const short8*)(al + 8);
        short8 vwh0 = *(const short8*)wh, vwh1 = *(const short8*)(wh + 8);
        short8 vwl0 = *(const short8*)wl, vwl1 = *(const short8*)(wl + 8);

        __syncthreads();   // previous iteration's frag reads done

        *(short8*)&Ah[sr * 40 + sk]     = vah0;
        *(short8*)&Ah[sr * 40 + sk + 8] = vah1;
        *(short8*)&Al[sr * 40 + sk]     = val0;
        *(short8*)&Al[sr * 40 + sk + 8] = val1;
        *(short8*)&Wh[sr * 40 + sk]     = vwh0;
        *(short8*)&Wh[sr * 40 + sk + 8] = vwh1;
        *(short8*)&Wl[sr * 40 + sk]     = vwl0;
        *(short8*)&Wl[sr * 40 + sk + 8] = vwl1;

        __syncthreads();

        short8 afh[4], afl[4], wfh[4], wfl[4];
#pragma unroll
        for (int g = 0; g < 4; g++) {
            int ra = (wr * 64 + g * 16 + frow) * 40 + fk;
            int rw = (wc * 64 + g * 16 + frow) * 40 + fk;
            afh[g] = *(const short8*)&Ah[ra];
            afl[g] = *(const short8*)&Al[ra];
            wfh[g] = *(const short8*)&Wh[rw];
            wfl[g] = *(const short8*)&Wl[rw];
        }
#pragma unroll
        for (int mg = 0; mg < 4; mg++)
#pragma unroll
            for (int ng = 0; ng < 4; ng++) {
                acc[mg][ng] = __builtin_amdgcn_mfma_f32_16x16x32_bf16(afh[mg], wfh[ng], acc[mg][ng], 0, 0, 0);
                acc[mg][ng] = __builtin_amdgcn_mfma_f32_16x16x32_bf16(afh[mg], wfl[ng], acc[mg][ng], 0, 0, 0);
                acc[mg][ng] = __builtin_amdgcn_mfma_f32_16x16x32_bf16(afl[mg], wfh[ng], acc[mg][ng], 0, 0, 0);
            }
    }

    // C layout: col=lane&15, row=(lane>>4)*4+reg  [verified m89]
#pragma unroll
    for (int ng = 0; ng < 4; ng++) {
        int col = n0 + wc * 64 + ng * 16 + frow;
        float bv = BIAS ? bias[col] : 0.f;
#pragma unroll
        for (int mg = 0; mg < 4; mg++)
#pragma unroll
            for (int r = 0; r < 4; r++) {
                int row = m0 + wr * 64 + mg * 16 + (ln >> 4) * 4 + r;
                float v = acc[mg][ng][r] + bv;
                if (OUTK == 0) {
                    ((float*)C0)[(size_t)row * N + col] = v;
                } else {
                    unsigned hb = f2bf_u(v);
                    ((u16*)C0)[(size_t)row * N + col] = (u16)hb;
                    ((u16*)C1)[(size_t)row * N + col] =
                        (u16)f2bf_u(v - __uint_as_float(hb << 16));
                }
            }
    }
}

// ---------------------------------------------------------------------------
// fp32 tiled GEMM (xproj, N=48): BM=BN=64, BK=16, 4x4/thread (proven ~25 us).
// ---------------------------------------------------------------------------
template <bool BIAS>
__global__ __launch_bounds__(256) void k_gemm(
    const float* __restrict__ A, const float* __restrict__ W,
    const float* __restrict__ bias, float* __restrict__ C,
    int M, int N, int K)
{
    const int BM = 64, BN = 64, BK = 16;
    __shared__ float As[BK][BM];
    __shared__ float Ws[BK][BN];

    int m0  = blockIdx.x * BM;
    int n0  = blockIdx.y * BN;
    int tid = threadIdx.x;
    int tx  = tid & 15, ty = tid >> 4;
    int lr  = tid >> 2;
    int lc  = (tid & 3) * 4;

    float acc[4][4] = {};

    for (int k0 = 0; k0 < K; k0 += BK) {
        float4 av = *(const float4*)(A + (size_t)(m0 + lr) * K + k0 + lc);
        As[lc + 0][lr] = av.x; As[lc + 1][lr] = av.y;
        As[lc + 2][lr] = av.z; As[lc + 3][lr] = av.w;
        float4 wv = make_float4(0.f, 0.f, 0.f, 0.f);
        if (n0 + lr < N) wv = *(const float4*)(W + (size_t)(n0 + lr) * K + k0 + lc);
        Ws[lc + 0][lr] = wv.x; Ws[lc + 1][lr] = wv.y;
        Ws[lc + 2][lr] = wv.z; Ws[lc + 3][lr] = wv.w;
        __syncthreads();
#pragma unroll
        for (int k = 0; k < BK; k++) {
            float a[4], bv[4];
            *(float4*)a  = *(const float4*)&As[k][ty * 4];
            *(float4*)bv = *(const float4*)&Ws[k][tx * 4];
#pragma unroll
            for (int i = 0; i < 4; i++)
#pragma unroll
                for (int j = 0; j < 4; j++)
                    acc[i][j] = fmaf(a[i], bv[j], acc[i][j]);
        }
        __syncthreads();
    }

    int n = n0 + tx * 4;
    float4 bv = make_float4(0.f, 0.f, 0.f, 0.f);
    if (BIAS && n < N) bv = *(const float4*)(bias + n);
#pragma unroll
    for (int i = 0; i < 4; i++) {
        if (n < N) {
            float4 v = make_float4(acc[i][0] + bv.x, acc[i][1] + bv.y,
                                   acc[i][2] + bv.z, acc[i][3] + bv.w);
            *(float4*)(C + (size_t)(m0 + ty * 4 + i) * N + n) = v;
        }
    }
}

// ---------------------------------------------------------------------------
// depthwise causal conv1d (k=4) + SiLU, chunked with halo [3][32][512].
// ---------------------------------------------------------------------------
__global__ __launch_bounds__(256) void k_conv(
    const float* __restrict__ xz, const float* __restrict__ halo,
    const float* __restrict__ cw, const float* __restrict__ cb,
    float* __restrict__ xc, int t0)
{
    size_t idx = (size_t)blockIdx.x * 256 + threadIdx.x;   // over RC*512
    int d  = (int)(idx & (DI - 1));
    int r  = (int)(idx >> 9);
    int b  = r & 31;
    int tl = r >> 5;

    float4 wv = *(const float4*)(cw + d * 4);
    float wk[4] = { wv.x, wv.y, wv.z, wv.w };
    float acc = cb[d];

    if (tl >= 3) {
        const float* base = xz + ((size_t)(tl - 3) * 32 + b) * 1024 + d;
#pragma unroll
        for (int k = 0; k < 4; k++) acc = fmaf(wk[k], base[(size_t)k * 32 * 1024], acc);
    } else {
#pragma unroll
        for (int k = 0; k < 4; k++) {
            int ts = t0 + tl - 3 + k;
            float v;
            if (ts < 0) continue;
            else if (ts >= t0) v = xz[((size_t)(tl - 3 + k) * 32 + b) * 1024 + d];
            else v = halo[((size_t)(tl - 3 + k + 3) * 32 + b) * 512 + d];
            acc = fmaf(wk[k], v, acc);
        }
    }
    xc[idx] = acc / (1.f + __expf(-acc));      // silu
}

__global__ __launch_bounds__(256) void k_halo(
    const float* __restrict__ xz, float* __restrict__ halo)
{
    int idx = blockIdx.x * 256 + threadIdx.x;  // over 3*32*512
    int d = idx & 511;
    int b = (idx >> 9) & 31;
    int s = idx >> 14;
    halo[idx] = xz[(((size_t)(CH - 3 + s) * 32 + b) << 10) + d];
}

// ---------------------------------------------------------------------------
// scan pass A (fused dt-proj, geometric-dA fast path): local scan, h=0.
// If A2[s] == (s+1)*A2[0] (true for this model's A_log = log(1..16)),
// dA[s] = q^(s+1) with q = exp2(dt*A2[0]): 16 exp2 -> 1 exp2 + 15 muls.
// Generic fallback preserved for arbitrary A. grid 1024 blocks.
// ---------------------------------------------------------------------------
__global__ __launch_bounds__(256) void k_scanA(
    const float* __restrict__ xc, const float* __restrict__ dbc,
    const float* __restrict__ dtw, const float* __restrict__ dtb,
    const float* __restrict__ A_log,
    float* __restrict__ hend, float* __restrict__ sumdt)
{
    int bx = blockIdx.x;
    int b    = bx >> 5;
    int half = (bx >> 4) & 1;
    int c    = bx & 15;
    int d = (half << 8) + threadIdx.x;

    float A2[DS], h[DS], wdt[DS];
#pragma unroll
    for (int s = 0; s < DS; s++) {
        A2[s] = -__expf(A_log[d * DS + s]) * LOG2E;
        h[s] = 0.f;
        wdt[s] = dtw[d * DS + s];
    }
    float dtbv = dtb[d];
    float A20 = A2[0];
    bool geo = true;
#pragma unroll
    for (int s = 0; s < DS; s++)
        geo = geo && (fabsf(A2[s] - (float)(s + 1) * A20) <=
                      1e-5f * fabsf(A2[s]) + 1e-30f);

    __shared__ float Bs[SCT][48];
    for (int f = threadIdx.x; f < SCT * 48; f += 256) {
        int tt = f / 48, jj = f - tt * 48;
        Bs[tt][jj] = dbc[((size_t)(c * SCT + tt) * 32 + b) * 48 + jj];
    }
    __syncthreads();

    float cum = 0.f;
    if (geo) {
        for (int tt = 0; tt < SCT; tt++) {
            size_t idx = ((size_t)(c * SCT + tt) * 32 + b) * DI + d;
            float s0 = dtbv;
#pragma unroll
            for (int k = 0; k < DS; k++) s0 = fmaf(Bs[tt][k], wdt[k], s0);
            float dt = (s0 > 20.f) ? s0 : log1pf(expf(s0));
            cum += dt;
            float dtx = dt * xc[idx];
            float q = exp2f(dt * A20);
            float dA = q;
#pragma unroll
            for (int s = 0; s < DS; s++) {
                h[s] = fmaf(dA, h[s], dtx * Bs[tt][16 + s]);
                dA *= q;
            }
        }
    } else {
        for (int tt = 0; tt < SCT; tt++) {
            size_t idx = ((size_t)(c * SCT + tt) * 32 + b) * DI + d;
            float s0 = dtbv;
#pragma unroll
            for (int k = 0; k < DS; k++) s0 = fmaf(Bs[tt][k], wdt[k], s0);
            float dt = (s0 > 20.f) ? s0 : log1pf(expf(s0));
            cum += dt;
            float dtx = dt * xc[idx];
#pragma unroll
            for (int s = 0; s < DS; s++) {
                float dA = exp2f(dt * A2[s]);
                h[s] = fmaf(dA, h[s], dtx * Bs[tt][16 + s]);
            }
        }
    }
    float* hp = hend + ((size_t)(c * 32 + b) * 512 + d) * DS;
#pragma unroll
    for (int s = 0; s < DS; s++) hp[s] = h[s];
    sumdt[((size_t)c * 32 + b) * 512 + d] = cum;
}

// ---------------------------------------------------------------------------
// scan pass B: carry across 16 sub-chunks; hend -> h_init, carry -> hs.
// ---------------------------------------------------------------------------
__global__ __launch_bounds__(256) void k_scanB(
    const float* __restrict__ sumdt, float* __restrict__ hend,
    const float* __restrict__ A_log, float* __restrict__ hs, int first)
{
    int id = blockIdx.x * 256 + threadIdx.x;   // 32*512*16 = 262144
    int s = id & 15;
    int d = (id >> 4) & 511;
    int b = id >> 13;
    float A2 = -__expf(A_log[d * DS + s]) * LOG2E;
    size_t hsi = ((size_t)(b << 9) + d) * DS + s;
    float hin = first ? 0.f : hs[hsi];
    for (int c = 0; c < NSC; c++) {
        size_t hi = ((size_t)(c * 32 + b) * 512 + d) * DS + s;
        float he = hend[hi];
        float sd = sumdt[((size_t)c * 32 + b) * 512 + d];
        hend[hi] = hin;
        hin = fmaf(exp2f(A2 * sd), hin, he);
    }
    hs[hsi] = hin;
}

// ---------------------------------------------------------------------------
// scan pass C (fused dt-proj, geometric-dA fast path): rescan seeded with
// h_init, y inline, epilogue (y+x*D)*silu(z) -> bf16 hi/lo planes yh/yl.
// ---------------------------------------------------------------------------
__global__ __launch_bounds__(256) void k_scanC(
    const float* __restrict__ xc, const float* __restrict__ dbc,
    const float* __restrict__ dtw, const float* __restrict__ dtb,
    const float* __restrict__ xz,
    const float* __restrict__ A_log, const float* __restrict__ Dp,
    const float* __restrict__ hinit,
    u16* __restrict__ yh, u16* __restrict__ yl)
{
    int bx = blockIdx.x;
    int b    = bx >> 5;
    int half = (bx >> 4) & 1;
    int c    = bx & 15;
    int d = (half << 8) + threadIdx.x;

    float A2[DS], h[DS], wdt[DS];
    const float* hp = hinit + ((size_t)(c * 32 + b) * 512 + d) * DS;
#pragma unroll
    for (int s = 0; s < DS; s++) {
        A2[s] = -__expf(A_log[d * DS + s]) * LOG2E;
        h[s] = hp[s];
        wdt[s] = dtw[d * DS + s];
    }
    float dtbv = dtb[d];
    float Dv = Dp[d];
    float A20 = A2[0];
    bool geo = true;
#pragma unroll
    for (int s = 0; s < DS; s++)
        geo = geo && (fabsf(A2[s] - (float)(s + 1) * A20) <=
                      1e-5f * fabsf(A2[s]) + 1e-30f);

    __shared__ float BC[SCT][48];
    for (int f = threadIdx.x; f < SCT * 48; f += 256) {
        int tt = f / 48, jj = f - tt * 48;
        BC[tt][jj] = dbc[((size_t)(c * SCT + tt) * 32 + b) * 48 + jj];
    }
    __syncthreads();

    if (geo) {
        for (int tt = 0; tt < SCT; tt++) {
            size_t row = (size_t)(c * SCT + tt) * 32 + b;
            size_t idx = row * DI + d;
            float s0 = dtbv;
#pragma unroll
            for (int k = 0; k < DS; k++) s0 = fmaf(BC[tt][k], wdt[k], s0);
            float dt = (s0 > 20.f) ? s0 : log1pf(expf(s0));
            float x  = xc[idx];
            float z  = xz[(row << 10) + 512 + d];
            float dtx = dt * x;
            float y = 0.f;
            float q = exp2f(dt * A20);
            float dA = q;
#pragma unroll
            for (int s = 0; s < DS; s++) {
                h[s] = fmaf(dA, h[s], dtx * BC[tt][16 + s]);
                y = fmaf(h[s], BC[tt][32 + s], y);
                dA *= q;
            }
            float yact = (y + x * Dv) * (z / (1.f + __expf(-z)));
            unsigned hb = f2bf_u(yact);
            yh[row * DI + d] = (u16)hb;
            yl[row * DI + d] = (u16)f2bf_u(yact - __uint_as_float(hb << 16));
        }
    } else {
        for (int tt = 0; tt < SCT; tt++) {
            size_t row = (size_t)(c * SCT + tt) * 32 + b;
            size_t idx = row * DI + d;
            float s0 = dtbv;
#pragma unroll
            for (int k = 0; k < DS; k++) s0 = fmaf(BC[tt][k], wdt[k], s0);
            float dt = (s0 > 20.f) ? s0 : log1pf(expf(s0));
            float x  = xc[idx];
            float z  = xz[(row << 10) + 512 + d];
            float dtx = dt * x;
            float y = 0.f;
#pragma unroll
            for (int s = 0; s < DS; s++) {
                float dA = exp2f(dt * A2[s]);
                h[s] = fmaf(dA, h[s], dtx * BC[tt][16 + s]);
                y = fmaf(h[s], BC[tt][32 + s], y);
            }
            float yact = (y + x * Dv) * (z / (1.f + __expf(-z)));
            unsigned hb = f2bf_u(yact);
            yh[row * DI + d] = (u16)hb;
            yl[row * DI + d] = (u16)f2bf_u(yact - __uint_as_float(hb << 16));
        }
    }
}

// ---------------------------------------------------------------------------
// mean accumulate / head
// ---------------------------------------------------------------------------
__global__ __launch_bounds__(256) void k_meanacc(
    const float* __restrict__ mo, float* __restrict__ meanacc, int first)
{
    int b = blockIdx.x;
    int m = threadIdx.x;
    float s = 0.f;
    for (int tl = 0; tl < CH; tl++)
        s += mo[((size_t)tl * 32 + b) * 256 + m];
    if (first) meanacc[b * 256 + m] = s;
    else       meanacc[b * 256 + m] += s;
}

__global__ __launch_bounds__(128) void k_head(
    const float* __restrict__ meanacc, const float* __restrict__ xst,
    const float* __restrict__ h1w, const float* __restrict__ h1b,
    const float* __restrict__ h2w, const float* __restrict__ h2b,
    float* __restrict__ out)
{
    int b = blockIdx.x;
    int j = threadIdx.x;
    const float* wr = h1w + j * 261;
    const float* mr = meanacc + b * 256;
    float s = h1b[j];
    for (int k = 0; k < 256; k++) s = fmaf(mr[k] * (1.f / 1024.f), wr[k], s);
    for (int k = 0; k < 5; k++) s = fmaf(xst[b * 5 + k], wr[256 + k], s);
    float e = (s > 0.f) ? s : expm1f(s);

    __shared__ float sb[128];
    sb[j] = e * h2w[j];
    __syncthreads();
    for (int o = 64; o > 0; o >>= 1) {
        if (j < o) sb[j] += sb[j + o];
        __syncthreads();
    }
    if (j == 0) out[b] = sb[0] + h2b[0];
}

// ---------------------------------------------------------------------------
// host side
// ---------------------------------------------------------------------------
static void run_mamba_chunk(hipStream_t stream,
                            const u16* x1h, const u16* x1l, void* const* P,
                            const u16* wih, const u16* wil,
                            const u16* woh, const u16* wol, int out_pairs,
                            float* xzc, float* xcc, float* dbcc,
                            float* moc, u16* moh, u16* mol,
                            u16* yh, u16* yl,
                            float* hendb, float* sumdtb, float* halo,
                            float* hstate, int t0)
{
    const float* cw     = (const float*)P[1];
    const float* cb     = (const float*)P[2];
    const float* xpw    = (const float*)P[3];
    const float* dtw    = (const float*)P[4];
    const float* dtbias = (const float*)P[5];
    const float* Alog   = (const float*)P[6];
    const float* Dp     = (const float*)P[7];
    int first = (t0 == 0);

    k_gmfma<0, false><<<dim3(RC / 128, 1024 / 128), 256, 0, stream>>>(
        x1h, x1l, 256, wih, wil, nullptr, xzc, nullptr, 1024, 256);
    k_conv<<<RC * DI / 256, 256, 0, stream>>>(xzc, halo, cw, cb, xcc, t0);
    k_halo<<<3 * 32 * 512 / 256, 256, 0, stream>>>(xzc, halo);
    k_gemm<false><<<dim3(RC / 64, 1), 256, 0, stream>>>(
        xcc, xpw, nullptr, dbcc, RC, 48, 512);
    k_scanA<<<32 * 2 * NSC, 256, 0, stream>>>(xcc, dbcc, dtw, dtbias, Alog,
                                              hendb, sumdtb);
    k_scanB<<<32 * 512 * DS / 256, 256, 0, stream>>>(sumdtb, hendb, Alog, hstate, first);
    k_scanC<<<32 * 2 * NSC, 256, 0, stream>>>(xcc, dbcc, dtw, dtbias, xzc,
                                              Alog, Dp, hendb, yh, yl);
    if (out_pairs)
        k_gmfma<1, false><<<dim3(RC / 128, 256 / 128), 256, 0, stream>>>(
            yh, yl, 512, woh, wol, nullptr, moh, mol, 256, 512);
    else
        k_gmfma<0, false><<<dim3(RC / 128, 256 / 128), 256, 0, stream>>>(
            yh, yl, 512, woh, wol, nullptr, moc, nullptr, 256, 512);
}

extern "C" void kernel_launch(void* const* d_in, const int* in_sizes, int n_in,
                              void* d_out, int out_size, void* d_ws, size_t ws_size,
                              hipStream_t stream)
{
    const float* xseq = (const float*)d_in[0];
    const float* xst  = (const float*)d_in[1];
    const float* p1w  = (const float*)d_in[2];
    const float* p1b  = (const float*)d_in[3];
    const float* ln1g = (const float*)d_in[4];
    const float* ln1b = (const float*)d_in[5];
    const float* p2w  = (const float*)d_in[6];
    const float* p2b  = (const float*)d_in[7];
    const float* ln2g = (const float*)d_in[8];
    const float* ln2b = (const float*)d_in[9];
    const float* h1w  = (const float*)d_in[10];
    const float* h1b  = (const float*)d_in[11];
    const float* h2w  = (const float*)d_in[12];
    const float* h2b  = (const float*)d_in[13];

    float* ws = (float*)d_ws;
    float* xzc    = ws;                                  // RC*1024 f32
    float* xcc    = xzc  + (size_t)RC * 1024;            // RC*512
    float* dbcc   = xcc  + (size_t)RC * 512;             // RC*48
    float* moc    = dbcc + (size_t)RC * 48;              // RC*256 f32
    u16*   x1h    = (u16*)(moc + (size_t)RC * 256);      // RC*256 u16
    u16*   x1l    = x1h + (size_t)RC * 256;              // RC*256 u16
    // hend aliases [moc | x1h | x1l] = exactly NSC*32*512*DS floats;
    // all three are dead during the scan phase (liveness audited).
    float* hendb  = moc;
    float* after  = (float*)(x1l + (size_t)RC * 256);
    u16*   yh     = (u16*)after;                         // RC*512 u16
    u16*   yl     = yh + (size_t)RC * 512;               // RC*512 u16
    u16*   moh    = yl + (size_t)RC * 512;               // RC*256 u16
    u16*   mol    = moh + (size_t)RC * 256;              // RC*256 u16
    float* sumdtb = (float*)(mol + (size_t)RC * 256);    // NSC*32*512
    float* halo1  = sumdtb + NSC * 32 * 512;             // 3*32*512
    float* halo2  = halo1 + 3 * 32 * 512;
    float* hs1    = halo2 + 3 * 32 * 512;                // 32*512*16
    float* hs2    = hs1  + 32 * 512 * DS;
    float* macc   = hs2  + 32 * 512 * DS;                // 32*256
    u16*   wm1ih  = (u16*)(macc + 32 * 256);             // 1024*256 u16 each
    u16*   wm1il  = wm1ih + 262144;
    u16*   wm1oh  = wm1il + 262144;                      // 256*512 u16 each
    u16*   wm1ol  = wm1oh + 131072;
    u16*   wm2ih  = wm1ol + 131072;
    u16*   wm2il  = wm2ih + 262144;
    u16*   wm2oh  = wm2il + 262144;
    u16*   wm2ol  = wm2oh + 131072;
    u16*   wp2h   = wm2ol + 131072;                      // 256*256 u16 each
    u16*   wp2l   = wp2h + 65536;
    size_t need = (size_t)((char*)(wp2l + 65536) - (char*)ws);
    if (ws_size < need) return;   // tripwire: fail cleanly, don't fault

    // weight bf16 hi/lo plane conversion (once per launch)
    k_wcvt<<<262144 / 256, 256, 0, stream>>>((const float*)d_in[14], wm1ih, wm1il, 262144);
    k_wcvt<<<131072 / 256, 256, 0, stream>>>((const float*)d_in[22], wm1oh, wm1ol, 131072);
    k_wcvt<<<262144 / 256, 256, 0, stream>>>((const float*)d_in[23], wm2ih, wm2il, 262144);
    k_wcvt<<<131072 / 256, 256, 0, stream>>>((const float*)d_in[31], wm2oh, wm2ol, 131072);
    k_wcvt<<<65536 / 256, 256, 0, stream>>>(p2w, wp2h, wp2l, 65536);

    for (int c = 0; c < NCH; c++) {
        int t0 = c * CH;
        int first = (c == 0);

        k_p1_ln<<<RC, 256, 0, stream>>>(xseq, p1w, p1b, ln1g, ln1b, x1h, x1l, t0);

        // mamba 1 (params d_in[14..22]); out_proj emits hi/lo planes for p2
        run_mamba_chunk(stream, x1h, x1l, d_in + 14, wm1ih, wm1il, wm1oh, wm1ol, 1,
                        xzc, xcc, dbcc, moc, moh, mol, yh, yl,
                        hendb, sumdtb, halo1, hs1, t0);

        // p2 + LN2
        k_gmfma<0, true><<<dim3(RC / 128, 256 / 128), 256, 0, stream>>>(
            moh, mol, 256, wp2h, wp2l, p2b, xzc, nullptr, 256, 256);
        k_ln<<<RC, 256, 0, stream>>>(xzc, ln2g, ln2b, x1h, x1l);

        // mamba 2 (params d_in[23..31]); out_proj emits f32 for meanacc
        run_mamba_chunk(stream, x1h, x1l, d_in + 23, wm2ih, wm2il, wm2oh, wm2ol, 0,
                        xzc, xcc, dbcc, moc, moh, mol, yh, yl,
                        hendb, sumdtb, halo2, hs2, t0);

        k_meanacc<<<NB, 256, 0, stream>>>(moc, macc, first);
    }

    k_head<<<NB, 128, 0, stream>>>(macc, xst, h1w, h1b, h2w, h2b, (float*)d_out);
}

// Round 11
// 1269.128 us; speedup vs baseline: 1.5896x; 1.0938x over previous
//
#include <hip/hip_runtime.h>
#include <math.h>

#define NB 32
#define L  1024
#define CH 256                 // timesteps per chunk
#define NCH (L / CH)           // 4 chunks
#define RC (NB * CH)           // 8192 rows per chunk
#define DM 256
#define DI 512
#define DS 16
#define SCT 16                 // sub-chunk timesteps (scan)
#define NSC (CH / SCT)         // 16 sub-chunks
#define LOG2E 1.44269504f

typedef short short8 __attribute__((ext_vector_type(8)));
typedef float f32x4 __attribute__((ext_vector_type(4)));
typedef unsigned short u16;

// bf16 split helpers: x ~= hi + lo, both bf16 (rne).
__device__ inline unsigned f2bf_u(float x) {
    unsigned u = __float_as_uint(x);
    return (u + 0x7fffu + ((u >> 16) & 1u)) >> 16;
}

// Layout: per-chunk activations use (t_local, b, feat): row r = t_local*32 + b.

// ---------------------------------------------------------------------------
// p1 (K=4) + bias + LayerNorm; emits bf16 hi/lo PLANES for MFMA in_proj.
// ---------------------------------------------------------------------------
__global__ __launch_bounds__(256) void k_p1_ln(
    const float* __restrict__ xseq, const float* __restrict__ w,
    const float* __restrict__ bias, const float* __restrict__ g,
    const float* __restrict__ bb, u16* __restrict__ outh, u16* __restrict__ outl,
    int t0)
{
    int r  = blockIdx.x;
    int b  = r & 31;
    int tl = r >> 5;
    int m  = threadIdx.x;
    const float* xr = xseq + ((size_t)b * L + t0 + tl) * 4;
    float x0 = xr[0], x1 = xr[1], x2 = xr[2], x3 = xr[3];
    const float* wr = w + m * 4;
    float v = bias[m] + x0 * wr[0] + x1 * wr[1] + x2 * wr[2] + x3 * wr[3];

    __shared__ float s1[4], s2[4];
    float a = v, bq = v * v;
    for (int o = 32; o > 0; o >>= 1) { a += __shfl_down(a, o); bq += __shfl_down(bq, o); }
    int wid = m >> 6, lane = m & 63;
    if (lane == 0) { s1[wid] = a; s2[wid] = bq; }
    __syncthreads();
    if (m == 0) {
        s1[0] = s1[0] + s1[1] + s1[2] + s1[3];
        s2[0] = s2[0] + s2[1] + s2[2] + s2[3];
    }
    __syncthreads();
    float mu  = s1[0] * (1.f / 256.f);
    float var = s2[0] * (1.f / 256.f) - mu * mu;
    float o2 = (v - mu) * rsqrtf(var + 1e-5f) * g[m] + bb[m];
    unsigned hb = f2bf_u(o2);
    outh[(size_t)r * 256 + m] = (u16)hb;
    outl[(size_t)r * 256 + m] = (u16)f2bf_u(o2 - __uint_as_float(hb << 16));
}

// ---------------------------------------------------------------------------
// LayerNorm over 256; fp32 in, bf16 hi/lo planes out.
// ---------------------------------------------------------------------------
__global__ __launch_bounds__(256) void k_ln(
    const float* __restrict__ in, const float* __restrict__ g,
    const float* __restrict__ bb, u16* __restrict__ outh, u16* __restrict__ outl)
{
    int r = blockIdx.x;
    int m = threadIdx.x;
    float v = in[(size_t)r * 256 + m];

    __shared__ float s1[4], s2[4];
    float a = v, bq = v * v;
    for (int o = 32; o > 0; o >>= 1) { a += __shfl_down(a, o); bq += __shfl_down(bq, o); }
    int wid = m >> 6, lane = m & 63;
    if (lane == 0) { s1[wid] = a; s2[wid] = bq; }
    __syncthreads();
    if (m == 0) {
        s1[0] = s1[0] + s1[1] + s1[2] + s1[3];
        s2[0] = s2[0] + s2[1] + s2[2] + s2[3];
    }
    __syncthreads();
    float mu  = s1[0] * (1.f / 256.f);
    float var = s2[0] * (1.f / 256.f) - mu * mu;
    float o2 = (v - mu) * rsqrtf(var + 1e-5f) * g[m] + bb[m];
    unsigned hb = f2bf_u(o2);
    outh[(size_t)r * 256 + m] = (u16)hb;
    outl[(size_t)r * 256 + m] = (u16)f2bf_u(o2 - __uint_as_float(hb << 16));
}

__global__ __launch_bounds__(256) void k_wcvt(
    const float* __restrict__ w, u16* __restrict__ oh, u16* __restrict__ ol, int n)
{
    int i = blockIdx.x * 256 + threadIdx.x;
    if (i < n) {
        float v = w[i];
        unsigned hb = f2bf_u(v);
        oh[i] = (u16)hb;
        ol[i] = (u16)f2bf_u(v - __uint_as_float(hb << 16));
    }
}

// ---------------------------------------------------------------------------
// split-bf16 MFMA GEMM (3-term): C[M,N] = A[M,K]*W[N,K]^T (+bias).
// A,W as separate hi/lo bf16 planes -> staging is pure load/store.
// 128x128 tile, BK=32, 4 waves x 64x64 quadrant.
// OUTK: 0 = fp32 out (C0), 1 = hi/lo plane out (C0=hi, C1=lo).
// ---------------------------------------------------------------------------
template <int OUTK, bool BIAS>
__global__ __launch_bounds__(256) void k_gmfma(
    const u16* __restrict__ Ahg, const u16* __restrict__ Alg, int lda,
    const u16* __restrict__ Whg, const u16* __restrict__ Wlg,
    const float* __restrict__ bias, void* __restrict__ C0, void* __restrict__ C1,
    int N, int K)
{
    __shared__ u16 Ah[128 * 40], Al[128 * 40];
    __shared__ u16 Wh[128 * 40], Wl[128 * 40];

    int tid = threadIdx.x;
    int wv = tid >> 6, ln = tid & 63;
    int wr = wv >> 1, wc = wv & 1;
    int m0 = blockIdx.x * 128, n0 = blockIdx.y * 128;
    int sr = tid >> 1, sk = (tid & 1) << 4;
    int frow = ln & 15, fk = (ln >> 4) << 3;

    f32x4 acc[4][4] = {};

    for (int k0 = 0; k0 < K; k0 += 32) {
        const u16* ah = Ahg + (size_t)(m0 + sr) * lda + k0 + sk;
        const u16* al = Alg + (size_t)(m0 + sr) * lda + k0 + sk;
        const u16* wh = Whg + (size_t)(n0 + sr) * K + k0 + sk;
        const u16* wl = Wlg + (size_t)(n0 + sr) * K + k0 + sk;
        short8 vah0 = *(const short8*)ah, vah1 = *(const short8*)(ah + 8);
        short8 val0 = *(const short8*)al, val1 = *(const short8*)(al + 8);
        short8 vwh0 = *(const short8*)wh, vwh1 = *(const short8*)(wh + 8);
        short8 vwl0 = *(const short8*)wl, vwl1 = *(const short8*)(wl + 8);

        __syncthreads();   // previous iteration's frag reads done

        *(short8*)&Ah[sr * 40 + sk]     = vah0;
        *(short8*)&Ah[sr * 40 + sk + 8] = vah1;
        *(short8*)&Al[sr * 40 + sk]     = val0;
        *(short8*)&Al[sr * 40 + sk + 8] = val1;
        *(short8*)&Wh[sr * 40 + sk]     = vwh0;
        *(short8*)&Wh[sr * 40 + sk + 8] = vwh1;
        *(short8*)&Wl[sr * 40 + sk]     = vwl0;
        *(short8*)&Wl[sr * 40 + sk + 8] = vwl1;

        __syncthreads();

        short8 afh[4], afl[4], wfh[4], wfl[4];
#pragma unroll
        for (int g = 0; g < 4; g++) {
            int ra = (wr * 64 + g * 16 + frow) * 40 + fk;
            int rw = (wc * 64 + g * 16 + frow) * 40 + fk;
            afh[g] = *(const short8*)&Ah[ra];
            afl[g] = *(const short8*)&Al[ra];
            wfh[g] = *(const short8*)&Wh[rw];
            wfl[g] = *(const short8*)&Wl[rw];
        }
#pragma unroll
        for (int mg = 0; mg < 4; mg++)
#pragma unroll
            for (int ng = 0; ng < 4; ng++) {
                acc[mg][ng] = __builtin_amdgcn_mfma_f32_16x16x32_bf16(afh[mg], wfh[ng], acc[mg][ng], 0, 0, 0);
                acc[mg][ng] = __builtin_amdgcn_mfma_f32_16x16x32_bf16(afh[mg], wfl[ng], acc[mg][ng], 0, 0, 0);
                acc[mg][ng] = __builtin_amdgcn_mfma_f32_16x16x32_bf16(afl[mg], wfh[ng], acc[mg][ng], 0, 0, 0);
            }
    }

    // C layout: col=lane&15, row=(lane>>4)*4+reg  [verified m89]
#pragma unroll
    for (int ng = 0; ng < 4; ng++) {
        int col = n0 + wc * 64 + ng * 16 + frow;
        float bv = BIAS ? bias[col] : 0.f;
#pragma unroll
        for (int mg = 0; mg < 4; mg++)
#pragma unroll
            for (int r = 0; r < 4; r++) {
                int row = m0 + wr * 64 + mg * 16 + (ln >> 4) * 4 + r;
                float v = acc[mg][ng][r] + bv;
                if (OUTK == 0) {
                    ((float*)C0)[(size_t)row * N + col] = v;
                } else {
                    unsigned hb = f2bf_u(v);
                    ((u16*)C0)[(size_t)row * N + col] = (u16)hb;
                    ((u16*)C1)[(size_t)row * N + col] =
                        (u16)f2bf_u(v - __uint_as_float(hb << 16));
                }
            }
    }
}

// ---------------------------------------------------------------------------
// xproj K-split partial GEMM: Cpart[slice][M][48] = A[:, ks..ks+128) * W^T.
// Same proven 64x64 LDS-tiled structure as the old k_gemm; grid (M/64, 4)
// = 512 blocks (full chip). Deterministic reduce in k_dbr.
// ---------------------------------------------------------------------------
__global__ __launch_bounds__(256) void k_xpart(
    const float* __restrict__ A, const float* __restrict__ W,
    float* __restrict__ Cpart, int M, int K, int kcnt)
{
    const int BM = 64, BN = 64, BK = 16;
    __shared__ float As[BK][BM];
    __shared__ float Ws[BK][BN];

    int m0   = blockIdx.x * BM;
    int kbeg = blockIdx.y * kcnt;
    int tid = threadIdx.x;
    int tx  = tid & 15, ty = tid >> 4;
    int lr  = tid >> 2;
    int lc  = (tid & 3) * 4;

    float acc[4][4] = {};

    for (int k0 = kbeg; k0 < kbeg + kcnt; k0 += BK) {
        float4 av = *(const float4*)(A + (size_t)(m0 + lr) * K + k0 + lc);
        As[lc + 0][lr] = av.x; As[lc + 1][lr] = av.y;
        As[lc + 2][lr] = av.z; As[lc + 3][lr] = av.w;
        float4 wv = make_float4(0.f, 0.f, 0.f, 0.f);
        if (lr < 48) wv = *(const float4*)(W + (size_t)lr * K + k0 + lc);
        Ws[lc + 0][lr] = wv.x; Ws[lc + 1][lr] = wv.y;
        Ws[lc + 2][lr] = wv.z; Ws[lc + 3][lr] = wv.w;
        __syncthreads();
#pragma unroll
        for (int k = 0; k < BK; k++) {
            float a[4], bv[4];
            *(float4*)a  = *(const float4*)&As[k][ty * 4];
            *(float4*)bv = *(const float4*)&Ws[k][tx * 4];
#pragma unroll
            for (int i = 0; i < 4; i++)
#pragma unroll
                for (int j = 0; j < 4; j++)
                    acc[i][j] = fmaf(a[i], bv[j], acc[i][j]);
        }
        __syncthreads();
    }

    int n = tx * 4;
    if (n < 48) {
        float* cp = Cpart + (size_t)blockIdx.y * M * 48;
#pragma unroll
        for (int i = 0; i < 4; i++) {
            float4 v = make_float4(acc[i][0], acc[i][1], acc[i][2], acc[i][3]);
            *(float4*)(cp + (size_t)(m0 + ty * 4 + i) * 48 + n) = v;
        }
    }
}

// deterministic 4-slice reduce: dbc = sum_slices Cpart
__global__ __launch_bounds__(256) void k_dbr(
    const float* __restrict__ part, float* __restrict__ dbc, int M)
{
    int i = blockIdx.x * 256 + threadIdx.x;   // over M*48
    size_t st = (size_t)M * 48;
    dbc[i] = ((part[i] + part[st + i]) + (part[2 * st + i] + part[3 * st + i]));
}

// ---------------------------------------------------------------------------
// depthwise causal conv1d (k=4) + SiLU, float4-vectorized (4 d's/thread).
// halo [3][32][512]. grid RC*512/1024 = 4096 blocks.
// ---------------------------------------------------------------------------
__global__ __launch_bounds__(256) void k_conv(
    const float* __restrict__ xz, const float* __restrict__ halo,
    const float* __restrict__ cw, const float* __restrict__ cb,
    float* __restrict__ xc, int t0)
{
    size_t i4 = ((size_t)blockIdx.x * 256 + threadIdx.x) * 4;   // over RC*512
    int d  = (int)(i4 & 511);
    int r  = (int)(i4 >> 9);
    int b  = r & 31;
    int tl = r >> 5;

    float4 w0 = *(const float4*)(cw + (d + 0) * 4);
    float4 w1 = *(const float4*)(cw + (d + 1) * 4);
    float4 w2 = *(const float4*)(cw + (d + 2) * 4);
    float4 w3 = *(const float4*)(cw + (d + 3) * 4);
    float4 acc = *(const float4*)(cb + d);

#pragma unroll
    for (int k = 0; k < 4; k++) {
        int tsl = tl - 3 + k;
        float4 v;
        if (tsl >= 0)
            v = *(const float4*)(xz + ((size_t)tsl * 32 + b) * 1024 + d);
        else if (t0 + tsl >= 0)
            v = *(const float4*)(halo + ((size_t)(tsl + 3) * 32 + b) * 512 + d);
        else
            continue;
        acc.x = fmaf((&w0.x)[k], v.x, acc.x);
        acc.y = fmaf((&w1.x)[k], v.y, acc.y);
        acc.z = fmaf((&w2.x)[k], v.z, acc.z);
        acc.w = fmaf((&w3.x)[k], v.w, acc.w);
    }
    float4 o;
    o.x = acc.x / (1.f + __expf(-acc.x));
    o.y = acc.y / (1.f + __expf(-acc.y));
    o.z = acc.z / (1.f + __expf(-acc.z));
    o.w = acc.w / (1.f + __expf(-acc.w));
    *(float4*)(xc + i4) = o;
}

__global__ __launch_bounds__(256) void k_halo(
    const float* __restrict__ xz, float* __restrict__ halo)
{
    int idx = blockIdx.x * 256 + threadIdx.x;  // over 3*32*512
    int d = idx & 511;
    int b = (idx >> 9) & 31;
    int s = idx >> 14;
    halo[idx] = xz[(((size_t)(CH - 3 + s) * 32 + b) << 10) + d];
}

// ---------------------------------------------------------------------------
// scan pass A (fused dt-proj, geometric-dA fast path): local scan, h=0.
// ---------------------------------------------------------------------------
__global__ __launch_bounds__(256) void k_scanA(
    const float* __restrict__ xc, const float* __restrict__ dbc,
    const float* __restrict__ dtw, const float* __restrict__ dtb,
    const float* __restrict__ A_log,
    float* __restrict__ hend, float* __restrict__ sumdt)
{
    int bx = blockIdx.x;
    int b    = bx >> 5;
    int half = (bx >> 4) & 1;
    int c    = bx & 15;
    int d = (half << 8) + threadIdx.x;

    float A2[DS], h[DS], wdt[DS];
#pragma unroll
    for (int s = 0; s < DS; s++) {
        A2[s] = -__expf(A_log[d * DS + s]) * LOG2E;
        h[s] = 0.f;
        wdt[s] = dtw[d * DS + s];
    }
    float dtbv = dtb[d];
    float A20 = A2[0];
    bool geo = true;
#pragma unroll
    for (int s = 0; s < DS; s++)
        geo = geo && (fabsf(A2[s] - (float)(s + 1) * A20) <=
                      1e-5f * fabsf(A2[s]) + 1e-30f);

    __shared__ float Bs[SCT][48];
    for (int f = threadIdx.x; f < SCT * 48; f += 256) {
        int tt = f / 48, jj = f - tt * 48;
        Bs[tt][jj] = dbc[((size_t)(c * SCT + tt) * 32 + b) * 48 + jj];
    }
    __syncthreads();

    float cum = 0.f;
    if (geo) {
        for (int tt = 0; tt < SCT; tt++) {
            size_t idx = ((size_t)(c * SCT + tt) * 32 + b) * DI + d;
            float s0 = dtbv;
#pragma unroll
            for (int k = 0; k < DS; k++) s0 = fmaf(Bs[tt][k], wdt[k], s0);
            float dt = (s0 > 20.f) ? s0 : log1pf(expf(s0));
            cum += dt;
            float dtx = dt * xc[idx];
            float q = exp2f(dt * A20);
            float dA = q;
#pragma unroll
            for (int s = 0; s < DS; s++) {
                h[s] = fmaf(dA, h[s], dtx * Bs[tt][16 + s]);
                dA *= q;
            }
        }
    } else {
        for (int tt = 0; tt < SCT; tt++) {
            size_t idx = ((size_t)(c * SCT + tt) * 32 + b) * DI + d;
            float s0 = dtbv;
#pragma unroll
            for (int k = 0; k < DS; k++) s0 = fmaf(Bs[tt][k], wdt[k], s0);
            float dt = (s0 > 20.f) ? s0 : log1pf(expf(s0));
            cum += dt;
            float dtx = dt * xc[idx];
#pragma unroll
            for (int s = 0; s < DS; s++) {
                float dA = exp2f(dt * A2[s]);
                h[s] = fmaf(dA, h[s], dtx * Bs[tt][16 + s]);
            }
        }
    }
    float* hp = hend + ((size_t)(c * 32 + b) * 512 + d) * DS;
#pragma unroll
    for (int s = 0; s < DS; s++) hp[s] = h[s];
    sumdt[((size_t)c * 32 + b) * 512 + d] = cum;
}

// ---------------------------------------------------------------------------
// scan pass B: carry across 16 sub-chunks; hend -> h_init, carry -> hs.
// ---------------------------------------------------------------------------
__global__ __launch_bounds__(256) void k_scanB(
    const float* __restrict__ sumdt, float* __restrict__ hend,
    const float* __restrict__ A_log, float* __restrict__ hs, int first)
{
    int id = blockIdx.x * 256 + threadIdx.x;   // 32*512*16 = 262144
    int s = id & 15;
    int d = (id >> 4) & 511;
    int b = id >> 13;
    float A2 = -__expf(A_log[d * DS + s]) * LOG2E;
    size_t hsi = ((size_t)(b << 9) + d) * DS + s;
    float hin = first ? 0.f : hs[hsi];
    for (int c = 0; c < NSC; c++) {
        size_t hi = ((size_t)(c * 32 + b) * 512 + d) * DS + s;
        float he = hend[hi];
        float sd = sumdt[((size_t)c * 32 + b) * 512 + d];
        hend[hi] = hin;
        hin = fmaf(exp2f(A2 * sd), hin, he);
    }
    hs[hsi] = hin;
}

// ---------------------------------------------------------------------------
// scan pass C (fused dt-proj, geometric-dA fast path): rescan seeded with
// h_init, y inline, epilogue (y+x*D)*silu(z) -> bf16 hi/lo planes yh/yl.
// ---------------------------------------------------------------------------
__global__ __launch_bounds__(256) void k_scanC(
    const float* __restrict__ xc, const float* __restrict__ dbc,
    const float* __restrict__ dtw, const float* __restrict__ dtb,
    const float* __restrict__ xz,
    const float* __restrict__ A_log, const float* __restrict__ Dp,
    const float* __restrict__ hinit,
    u16* __restrict__ yh, u16* __restrict__ yl)
{
    int bx = blockIdx.x;
    int b    = bx >> 5;
    int half = (bx >> 4) & 1;
    int c    = bx & 15;
    int d = (half << 8) + threadIdx.x;

    float A2[DS], h[DS], wdt[DS];
    const float* hp = hinit + ((size_t)(c * 32 + b) * 512 + d) * DS;
#pragma unroll
    for (int s = 0; s < DS; s++) {
        A2[s] = -__expf(A_log[d * DS + s]) * LOG2E;
        h[s] = hp[s];
        wdt[s] = dtw[d * DS + s];
    }
    float dtbv = dtb[d];
    float Dv = Dp[d];
    float A20 = A2[0];
    bool geo = true;
#pragma unroll
    for (int s = 0; s < DS; s++)
        geo = geo && (fabsf(A2[s] - (float)(s + 1) * A20) <=
                      1e-5f * fabsf(A2[s]) + 1e-30f);

    __shared__ float BC[SCT][48];
    for (int f = threadIdx.x; f < SCT * 48; f += 256) {
        int tt = f / 48, jj = f - tt * 48;
        BC[tt][jj] = dbc[((size_t)(c * SCT + tt) * 32 + b) * 48 + jj];
    }
    __syncthreads();

    if (geo) {
        for (int tt = 0; tt < SCT; tt++) {
            size_t row = (size_t)(c * SCT + tt) * 32 + b;
            size_t idx = row * DI + d;
            float s0 = dtbv;
#pragma unroll
            for (int k = 0; k < DS; k++) s0 = fmaf(BC[tt][k], wdt[k], s0);
            float dt = (s0 > 20.f) ? s0 : log1pf(expf(s0));
            float x  = xc[idx];
            float z  = xz[(row << 10) + 512 + d];
            float dtx = dt * x;
            float y = 0.f;
            float q = exp2f(dt * A20);
            float dA = q;
#pragma unroll
            for (int s = 0; s < DS; s++) {
                h[s] = fmaf(dA, h[s], dtx * BC[tt][16 + s]);
                y = fmaf(h[s], BC[tt][32 + s], y);
                dA *= q;
            }
            float yact = (y + x * Dv) * (z / (1.f + __expf(-z)));
            unsigned hb = f2bf_u(yact);
            yh[row * DI + d] = (u16)hb;
            yl[row * DI + d] = (u16)f2bf_u(yact - __uint_as_float(hb << 16));
        }
    } else {
        for (int tt = 0; tt < SCT; tt++) {
            size_t row = (size_t)(c * SCT + tt) * 32 + b;
            size_t idx = row * DI + d;
            float s0 = dtbv;
#pragma unroll
            for (int k = 0; k < DS; k++) s0 = fmaf(BC[tt][k], wdt[k], s0);
            float dt = (s0 > 20.f) ? s0 : log1pf(expf(s0));
            float x  = xc[idx];
            float z  = xz[(row << 10) + 512 + d];
            float dtx = dt * x;
            float y = 0.f;
#pragma unroll
            for (int s = 0; s < DS; s++) {
                float dA = exp2f(dt * A2[s]);
                h[s] = fmaf(dA, h[s], dtx * BC[tt][16 + s]);
                y = fmaf(h[s], BC[tt][32 + s], y);
            }
            float yact = (y + x * Dv) * (z / (1.f + __expf(-z)));
            unsigned hb = f2bf_u(yact);
            yh[row * DI + d] = (u16)hb;
            yl[row * DI + d] = (u16)f2bf_u(yact - __uint_as_float(hb << 16));
        }
    }
}

// ---------------------------------------------------------------------------
// mean accumulate / head
// ---------------------------------------------------------------------------
__global__ __launch_bounds__(256) void k_meanacc(
    const float* __restrict__ mo, float* __restrict__ meanacc, int first)
{
    int b = blockIdx.x;
    int m = threadIdx.x;
    float s = 0.f;
    for (int tl = 0; tl < CH; tl++)
        s += mo[((size_t)tl * 32 + b) * 256 + m];
    if (first) meanacc[b * 256 + m] = s;
    else       meanacc[b * 256 + m] += s;
}

__global__ __launch_bounds__(128) void k_head(
    const float* __restrict__ meanacc, const float* __restrict__ xst,
    const float* __restrict__ h1w, const float* __restrict__ h1b,
    const float* __restrict__ h2w, const float* __restrict__ h2b,
    float* __restrict__ out)
{
    int b = blockIdx.x;
    int j = threadIdx.x;
    const float* wr = h1w + j * 261;
    const float* mr = meanacc + b * 256;
    float s = h1b[j];
    for (int k = 0; k < 256; k++) s = fmaf(mr[k] * (1.f / 1024.f), wr[k], s);
    for (int k = 0; k < 5; k++) s = fmaf(xst[b * 5 + k], wr[256 + k], s);
    float e = (s > 0.f) ? s : expm1f(s);

    __shared__ float sb[128];
    sb[j] = e * h2w[j];
    __syncthreads();
    for (int o = 64; o > 0; o >>= 1) {
        if (j < o) sb[j] += sb[j + o];
        __syncthreads();
    }
    if (j == 0) out[b] = sb[0] + h2b[0];
}

// ---------------------------------------------------------------------------
// host side
// ---------------------------------------------------------------------------
static void run_mamba_chunk(hipStream_t stream,
                            const u16* x1h, const u16* x1l, void* const* P,
                            const u16* wih, const u16* wil,
                            const u16* woh, const u16* wol, int out_pairs,
                            float* xzc, float* xcc, float* dbcc, float* xpartb,
                            float* moc, u16* moh, u16* mol,
                            u16* yh, u16* yl,
                            float* hendb, float* sumdtb, float* halo,
                            float* hstate, int t0)
{
    const float* cw     = (const float*)P[1];
    const float* cb     = (const float*)P[2];
    const float* xpw    = (const float*)P[3];
    const float* dtw    = (const float*)P[4];
    const float* dtbias = (const float*)P[5];
    const float* Alog   = (const float*)P[6];
    const float* Dp     = (const float*)P[7];
    int first = (t0 == 0);

    k_gmfma<0, false><<<dim3(RC / 128, 1024 / 128), 256, 0, stream>>>(
        x1h, x1l, 256, wih, wil, nullptr, xzc, nullptr, 1024, 256);
    k_conv<<<RC * DI / 1024, 256, 0, stream>>>(xzc, halo, cw, cb, xcc, t0);
    k_halo<<<3 * 32 * 512 / 256, 256, 0, stream>>>(xzc, halo);
    k_xpart<<<dim3(RC / 64, 4), 256, 0, stream>>>(xcc, xpw, xpartb, RC, 512, 128);
    k_dbr<<<RC * 48 / 256, 256, 0, stream>>>(xpartb, dbcc, RC);
    k_scanA<<<32 * 2 * NSC, 256, 0, stream>>>(xcc, dbcc, dtw, dtbias, Alog,
                                              hendb, sumdtb);
    k_scanB<<<32 * 512 * DS / 256, 256, 0, stream>>>(sumdtb, hendb, Alog, hstate, first);
    k_scanC<<<32 * 2 * NSC, 256, 0, stream>>>(xcc, dbcc, dtw, dtbias, xzc,
                                              Alog, Dp, hendb, yh, yl);
    if (out_pairs)
        k_gmfma<1, false><<<dim3(RC / 128, 256 / 128), 256, 0, stream>>>(
            yh, yl, 512, woh, wol, nullptr, moh, mol, 256, 512);
    else
        k_gmfma<0, false><<<dim3(RC / 128, 256 / 128), 256, 0, stream>>>(
            yh, yl, 512, woh, wol, nullptr, moc, nullptr, 256, 512);
}

extern "C" void kernel_launch(void* const* d_in, const int* in_sizes, int n_in,
                              void* d_out, int out_size, void* d_ws, size_t ws_size,
                              hipStream_t stream)
{
    const float* xseq = (const float*)d_in[0];
    const float* xst  = (const float*)d_in[1];
    const float* p1w  = (const float*)d_in[2];
    const float* p1b  = (const float*)d_in[3];
    const float* ln1g = (const float*)d_in[4];
    const float* ln1b = (const float*)d_in[5];
    const float* p2w  = (const float*)d_in[6];
    const float* p2b  = (const float*)d_in[7];
    const float* ln2g = (const float*)d_in[8];
    const float* ln2b = (const float*)d_in[9];
    const float* h1w  = (const float*)d_in[10];
    const float* h1b  = (const float*)d_in[11];
    const float* h2w  = (const float*)d_in[12];
    const float* h2b  = (const float*)d_in[13];

    float* ws = (float*)d_ws;
    float* xzc    = ws;                                  // RC*1024 f32
    float* xcc    = xzc  + (size_t)RC * 1024;            // RC*512
    float* dbcc   = xcc  + (size_t)RC * 512;             // RC*48
    float* moc    = dbcc + (size_t)RC * 48;              // RC*256 f32
    u16*   x1h    = (u16*)(moc + (size_t)RC * 256);      // RC*256 u16
    u16*   x1l    = x1h + (size_t)RC * 256;              // RC*256 u16
    // hend aliases [moc | x1h | x1l] = exactly NSC*32*512*DS floats;
    // all three are dead during the scan phase (liveness audited).
    float* hendb  = moc;
    float* after  = (float*)(x1l + (size_t)RC * 256);
    u16*   yh     = (u16*)after;                         // RC*512 u16
    u16*   yl     = yh + (size_t)RC * 512;               // RC*512 u16
    u16*   moh    = yl + (size_t)RC * 512;               // RC*256 u16
    u16*   mol    = moh + (size_t)RC * 256;              // RC*256 u16
    float* sumdtb = (float*)(mol + (size_t)RC * 256);    // NSC*32*512
    float* halo1  = sumdtb + NSC * 32 * 512;             // 3*32*512
    float* halo2  = halo1 + 3 * 32 * 512;
    float* hs1    = halo2 + 3 * 32 * 512;                // 32*512*16
    float* hs2    = hs1  + 32 * 512 * DS;
    float* macc   = hs2  + 32 * 512 * DS;                // 32*256
    u16*   wm1ih  = (u16*)(macc + 32 * 256);             // 1024*256 u16 each
    u16*   wm1il  = wm1ih + 262144;
    u16*   wm1oh  = wm1il + 262144;                      // 256*512 u16 each
    u16*   wm1ol  = wm1oh + 131072;
    u16*   wm2ih  = wm1ol + 131072;
    u16*   wm2il  = wm2ih + 262144;
    u16*   wm2oh  = wm2il + 262144;
    u16*   wm2ol  = wm2oh + 131072;
    u16*   wp2h   = wm2ol + 131072;                      // 256*256 u16 each
    u16*   wp2l   = wp2h + 65536;
    float* xpartb = (float*)(wp2l + 65536);              // 4*RC*48 f32
    size_t need = (size_t)((char*)(xpartb + 4 * (size_t)RC * 48) - (char*)ws);
    if (ws_size < need) return;   // tripwire: fail cleanly, don't fault

    // weight bf16 hi/lo plane conversion (once per launch)
    k_wcvt<<<262144 / 256, 256, 0, stream>>>((const float*)d_in[14], wm1ih, wm1il, 262144);
    k_wcvt<<<131072 / 256, 256, 0, stream>>>((const float*)d_in[22], wm1oh, wm1ol, 131072);
    k_wcvt<<<262144 / 256, 256, 0, stream>>>((const float*)d_in[23], wm2ih, wm2il, 262144);
    k_wcvt<<<131072 / 256, 256, 0, stream>>>((const float*)d_in[31], wm2oh, wm2ol, 131072);
    k_wcvt<<<65536 / 256, 256, 0, stream>>>(p2w, wp2h, wp2l, 65536);

    for (int c = 0; c < NCH; c++) {
        int t0 = c * CH;
        int first = (c == 0);

        k_p1_ln<<<RC, 256, 0, stream>>>(xseq, p1w, p1b, ln1g, ln1b, x1h, x1l, t0);

        // mamba 1 (params d_in[14..22]); out_proj emits hi/lo planes for p2
        run_mamba_chunk(stream, x1h, x1l, d_in + 14, wm1ih, wm1il, wm1oh, wm1ol, 1,
                        xzc, xcc, dbcc, xpartb, moc, moh, mol, yh, yl,
                        hendb, sumdtb, halo1, hs1, t0);

        // p2 + LN2
        k_gmfma<0, true><<<dim3(RC / 128, 256 / 128), 256, 0, stream>>>(
            moh, mol, 256, wp2h, wp2l, p2b, xzc, nullptr, 256, 256);
        k_ln<<<RC, 256, 0, stream>>>(xzc, ln2g, ln2b, x1h, x1l);

        // mamba 2 (params d_in[23..31]); out_proj emits f32 for meanacc
        run_mamba_chunk(stream, x1h, x1l, d_in + 23, wm2ih, wm2il, wm2oh, wm2ol, 0,
                        xzc, xcc, dbcc, xpartb, moc, moh, mol, yh, yl,
                        hendb, sumdtb, halo2, hs2, t0);

        k_meanacc<<<NB, 256, 0, stream>>>(moc, macc, first);
    }

    k_head<<<NB, 128, 0, stream>>>(macc, xst, h1w, h1b, h2w, h2b, (float*)d_out);
}

// Round 12
// 1013.668 us; speedup vs baseline: 1.9902x; 1.2520x over previous
//
#include <hip/hip_runtime.h>
#include <math.h>

#define NB 32
#define L  1024
#define CH 512                 // timesteps per chunk
#define NCH (L / CH)           // 2 chunks
#define RC (NB * CH)           // 16384 rows per chunk
#define DM 256
#define DI 512
#define DS 16
#define SCT 16                 // sub-chunk timesteps (scan)
#define NSC (CH / SCT)         // 32 sub-chunks
#define LOG2E 1.44269504f

typedef short short8 __attribute__((ext_vector_type(8)));
typedef float f32x4 __attribute__((ext_vector_type(4)));
typedef unsigned short u16;

// bf16 split helpers: x ~= hi + lo, both bf16 (rne).
__device__ inline unsigned f2bf_u(float x) {
    unsigned u = __float_as_uint(x);
    return (u + 0x7fffu + ((u >> 16) & 1u)) >> 16;
}

// Layout: per-chunk activations use (t_local, b, feat): row r = t_local*32 + b.

// ---------------------------------------------------------------------------
// p1 (K=4) + bias + LayerNorm; emits bf16 hi/lo PLANES for MFMA in_proj.
// ---------------------------------------------------------------------------
__global__ __launch_bounds__(256) void k_p1_ln(
    const float* __restrict__ xseq, const float* __restrict__ w,
    const float* __restrict__ bias, const float* __restrict__ g,
    const float* __restrict__ bb, u16* __restrict__ outh, u16* __restrict__ outl,
    int t0)
{
    int r  = blockIdx.x;
    int b  = r & 31;
    int tl = r >> 5;
    int m  = threadIdx.x;
    const float* xr = xseq + ((size_t)b * L + t0 + tl) * 4;
    float x0 = xr[0], x1 = xr[1], x2 = xr[2], x3 = xr[3];
    const float* wr = w + m * 4;
    float v = bias[m] + x0 * wr[0] + x1 * wr[1] + x2 * wr[2] + x3 * wr[3];

    __shared__ float s1[4], s2[4];
    float a = v, bq = v * v;
    for (int o = 32; o > 0; o >>= 1) { a += __shfl_down(a, o); bq += __shfl_down(bq, o); }
    int wid = m >> 6, lane = m & 63;
    if (lane == 0) { s1[wid] = a; s2[wid] = bq; }
    __syncthreads();
    if (m == 0) {
        s1[0] = s1[0] + s1[1] + s1[2] + s1[3];
        s2[0] = s2[0] + s2[1] + s2[2] + s2[3];
    }
    __syncthreads();
    float mu  = s1[0] * (1.f / 256.f);
    float var = s2[0] * (1.f / 256.f) - mu * mu;
    float o2 = (v - mu) * rsqrtf(var + 1e-5f) * g[m] + bb[m];
    unsigned hb = f2bf_u(o2);
    outh[(size_t)r * 256 + m] = (u16)hb;
    outl[(size_t)r * 256 + m] = (u16)f2bf_u(o2 - __uint_as_float(hb << 16));
}

// ---------------------------------------------------------------------------
// LayerNorm over 256; fp32 in, bf16 hi/lo planes out.
// ---------------------------------------------------------------------------
__global__ __launch_bounds__(256) void k_ln(
    const float* __restrict__ in, const float* __restrict__ g,
    const float* __restrict__ bb, u16* __restrict__ outh, u16* __restrict__ outl)
{
    int r = blockIdx.x;
    int m = threadIdx.x;
    float v = in[(size_t)r * 256 + m];

    __shared__ float s1[4], s2[4];
    float a = v, bq = v * v;
    for (int o = 32; o > 0; o >>= 1) { a += __shfl_down(a, o); bq += __shfl_down(bq, o); }
    int wid = m >> 6, lane = m & 63;
    if (lane == 0) { s1[wid] = a; s2[wid] = bq; }
    __syncthreads();
    if (m == 0) {
        s1[0] = s1[0] + s1[1] + s1[2] + s1[3];
        s2[0] = s2[0] + s2[1] + s2[2] + s2[3];
    }
    __syncthreads();
    float mu  = s1[0] * (1.f / 256.f);
    float var = s2[0] * (1.f / 256.f) - mu * mu;
    float o2 = (v - mu) * rsqrtf(var + 1e-5f) * g[m] + bb[m];
    unsigned hb = f2bf_u(o2);
    outh[(size_t)r * 256 + m] = (u16)hb;
    outl[(size_t)r * 256 + m] = (u16)f2bf_u(o2 - __uint_as_float(hb << 16));
}

__global__ __launch_bounds__(256) void k_wcvt(
    const float* __restrict__ w, u16* __restrict__ oh, u16* __restrict__ ol, int n)
{
    int i = blockIdx.x * 256 + threadIdx.x;
    if (i < n) {
        float v = w[i];
        unsigned hb = f2bf_u(v);
        oh[i] = (u16)hb;
        ol[i] = (u16)f2bf_u(v - __uint_as_float(hb << 16));
    }
}

// ---------------------------------------------------------------------------
// split-bf16 MFMA GEMM (3-term): C[M,N] = A[M,K]*W[N,K]^T (+bias).
// A,W as separate hi/lo bf16 planes -> staging is pure load/store.
// 128x128 tile, BK=32, 4 waves x 64x64 quadrant.
// OUTK: 0 = fp32 out (C0), 1 = hi/lo plane out (C0=hi, C1=lo).
// ---------------------------------------------------------------------------
template <int OUTK, bool BIAS>
__global__ __launch_bounds__(256) void k_gmfma(
    const u16* __restrict__ Ahg, const u16* __restrict__ Alg, int lda,
    const u16* __restrict__ Whg, const u16* __restrict__ Wlg,
    const float* __restrict__ bias, void* __restrict__ C0, void* __restrict__ C1,
    int N, int K)
{
    __shared__ u16 Ah[128 * 40], Al[128 * 40];
    __shared__ u16 Wh[128 * 40], Wl[128 * 40];

    int tid = threadIdx.x;
    int wv = tid >> 6, ln = tid & 63;
    int wr = wv >> 1, wc = wv & 1;
    int m0 = blockIdx.x * 128, n0 = blockIdx.y * 128;
    int sr = tid >> 1, sk = (tid & 1) << 4;
    int frow = ln & 15, fk = (ln >> 4) << 3;

    f32x4 acc[4][4] = {};

    for (int k0 = 0; k0 < K; k0 += 32) {
        const u16* ah = Ahg + (size_t)(m0 + sr) * lda + k0 + sk;
        const u16* al = Alg + (size_t)(m0 + sr) * lda + k0 + sk;
        const u16* wh = Whg + (size_t)(n0 + sr) * K + k0 + sk;
        const u16* wl = Wlg + (size_t)(n0 + sr) * K + k0 + sk;
        short8 vah0 = *(const short8*)ah, vah1 = *(const short8*)(ah + 8);
        short8 val0 = *(const short8*)al, val1 = *(const short8*)(al + 8);
        short8 vwh0 = *(const short8*)wh, vwh1 = *(const short8*)(wh + 8);
        short8 vwl0 = *(const short8*)wl, vwl1 = *(const short8*)(wl + 8);

        __syncthreads();   // previous iteration's frag reads done

        *(short8*)&Ah[sr * 40 + sk]     = vah0;
        *(short8*)&Ah[sr * 40 + sk + 8] = vah1;
        *(short8*)&Al[sr * 40 + sk]     = val0;
        *(short8*)&Al[sr * 40 + sk + 8] = val1;
        *(short8*)&Wh[sr * 40 + sk]     = vwh0;
        *(short8*)&Wh[sr * 40 + sk + 8] = vwh1;
        *(short8*)&Wl[sr * 40 + sk]     = vwl0;
        *(short8*)&Wl[sr * 40 + sk + 8] = vwl1;

        __syncthreads();

        short8 afh[4], afl[4], wfh[4], wfl[4];
#pragma unroll
        for (int g = 0; g < 4; g++) {
            int ra = (wr * 64 + g * 16 + frow) * 40 + fk;
            int rw = (wc * 64 + g * 16 + frow) * 40 + fk;
            afh[g] = *(const short8*)&Ah[ra];
            afl[g] = *(const short8*)&Al[ra];
            wfh[g] = *(const short8*)&Wh[rw];
            wfl[g] = *(const short8*)&Wl[rw];
        }
#pragma unroll
        for (int mg = 0; mg < 4; mg++)
#pragma unroll
            for (int ng = 0; ng < 4; ng++) {
                acc[mg][ng] = __builtin_amdgcn_mfma_f32_16x16x32_bf16(afh[mg], wfh[ng], acc[mg][ng], 0, 0, 0);
                acc[mg][ng] = __builtin_amdgcn_mfma_f32_16x16x32_bf16(afh[mg], wfl[ng], acc[mg][ng], 0, 0, 0);
                acc[mg][ng] = __builtin_amdgcn_mfma_f32_16x16x32_bf16(afl[mg], wfh[ng], acc[mg][ng], 0, 0, 0);
            }
    }

    // C layout: col=lane&15, row=(lane>>4)*4+reg  [verified m89]
#pragma unroll
    for (int ng = 0; ng < 4; ng++) {
        int col = n0 + wc * 64 + ng * 16 + frow;
        float bv = BIAS ? bias[col] : 0.f;
#pragma unroll
        for (int mg = 0; mg < 4; mg++)
#pragma unroll
            for (int r = 0; r < 4; r++) {
                int row = m0 + wr * 64 + mg * 16 + (ln >> 4) * 4 + r;
                float v = acc[mg][ng][r] + bv;
                if (OUTK == 0) {
                    ((float*)C0)[(size_t)row * N + col] = v;
                } else {
                    unsigned hb = f2bf_u(v);
                    ((u16*)C0)[(size_t)row * N + col] = (u16)hb;
                    ((u16*)C1)[(size_t)row * N + col] =
                        (u16)f2bf_u(v - __uint_as_float(hb << 16));
                }
            }
    }
}

// ---------------------------------------------------------------------------
// xproj K-split partial GEMM: Cpart[slice][M][48] = A[:, ks..ks+128) * W^T.
// grid (M/64, 4). Deterministic reduce in k_dbr.
// ---------------------------------------------------------------------------
__global__ __launch_bounds__(256) void k_xpart(
    const float* __restrict__ A, const float* __restrict__ W,
    float* __restrict__ Cpart, int M, int K, int kcnt)
{
    const int BM = 64, BK = 16;
    __shared__ float As[BK][BM];
    __shared__ float Ws[BK][64];

    int m0   = blockIdx.x * BM;
    int kbeg = blockIdx.y * kcnt;
    int tid = threadIdx.x;
    int tx  = tid & 15, ty = tid >> 4;
    int lr  = tid >> 2;
    int lc  = (tid & 3) * 4;

    float acc[4][4] = {};

    for (int k0 = kbeg; k0 < kbeg + kcnt; k0 += BK) {
        float4 av = *(const float4*)(A + (size_t)(m0 + lr) * K + k0 + lc);
        As[lc + 0][lr] = av.x; As[lc + 1][lr] = av.y;
        As[lc + 2][lr] = av.z; As[lc + 3][lr] = av.w;
        float4 wv = make_float4(0.f, 0.f, 0.f, 0.f);
        if (lr < 48) wv = *(const float4*)(W + (size_t)lr * K + k0 + lc);
        Ws[lc + 0][lr] = wv.x; Ws[lc + 1][lr] = wv.y;
        Ws[lc + 2][lr] = wv.z; Ws[lc + 3][lr] = wv.w;
        __syncthreads();
#pragma unroll
        for (int k = 0; k < BK; k++) {
            float a[4], bv[4];
            *(float4*)a  = *(const float4*)&As[k][ty * 4];
            *(float4*)bv = *(const float4*)&Ws[k][tx * 4];
#pragma unroll
            for (int i = 0; i < 4; i++)
#pragma unroll
                for (int j = 0; j < 4; j++)
                    acc[i][j] = fmaf(a[i], bv[j], acc[i][j]);
        }
        __syncthreads();
    }

    int n = tx * 4;
    if (n < 48) {
        float* cp = Cpart + (size_t)blockIdx.y * M * 48;
#pragma unroll
        for (int i = 0; i < 4; i++) {
            float4 v = make_float4(acc[i][0], acc[i][1], acc[i][2], acc[i][3]);
            *(float4*)(cp + (size_t)(m0 + ty * 4 + i) * 48 + n) = v;
        }
    }
}

// deterministic 4-slice reduce: dbc = sum_slices Cpart
__global__ __launch_bounds__(256) void k_dbr(
    const float* __restrict__ part, float* __restrict__ dbc, int M)
{
    int i = blockIdx.x * 256 + threadIdx.x;   // over M*48
    size_t st = (size_t)M * 48;
    dbc[i] = ((part[i] + part[st + i]) + (part[2 * st + i] + part[3 * st + i]));
}

// ---------------------------------------------------------------------------
// depthwise causal conv1d (k=4) + SiLU, float4-vectorized (4 d's/thread).
// halo [3][32][512]. grid RC*512/1024 blocks.
// ---------------------------------------------------------------------------
__global__ __launch_bounds__(256) void k_conv(
    const float* __restrict__ xz, const float* __restrict__ halo,
    const float* __restrict__ cw, const float* __restrict__ cb,
    float* __restrict__ xc, int t0)
{
    size_t i4 = ((size_t)blockIdx.x * 256 + threadIdx.x) * 4;   // over RC*512
    int d  = (int)(i4 & 511);
    int r  = (int)(i4 >> 9);
    int b  = r & 31;
    int tl = r >> 5;

    float4 w0 = *(const float4*)(cw + (d + 0) * 4);
    float4 w1 = *(const float4*)(cw + (d + 1) * 4);
    float4 w2 = *(const float4*)(cw + (d + 2) * 4);
    float4 w3 = *(const float4*)(cw + (d + 3) * 4);
    float4 acc = *(const float4*)(cb + d);

#pragma unroll
    for (int k = 0; k < 4; k++) {
        int tsl = tl - 3 + k;
        float4 v;
        if (tsl >= 0)
            v = *(const float4*)(xz + ((size_t)tsl * 32 + b) * 1024 + d);
        else if (t0 + tsl >= 0)
            v = *(const float4*)(halo + ((size_t)(tsl + 3) * 32 + b) * 512 + d);
        else
            continue;
        acc.x = fmaf((&w0.x)[k], v.x, acc.x);
        acc.y = fmaf((&w1.x)[k], v.y, acc.y);
        acc.z = fmaf((&w2.x)[k], v.z, acc.z);
        acc.w = fmaf((&w3.x)[k], v.w, acc.w);
    }
    float4 o;
    o.x = acc.x / (1.f + __expf(-acc.x));
    o.y = acc.y / (1.f + __expf(-acc.y));
    o.z = acc.z / (1.f + __expf(-acc.z));
    o.w = acc.w / (1.f + __expf(-acc.w));
    *(float4*)(xc + i4) = o;
}

__global__ __launch_bounds__(256) void k_halo(
    const float* __restrict__ xz, float* __restrict__ halo)
{
    int idx = blockIdx.x * 256 + threadIdx.x;  // over 3*32*512
    int d = idx & 511;
    int b = (idx >> 9) & 31;
    int s = idx >> 14;
    halo[idx] = xz[(((size_t)(CH - 3 + s) * 32 + b) << 10) + d];
}

// ---------------------------------------------------------------------------
// scan pass A (fused dt-proj, geometric-dA fast path): local scan, h=0.
// grid: b(32) x half(2) x subchunk(32) = 2048 blocks.
// ---------------------------------------------------------------------------
__global__ __launch_bounds__(256) void k_scanA(
    const float* __restrict__ xc, const float* __restrict__ dbc,
    const float* __restrict__ dtw, const float* __restrict__ dtb,
    const float* __restrict__ A_log,
    float* __restrict__ hend, float* __restrict__ sumdt)
{
    int bx = blockIdx.x;
    int b    = bx >> 6;
    int half = (bx >> 5) & 1;
    int c    = bx & 31;
    int d = (half << 8) + threadIdx.x;

    float A2[DS], h[DS], wdt[DS];
#pragma unroll
    for (int s = 0; s < DS; s++) {
        A2[s] = -__expf(A_log[d * DS + s]) * LOG2E;
        h[s] = 0.f;
        wdt[s] = dtw[d * DS + s];
    }
    float dtbv = dtb[d];
    float A20 = A2[0];
    bool geo = true;
#pragma unroll
    for (int s = 0; s < DS; s++)
        geo = geo && (fabsf(A2[s] - (float)(s + 1) * A20) <=
                      1e-5f * fabsf(A2[s]) + 1e-30f);

    __shared__ float Bs[SCT][48];
    for (int f = threadIdx.x; f < SCT * 48; f += 256) {
        int tt = f / 48, jj = f - tt * 48;
        Bs[tt][jj] = dbc[((size_t)(c * SCT + tt) * 32 + b) * 48 + jj];
    }
    __syncthreads();

    float cum = 0.f;
    if (geo) {
        for (int tt = 0; tt < SCT; tt++) {
            size_t idx = ((size_t)(c * SCT + tt) * 32 + b) * DI + d;
            float s0 = dtbv;
#pragma unroll
            for (int k = 0; k < DS; k++) s0 = fmaf(Bs[tt][k], wdt[k], s0);
            float dt = (s0 > 20.f) ? s0 : log1pf(expf(s0));
            cum += dt;
            float dtx = dt * xc[idx];
            float q = exp2f(dt * A20);
            float dA = q;
#pragma unroll
            for (int s = 0; s < DS; s++) {
                h[s] = fmaf(dA, h[s], dtx * Bs[tt][16 + s]);
                dA *= q;
            }
        }
    } else {
        for (int tt = 0; tt < SCT; tt++) {
            size_t idx = ((size_t)(c * SCT + tt) * 32 + b) * DI + d;
            float s0 = dtbv;
#pragma unroll
            for (int k = 0; k < DS; k++) s0 = fmaf(Bs[tt][k], wdt[k], s0);
            float dt = (s0 > 20.f) ? s0 : log1pf(expf(s0));
            cum += dt;
            float dtx = dt * xc[idx];
#pragma unroll
            for (int s = 0; s < DS; s++) {
                float dA = exp2f(dt * A2[s]);
                h[s] = fmaf(dA, h[s], dtx * Bs[tt][16 + s]);
            }
        }
    }
    float* hp = hend + ((size_t)(c * 32 + b) * 512 + d) * DS;
#pragma unroll
    for (int s = 0; s < DS; s++) hp[s] = h[s];
    sumdt[((size_t)c * 32 + b) * 512 + d] = cum;
}

// ---------------------------------------------------------------------------
// scan pass B: carry across 32 sub-chunks; hend -> h_init, carry -> hs.
// ---------------------------------------------------------------------------
__global__ __launch_bounds__(256) void k_scanB(
    const float* __restrict__ sumdt, float* __restrict__ hend,
    const float* __restrict__ A_log, float* __restrict__ hs, int first)
{
    int id = blockIdx.x * 256 + threadIdx.x;   // 32*512*16 = 262144
    int s = id & 15;
    int d = (id >> 4) & 511;
    int b = id >> 13;
    float A2 = -__expf(A_log[d * DS + s]) * LOG2E;
    size_t hsi = ((size_t)(b << 9) + d) * DS + s;
    float hin = first ? 0.f : hs[hsi];
    for (int c = 0; c < NSC; c++) {
        size_t hi = ((size_t)(c * 32 + b) * 512 + d) * DS + s;
        float he = hend[hi];
        float sd = sumdt[((size_t)c * 32 + b) * 512 + d];
        hend[hi] = hin;
        hin = fmaf(exp2f(A2 * sd), hin, he);
    }
    hs[hsi] = hin;
}

// ---------------------------------------------------------------------------
// scan pass C (fused dt-proj, geometric-dA fast path): rescan seeded with
// h_init, y inline, epilogue (y+x*D)*silu(z) -> bf16 hi/lo planes yh/yl.
// grid 2048 blocks.
// ---------------------------------------------------------------------------
__global__ __launch_bounds__(256) void k_scanC(
    const float* __restrict__ xc, const float* __restrict__ dbc,
    const float* __restrict__ dtw, const float* __restrict__ dtb,
    const float* __restrict__ xz,
    const float* __restrict__ A_log, const float* __restrict__ Dp,
    const float* __restrict__ hinit,
    u16* __restrict__ yh, u16* __restrict__ yl)
{
    int bx = blockIdx.x;
    int b    = bx >> 6;
    int half = (bx >> 5) & 1;
    int c    = bx & 31;
    int d = (half << 8) + threadIdx.x;

    float A2[DS], h[DS], wdt[DS];
    const float* hp = hinit + ((size_t)(c * 32 + b) * 512 + d) * DS;
#pragma unroll
    for (int s = 0; s < DS; s++) {
        A2[s] = -__expf(A_log[d * DS + s]) * LOG2E;
        h[s] = hp[s];
        wdt[s] = dtw[d * DS + s];
    }
    float dtbv = dtb[d];
    float Dv = Dp[d];
    float A20 = A2[0];
    bool geo = true;
#pragma unroll
    for (int s = 0; s < DS; s++)
        geo = geo && (fabsf(A2[s] - (float)(s + 1) * A20) <=
                      1e-5f * fabsf(A2[s]) + 1e-30f);

    __shared__ float BC[SCT][48];
    for (int f = threadIdx.x; f < SCT * 48; f += 256) {
        int tt = f / 48, jj = f - tt * 48;
        BC[tt][jj] = dbc[((size_t)(c * SCT + tt) * 32 + b) * 48 + jj];
    }
    __syncthreads();

    if (geo) {
        for (int tt = 0; tt < SCT; tt++) {
            size_t row = (size_t)(c * SCT + tt) * 32 + b;
            size_t idx = row * DI + d;
            float s0 = dtbv;
#pragma unroll
            for (int k = 0; k < DS; k++) s0 = fmaf(BC[tt][k], wdt[k], s0);
            float dt = (s0 > 20.f) ? s0 : log1pf(expf(s0));
            float x  = xc[idx];
            float z  = xz[(row << 10) + 512 + d];
            float dtx = dt * x;
            float y = 0.f;
            float q = exp2f(dt * A20);
            float dA = q;
#pragma unroll
            for (int s = 0; s < DS; s++) {
                h[s] = fmaf(dA, h[s], dtx * BC[tt][16 + s]);
                y = fmaf(h[s], BC[tt][32 + s], y);
                dA *= q;
            }
            float yact = (y + x * Dv) * (z / (1.f + __expf(-z)));
            unsigned hb = f2bf_u(yact);
            yh[row * DI + d] = (u16)hb;
            yl[row * DI + d] = (u16)f2bf_u(yact - __uint_as_float(hb << 16));
        }
    } else {
        for (int tt = 0; tt < SCT; tt++) {
            size_t row = (size_t)(c * SCT + tt) * 32 + b;
            size_t idx = row * DI + d;
            float s0 = dtbv;
#pragma unroll
            for (int k = 0; k < DS; k++) s0 = fmaf(BC[tt][k], wdt[k], s0);
            float dt = (s0 > 20.f) ? s0 : log1pf(expf(s0));
            float x  = xc[idx];
            float z  = xz[(row << 10) + 512 + d];
            float dtx = dt * x;
            float y = 0.f;
#pragma unroll
            for (int s = 0; s < DS; s++) {
                float dA = exp2f(dt * A2[s]);
                h[s] = fmaf(dA, h[s], dtx * BC[tt][16 + s]);
                y = fmaf(h[s], BC[tt][32 + s], y);
            }
            float yact = (y + x * Dv) * (z / (1.f + __expf(-z)));
            unsigned hb = f2bf_u(yact);
            yh[row * DI + d] = (u16)hb;
            yl[row * DI + d] = (u16)f2bf_u(yact - __uint_as_float(hb << 16));
        }
    }
}

// ---------------------------------------------------------------------------
// mean accumulate (partial over 8 tl-slices) / head (sums 8 partials)
// ---------------------------------------------------------------------------
__global__ __launch_bounds__(256) void k_meanacc(
    const float* __restrict__ mo, float* __restrict__ macc, int first)
{
    int b = blockIdx.x, g = blockIdx.y;
    int m = threadIdx.x;
    float s = 0.f;
    const int TLP = CH / 8;
    for (int t = 0; t < TLP; t++) {
        int tl = g * TLP + t;
        s += mo[((size_t)tl * 32 + b) * 256 + m];
    }
    int i = (b * 8 + g) * 256 + m;
    if (first) macc[i] = s;
    else       macc[i] += s;
}

__global__ __launch_bounds__(128) void k_head(
    const float* __restrict__ macc, const float* __restrict__ xst,
    const float* __restrict__ h1w, const float* __restrict__ h1b,
    const float* __restrict__ h2w, const float* __restrict__ h2b,
    float* __restrict__ out)
{
    int b = blockIdx.x;
    int j = threadIdx.x;
    const float* wr = h1w + j * 261;
    const float* mr = macc + (size_t)b * 8 * 256;
    float s = h1b[j];
    for (int k = 0; k < 256; k++) {
        float mv = 0.f;
#pragma unroll
        for (int g = 0; g < 8; g++) mv += mr[g * 256 + k];
        s = fmaf(mv * (1.f / 1024.f), wr[k], s);
    }
    for (int k = 0; k < 5; k++) s = fmaf(xst[b * 5 + k], wr[256 + k], s);
    float e = (s > 0.f) ? s : expm1f(s);

    __shared__ float sb[128];
    sb[j] = e * h2w[j];
    __syncthreads();
    for (int o = 64; o > 0; o >>= 1) {
        if (j < o) sb[j] += sb[j + o];
        __syncthreads();
    }
    if (j == 0) out[b] = sb[0] + h2b[0];
}

// ---------------------------------------------------------------------------
// host side
// ---------------------------------------------------------------------------
static void run_mamba_chunk(hipStream_t stream,
                            const u16* x1h, const u16* x1l, void* const* P,
                            const u16* wih, const u16* wil,
                            const u16* woh, const u16* wol, int out_pairs,
                            float* xzc, float* xcc, float* dbcc, float* xpartb,
                            float* moc, u16* moh, u16* mol,
                            u16* yh, u16* yl,
                            float* hendb, float* sumdtb, float* halo,
                            float* hstate, int t0)
{
    const float* cw     = (const float*)P[1];
    const float* cb     = (const float*)P[2];
    const float* xpw    = (const float*)P[3];
    const float* dtw    = (const float*)P[4];
    const float* dtbias = (const float*)P[5];
    const float* Alog   = (const float*)P[6];
    const float* Dp     = (const float*)P[7];
    int first = (t0 == 0);

    k_gmfma<0, false><<<dim3(RC / 128, 1024 / 128), 256, 0, stream>>>(
        x1h, x1l, 256, wih, wil, nullptr, xzc, nullptr, 1024, 256);
    k_conv<<<RC * DI / 1024, 256, 0, stream>>>(xzc, halo, cw, cb, xcc, t0);
    k_halo<<<3 * 32 * 512 / 256, 256, 0, stream>>>(xzc, halo);
    k_xpart<<<dim3(RC / 64, 4), 256, 0, stream>>>(xcc, xpw, xpartb, RC, 512, 128);
    k_dbr<<<RC * 48 / 256, 256, 0, stream>>>(xpartb, dbcc, RC);
    k_scanA<<<32 * 2 * NSC, 256, 0, stream>>>(xcc, dbcc, dtw, dtbias, Alog,
                                              hendb, sumdtb);
    k_scanB<<<32 * 512 * DS / 256, 256, 0, stream>>>(sumdtb, hendb, Alog, hstate, first);
    k_scanC<<<32 * 2 * NSC, 256, 0, stream>>>(xcc, dbcc, dtw, dtbias, xzc,
                                              Alog, Dp, hendb, yh, yl);
    if (out_pairs)
        k_gmfma<1, false><<<dim3(RC / 128, 256 / 128), 256, 0, stream>>>(
            yh, yl, 512, woh, wol, nullptr, moh, mol, 256, 512);
    else
        k_gmfma<0, false><<<dim3(RC / 128, 256 / 128), 256, 0, stream>>>(
            yh, yl, 512, woh, wol, nullptr, moc, nullptr, 256, 512);
}

extern "C" void kernel_launch(void* const* d_in, const int* in_sizes, int n_in,
                              void* d_out, int out_size, void* d_ws, size_t ws_size,
                              hipStream_t stream)
{
    const float* xseq = (const float*)d_in[0];
    const float* xst  = (const float*)d_in[1];
    const float* p1w  = (const float*)d_in[2];
    const float* p1b  = (const float*)d_in[3];
    const float* ln1g = (const float*)d_in[4];
    const float* ln1b = (const float*)d_in[5];
    const float* p2w  = (const float*)d_in[6];
    const float* p2b  = (const float*)d_in[7];
    const float* ln2g = (const float*)d_in[8];
    const float* ln2b = (const float*)d_in[9];
    const float* h1w  = (const float*)d_in[10];
    const float* h1b  = (const float*)d_in[11];
    const float* h2w  = (const float*)d_in[12];
    const float* h2b  = (const float*)d_in[13];

    float* ws = (float*)d_ws;
    float* xzc    = ws;                                  // RC*1024 f32
    float* xcc    = xzc  + (size_t)RC * 1024;            // RC*512
    float* dbcc   = xcc  + (size_t)RC * 512;             // RC*48
    float* moc    = dbcc + (size_t)RC * 48;              // RC*256 f32
    u16*   x1h    = (u16*)(moc + (size_t)RC * 256);      // RC*256 u16
    u16*   x1l    = x1h + (size_t)RC * 256;              // RC*256 u16
    // hend aliases [moc | x1h | x1l] = exactly NSC*32*512*DS floats;
    // all three are dead during the scan phase (liveness audited at CH=512).
    float* hendb  = moc;
    float* after  = (float*)(x1l + (size_t)RC * 256);
    u16*   yh     = (u16*)after;                         // RC*512 u16
    u16*   yl     = yh + (size_t)RC * 512;               // RC*512 u16
    u16*   moh    = yl + (size_t)RC * 512;               // RC*256 u16
    u16*   mol    = moh + (size_t)RC * 256;              // RC*256 u16
    float* sumdtb = (float*)(mol + (size_t)RC * 256);    // NSC*32*512
    float* halo1  = sumdtb + NSC * 32 * 512;             // 3*32*512
    float* halo2  = halo1 + 3 * 32 * 512;
    float* hs1    = halo2 + 3 * 32 * 512;                // 32*512*16
    float* hs2    = hs1  + 32 * 512 * DS;
    float* macc   = hs2  + 32 * 512 * DS;                // 32*8*256
    u16*   wm1ih  = (u16*)(macc + 32 * 8 * 256);         // 1024*256 u16 each
    u16*   wm1il  = wm1ih + 262144;
    u16*   wm1oh  = wm1il + 262144;                      // 256*512 u16 each
    u16*   wm1ol  = wm1oh + 131072;
    u16*   wm2ih  = wm1ol + 131072;
    u16*   wm2il  = wm2ih + 262144;
    u16*   wm2oh  = wm2il + 262144;
    u16*   wm2ol  = wm2oh + 131072;
    u16*   wp2h   = wm2ol + 131072;                      // 256*256 u16 each
    u16*   wp2l   = wp2h + 65536;
    float* xpartb = (float*)(wp2l + 65536);              // 4*RC*48 f32
    size_t need = (size_t)((char*)(xpartb + 4 * (size_t)RC * 48) - (char*)ws);
    if (ws_size < need) return;   // tripwire: fail cleanly, don't fault

    // weight bf16 hi/lo plane conversion (once per launch)
    k_wcvt<<<262144 / 256, 256, 0, stream>>>((const float*)d_in[14], wm1ih, wm1il, 262144);
    k_wcvt<<<131072 / 256, 256, 0, stream>>>((const float*)d_in[22], wm1oh, wm1ol, 131072);
    k_wcvt<<<262144 / 256, 256, 0, stream>>>((const float*)d_in[23], wm2ih, wm2il, 262144);
    k_wcvt<<<131072 / 256, 256, 0, stream>>>((const float*)d_in[31], wm2oh, wm2ol, 131072);
    k_wcvt<<<65536 / 256, 256, 0, stream>>>(p2w, wp2h, wp2l, 65536);

    for (int c = 0; c < NCH; c++) {
        int t0 = c * CH;
        int first = (c == 0);

        k_p1_ln<<<RC, 256, 0, stream>>>(xseq, p1w, p1b, ln1g, ln1b, x1h, x1l, t0);

        // mamba 1 (params d_in[14..22]); out_proj emits hi/lo planes for p2
        run_mamba_chunk(stream, x1h, x1l, d_in + 14, wm1ih, wm1il, wm1oh, wm1ol, 1,
                        xzc, xcc, dbcc, xpartb, moc, moh, mol, yh, yl,
                        hendb, sumdtb, halo1, hs1, t0);

        // p2 + LN2
        k_gmfma<0, true><<<dim3(RC / 128, 256 / 128), 256, 0, stream>>>(
            moh, mol, 256, wp2h, wp2l, p2b, xzc, nullptr, 256, 256);
        k_ln<<<RC, 256, 0, stream>>>(xzc, ln2g, ln2b, x1h, x1l);

        // mamba 2 (params d_in[23..31]); out_proj emits f32 for meanacc
        run_mamba_chunk(stream, x1h, x1l, d_in + 23, wm2ih, wm2il, wm2oh, wm2ol, 0,
                        xzc, xcc, dbcc, xpartb, moc, moh, mol, yh, yl,
                        hendb, sumdtb, halo2, hs2, t0);

        k_meanacc<<<dim3(NB, 8), 256, 0, stream>>>(moc, macc, first);
    }

    k_head<<<NB, 128, 0, stream>>>(macc, xst, h1w, h1b, h2w, h2b, (float*)d_out);
}

// Round 13
// 860.498 us; speedup vs baseline: 2.3445x; 1.1780x over previous
//
#include <hip/hip_runtime.h>
#include <math.h>

#define NB 32
#define L  1024
#define CH 512                 // timesteps per chunk
#define NCH (L / CH)           // 2 chunks
#define RC (NB * CH)           // 16384 rows per chunk
#define DM 256
#define DI 512
#define DS 16
#define SCT 16                 // sub-chunk timesteps (scan)
#define NSC (CH / SCT)         // 32 sub-chunks
#define LOG2E 1.44269504f
#define LN2   0.69314718f

typedef short short8 __attribute__((ext_vector_type(8)));
typedef float f32x4 __attribute__((ext_vector_type(4)));
typedef unsigned short u16;

// bf16 split helpers: x ~= hi + lo, both bf16 (rne).
__device__ inline unsigned f2bf_u(float x) {
    unsigned u = __float_as_uint(x);
    return (u + 0x7fffu + ((u >> 16) & 1u)) >> 16;
}

// Layout: per-chunk activations use (t_local, b, feat): row r = t_local*32 + b.

// ---------------------------------------------------------------------------
// p1 (K=4) + bias + LayerNorm; emits bf16 hi/lo PLANES for MFMA in_proj.
// ---------------------------------------------------------------------------
__global__ __launch_bounds__(256) void k_p1_ln(
    const float* __restrict__ xseq, const float* __restrict__ w,
    const float* __restrict__ bias, const float* __restrict__ g,
    const float* __restrict__ bb, u16* __restrict__ outh, u16* __restrict__ outl,
    int t0)
{
    int r  = blockIdx.x;
    int b  = r & 31;
    int tl = r >> 5;
    int m  = threadIdx.x;
    const float* xr = xseq + ((size_t)b * L + t0 + tl) * 4;
    float x0 = xr[0], x1 = xr[1], x2 = xr[2], x3 = xr[3];
    const float* wr = w + m * 4;
    float v = bias[m] + x0 * wr[0] + x1 * wr[1] + x2 * wr[2] + x3 * wr[3];

    __shared__ float s1[4], s2[4];
    float a = v, bq = v * v;
    for (int o = 32; o > 0; o >>= 1) { a += __shfl_down(a, o); bq += __shfl_down(bq, o); }
    int wid = m >> 6, lane = m & 63;
    if (lane == 0) { s1[wid] = a; s2[wid] = bq; }
    __syncthreads();
    if (m == 0) {
        s1[0] = s1[0] + s1[1] + s1[2] + s1[3];
        s2[0] = s2[0] + s2[1] + s2[2] + s2[3];
    }
    __syncthreads();
    float mu  = s1[0] * (1.f / 256.f);
    float var = s2[0] * (1.f / 256.f) - mu * mu;
    float o2 = (v - mu) * rsqrtf(var + 1e-5f) * g[m] + bb[m];
    unsigned hb = f2bf_u(o2);
    outh[(size_t)r * 256 + m] = (u16)hb;
    outl[(size_t)r * 256 + m] = (u16)f2bf_u(o2 - __uint_as_float(hb << 16));
}

// ---------------------------------------------------------------------------
// LayerNorm over 256; fp32 in, bf16 hi/lo planes out.
// ---------------------------------------------------------------------------
__global__ __launch_bounds__(256) void k_ln(
    const float* __restrict__ in, const float* __restrict__ g,
    const float* __restrict__ bb, u16* __restrict__ outh, u16* __restrict__ outl)
{
    int r = blockIdx.x;
    int m = threadIdx.x;
    float v = in[(size_t)r * 256 + m];

    __shared__ float s1[4], s2[4];
    float a = v, bq = v * v;
    for (int o = 32; o > 0; o >>= 1) { a += __shfl_down(a, o); bq += __shfl_down(bq, o); }
    int wid = m >> 6, lane = m & 63;
    if (lane == 0) { s1[wid] = a; s2[wid] = bq; }
    __syncthreads();
    if (m == 0) {
        s1[0] = s1[0] + s1[1] + s1[2] + s1[3];
        s2[0] = s2[0] + s2[1] + s2[2] + s2[3];
    }
    __syncthreads();
    float mu  = s1[0] * (1.f / 256.f);
    float var = s2[0] * (1.f / 256.f) - mu * mu;
    float o2 = (v - mu) * rsqrtf(var + 1e-5f) * g[m] + bb[m];
    unsigned hb = f2bf_u(o2);
    outh[(size_t)r * 256 + m] = (u16)hb;
    outl[(size_t)r * 256 + m] = (u16)f2bf_u(o2 - __uint_as_float(hb << 16));
}

__global__ __launch_bounds__(256) void k_wcvt(
    const float* __restrict__ w, u16* __restrict__ oh, u16* __restrict__ ol, int n)
{
    int i = blockIdx.x * 256 + threadIdx.x;
    if (i < n) {
        float v = w[i];
        unsigned hb = f2bf_u(v);
        oh[i] = (u16)hb;
        ol[i] = (u16)f2bf_u(v - __uint_as_float(hb << 16));
    }
}

// ---------------------------------------------------------------------------
// split-bf16 MFMA GEMM (3-term): C[M,N] = A[M,K]*W[N,K]^T (+bias).
// A,W as separate hi/lo bf16 planes -> staging is pure load/store.
// 128x128 tile, BK=32, 4 waves x 64x64 quadrant.
// OUTK: 0 = fp32 out (C0), 1 = hi/lo plane out (C0=hi, C1=lo).
// ---------------------------------------------------------------------------
template <int OUTK, bool BIAS>
__global__ __launch_bounds__(256) void k_gmfma(
    const u16* __restrict__ Ahg, const u16* __restrict__ Alg, int lda,
    const u16* __restrict__ Whg, const u16* __restrict__ Wlg,
    const float* __restrict__ bias, void* __restrict__ C0, void* __restrict__ C1,
    int N, int K)
{
    __shared__ u16 Ah[128 * 40], Al[128 * 40];
    __shared__ u16 Wh[128 * 40], Wl[128 * 40];

    int tid = threadIdx.x;
    int wv = tid >> 6, ln = tid & 63;
    int wr = wv >> 1, wc = wv & 1;
    int m0 = blockIdx.x * 128, n0 = blockIdx.y * 128;
    int sr = tid >> 1, sk = (tid & 1) << 4;
    int frow = ln & 15, fk = (ln >> 4) << 3;

    f32x4 acc[4][4] = {};

    for (int k0 = 0; k0 < K; k0 += 32) {
        const u16* ah = Ahg + (size_t)(m0 + sr) * lda + k0 + sk;
        const u16* al = Alg + (size_t)(m0 + sr) * lda + k0 + sk;
        const u16* wh = Whg + (size_t)(n0 + sr) * K + k0 + sk;
        const u16* wl = Wlg + (size_t)(n0 + sr) * K + k0 + sk;
        short8 vah0 = *(const short8*)ah, vah1 = *(const short8*)(ah + 8);
        short8 val0 = *(const short8*)al, val1 = *(const short8*)(al + 8);
        short8 vwh0 = *(const short8*)wh, vwh1 = *(const short8*)(wh + 8);
        short8 vwl0 = *(const short8*)wl, vwl1 = *(const short8*)(wl + 8);

        __syncthreads();   // previous iteration's frag reads done

        *(short8*)&Ah[sr * 40 + sk]     = vah0;
        *(short8*)&Ah[sr * 40 + sk + 8] = vah1;
        *(short8*)&Al[sr * 40 + sk]     = val0;
        *(short8*)&Al[sr * 40 + sk + 8] = val1;
        *(short8*)&Wh[sr * 40 + sk]     = vwh0;
        *(short8*)&Wh[sr * 40 + sk + 8] = vwh1;
        *(short8*)&Wl[sr * 40 + sk]     = vwl0;
        *(short8*)&Wl[sr * 40 + sk + 8] = vwl1;

        __syncthreads();

        short8 afh[4], afl[4], wfh[4], wfl[4];
#pragma unroll
        for (int g = 0; g < 4; g++) {
            int ra = (wr * 64 + g * 16 + frow) * 40 + fk;
            int rw = (wc * 64 + g * 16 + frow) * 40 + fk;
            afh[g] = *(const short8*)&Ah[ra];
            afl[g] = *(const short8*)&Al[ra];
            wfh[g] = *(const short8*)&Wh[rw];
            wfl[g] = *(const short8*)&Wl[rw];
        }
#pragma unroll
        for (int mg = 0; mg < 4; mg++)
#pragma unroll
            for (int ng = 0; ng < 4; ng++) {
                acc[mg][ng] = __builtin_amdgcn_mfma_f32_16x16x32_bf16(afh[mg], wfh[ng], acc[mg][ng], 0, 0, 0);
                acc[mg][ng] = __builtin_amdgcn_mfma_f32_16x16x32_bf16(afh[mg], wfl[ng], acc[mg][ng], 0, 0, 0);
                acc[mg][ng] = __builtin_amdgcn_mfma_f32_16x16x32_bf16(afl[mg], wfh[ng], acc[mg][ng], 0, 0, 0);
            }
    }

    // C layout: col=lane&15, row=(lane>>4)*4+reg  [verified m89]
#pragma unroll
    for (int ng = 0; ng < 4; ng++) {
        int col = n0 + wc * 64 + ng * 16 + frow;
        float bv = BIAS ? bias[col] : 0.f;
#pragma unroll
        for (int mg = 0; mg < 4; mg++)
#pragma unroll
            for (int r = 0; r < 4; r++) {
                int row = m0 + wr * 64 + mg * 16 + (ln >> 4) * 4 + r;
                float v = acc[mg][ng][r] + bv;
                if (OUTK == 0) {
                    ((float*)C0)[(size_t)row * N + col] = v;
                } else {
                    unsigned hb = f2bf_u(v);
                    ((u16*)C0)[(size_t)row * N + col] = (u16)hb;
                    ((u16*)C1)[(size_t)row * N + col] =
                        (u16)f2bf_u(v - __uint_as_float(hb << 16));
                }
            }
    }
}

// ---------------------------------------------------------------------------
// xproj K-split partial GEMM: Cpart[slice][M][48] = A[:, ks..ks+128) * W^T.
// grid (M/64, 4). Deterministic reduce in k_dbr.
// ---------------------------------------------------------------------------
__global__ __launch_bounds__(256) void k_xpart(
    const float* __restrict__ A, const float* __restrict__ W,
    float* __restrict__ Cpart, int M, int K, int kcnt)
{
    const int BM = 64, BK = 16;
    __shared__ float As[BK][BM];
    __shared__ float Ws[BK][64];

    int m0   = blockIdx.x * BM;
    int kbeg = blockIdx.y * kcnt;
    int tid = threadIdx.x;
    int tx  = tid & 15, ty = tid >> 4;
    int lr  = tid >> 2;
    int lc  = (tid & 3) * 4;

    float acc[4][4] = {};

    for (int k0 = kbeg; k0 < kbeg + kcnt; k0 += BK) {
        float4 av = *(const float4*)(A + (size_t)(m0 + lr) * K + k0 + lc);
        As[lc + 0][lr] = av.x; As[lc + 1][lr] = av.y;
        As[lc + 2][lr] = av.z; As[lc + 3][lr] = av.w;
        float4 wv = make_float4(0.f, 0.f, 0.f, 0.f);
        if (lr < 48) wv = *(const float4*)(W + (size_t)lr * K + k0 + lc);
        Ws[lc + 0][lr] = wv.x; Ws[lc + 1][lr] = wv.y;
        Ws[lc + 2][lr] = wv.z; Ws[lc + 3][lr] = wv.w;
        __syncthreads();
#pragma unroll
        for (int k = 0; k < BK; k++) {
            float a[4], bv[4];
            *(float4*)a  = *(const float4*)&As[k][ty * 4];
            *(float4*)bv = *(const float4*)&Ws[k][tx * 4];
#pragma unroll
            for (int i = 0; i < 4; i++)
#pragma unroll
                for (int j = 0; j < 4; j++)
                    acc[i][j] = fmaf(a[i], bv[j], acc[i][j]);
        }
        __syncthreads();
    }

    int n = tx * 4;
    if (n < 48) {
        float* cp = Cpart + (size_t)blockIdx.y * M * 48;
#pragma unroll
        for (int i = 0; i < 4; i++) {
            float4 v = make_float4(acc[i][0], acc[i][1], acc[i][2], acc[i][3]);
            *(float4*)(cp + (size_t)(m0 + ty * 4 + i) * 48 + n) = v;
        }
    }
}

// deterministic 4-slice reduce: dbc = sum_slices Cpart
__global__ __launch_bounds__(256) void k_dbr(
    const float* __restrict__ part, float* __restrict__ dbc, int M)
{
    int i = blockIdx.x * 256 + threadIdx.x;   // over M*48
    size_t st = (size_t)M * 48;
    dbc[i] = ((part[i] + part[st + i]) + (part[2 * st + i] + part[3 * st + i]));
}

// ---------------------------------------------------------------------------
// depthwise causal conv1d (k=4) + SiLU, float4-vectorized (4 d's/thread).
// halo [3][32][512]. grid RC*512/1024 blocks.
// ---------------------------------------------------------------------------
__global__ __launch_bounds__(256) void k_conv(
    const float* __restrict__ xz, const float* __restrict__ halo,
    const float* __restrict__ cw, const float* __restrict__ cb,
    float* __restrict__ xc, int t0)
{
    size_t i4 = ((size_t)blockIdx.x * 256 + threadIdx.x) * 4;   // over RC*512
    int d  = (int)(i4 & 511);
    int r  = (int)(i4 >> 9);
    int b  = r & 31;
    int tl = r >> 5;

    float4 w0 = *(const float4*)(cw + (d + 0) * 4);
    float4 w1 = *(const float4*)(cw + (d + 1) * 4);
    float4 w2 = *(const float4*)(cw + (d + 2) * 4);
    float4 w3 = *(const float4*)(cw + (d + 3) * 4);
    float4 acc = *(const float4*)(cb + d);

#pragma unroll
    for (int k = 0; k < 4; k++) {
        int tsl = tl - 3 + k;
        float4 v;
        if (tsl >= 0)
            v = *(const float4*)(xz + ((size_t)tsl * 32 + b) * 1024 + d);
        else if (t0 + tsl >= 0)
            v = *(const float4*)(halo + ((size_t)(tsl + 3) * 32 + b) * 512 + d);
        else
            continue;
        acc.x = fmaf((&w0.x)[k], v.x, acc.x);
        acc.y = fmaf((&w1.x)[k], v.y, acc.y);
        acc.z = fmaf((&w2.x)[k], v.z, acc.z);
        acc.w = fmaf((&w3.x)[k], v.w, acc.w);
    }
    float4 o;
    o.x = acc.x / (1.f + __expf(-acc.x));
    o.y = acc.y / (1.f + __expf(-acc.y));
    o.z = acc.z / (1.f + __expf(-acc.z));
    o.w = acc.w / (1.f + __expf(-acc.w));
    *(float4*)(xc + i4) = o;
}

__global__ __launch_bounds__(256) void k_halo(
    const float* __restrict__ xz, float* __restrict__ halo)
{
    int idx = blockIdx.x * 256 + threadIdx.x;  // over 3*32*512
    int d = idx & 511;
    int b = (idx >> 9) & 31;
    int s = idx >> 14;
    halo[idx] = xz[(((size_t)(CH - 3 + s) * 32 + b) << 10) + d];
}

// ---------------------------------------------------------------------------
// scan pass A (fused dt-proj, geometric-dA fast path): local scan, h=0.
// Fast softplus: t2 = log2(1+e^s0); dt = ln2*t2; q = exp2(t2*A0nat)
// where A0nat = -exp(A_log[d,0]) (since A2[0]*ln2 = A0nat).
// grid: b(32) x half(2) x subchunk(32) = 2048 blocks.
// ---------------------------------------------------------------------------
__global__ __launch_bounds__(256) void k_scanA(
    const float* __restrict__ xc, const float* __restrict__ dbc,
    const float* __restrict__ dtw, const float* __restrict__ dtb,
    const float* __restrict__ A_log,
    float* __restrict__ hend, float* __restrict__ sumdt)
{
    int bx = blockIdx.x;
    int b    = bx >> 6;
    int half = (bx >> 5) & 1;
    int c    = bx & 31;
    int d = (half << 8) + threadIdx.x;

    float A2[DS], h[DS], wdt[DS];
#pragma unroll
    for (int s = 0; s < DS; s++) {
        A2[s] = -__expf(A_log[d * DS + s]) * LOG2E;
        h[s] = 0.f;
        wdt[s] = dtw[d * DS + s];
    }
    float dtbv = dtb[d];
    float A20 = A2[0];
    float A0nat = A20 * LN2;
    bool geo = true;
#pragma unroll
    for (int s = 0; s < DS; s++)
        geo = geo && (fabsf(A2[s] - (float)(s + 1) * A20) <=
                      1e-5f * fabsf(A2[s]) + 1e-30f);

    __shared__ float Bs[SCT][48];
    for (int f = threadIdx.x; f < SCT * 48; f += 256) {
        int tt = f / 48, jj = f - tt * 48;
        Bs[tt][jj] = dbc[((size_t)(c * SCT + tt) * 32 + b) * 48 + jj];
    }
    __syncthreads();

    float cum = 0.f;
    if (geo) {
        for (int tt = 0; tt < SCT; tt++) {
            size_t idx = ((size_t)(c * SCT + tt) * 32 + b) * DI + d;
            float p0 = 0.f, p1 = 0.f, p2 = 0.f, p3 = 0.f;
#pragma unroll
            for (int k = 0; k < 4; k++) {
                p0 = fmaf(Bs[tt][k],      wdt[k],      p0);
                p1 = fmaf(Bs[tt][4 + k],  wdt[4 + k],  p1);
                p2 = fmaf(Bs[tt][8 + k],  wdt[8 + k],  p2);
                p3 = fmaf(Bs[tt][12 + k], wdt[12 + k], p3);
            }
            float s0 = dtbv + ((p0 + p1) + (p2 + p3));
            float u  = __expf(s0);
            float t2 = __log2f(1.f + u);
            if (s0 > 80.f) t2 = s0 * LOG2E;
            float dt = LN2 * t2;
            cum += dt;
            float dtx = dt * xc[idx];
            float q  = exp2f(t2 * A0nat);
            float q2 = q * q, q3 = q2 * q, q4 = q2 * q2;
            float pv[4] = { q, q2, q3, q4 };
            float r = 1.f;
#pragma unroll
            for (int g = 0; g < 4; g++) {
#pragma unroll
                for (int j = 0; j < 4; j++) {
                    int s = g * 4 + j;
                    float dA = r * pv[j];
                    h[s] = fmaf(dA, h[s], dtx * Bs[tt][16 + s]);
                }
                r *= q4;
            }
        }
    } else {
        for (int tt = 0; tt < SCT; tt++) {
            size_t idx = ((size_t)(c * SCT + tt) * 32 + b) * DI + d;
            float s0 = dtbv;
#pragma unroll
            for (int k = 0; k < DS; k++) s0 = fmaf(Bs[tt][k], wdt[k], s0);
            float dt = (s0 > 20.f) ? s0 : log1pf(expf(s0));
            cum += dt;
            float dtx = dt * xc[idx];
#pragma unroll
            for (int s = 0; s < DS; s++) {
                float dA = exp2f(dt * A2[s]);
                h[s] = fmaf(dA, h[s], dtx * Bs[tt][16 + s]);
            }
        }
    }
    float* hp = hend + ((size_t)(c * 32 + b) * 512 + d) * DS;
#pragma unroll
    for (int s = 0; s < DS; s++) hp[s] = h[s];
    sumdt[((size_t)c * 32 + b) * 512 + d] = cum;
}

// ---------------------------------------------------------------------------
// scan pass B: carry across 32 sub-chunks; hend -> h_init, carry -> hs.
// ---------------------------------------------------------------------------
__global__ __launch_bounds__(256) void k_scanB(
    const float* __restrict__ sumdt, float* __restrict__ hend,
    const float* __restrict__ A_log, float* __restrict__ hs, int first)
{
    int id = blockIdx.x * 256 + threadIdx.x;   // 32*512*16 = 262144
    int s = id & 15;
    int d = (id >> 4) & 511;
    int b = id >> 13;
    float A2 = -__expf(A_log[d * DS + s]) * LOG2E;
    size_t hsi = ((size_t)(b << 9) + d) * DS + s;
    float hin = first ? 0.f : hs[hsi];
    for (int c = 0; c < NSC; c++) {
        size_t hi = ((size_t)(c * 32 + b) * 512 + d) * DS + s;
        float he = hend[hi];
        float sd = sumdt[((size_t)c * 32 + b) * 512 + d];
        hend[hi] = hin;
        hin = fmaf(exp2f(A2 * sd), hin, he);
    }
    hs[hsi] = hin;
}

// ---------------------------------------------------------------------------
// scan pass C (fused dt-proj, geometric-dA fast path, fast softplus):
// rescan seeded with h_init, y inline, epilogue (y+x*D)*silu(z) ->
// bf16 hi/lo planes yh/yl. grid 2048 blocks.
// ---------------------------------------------------------------------------
__global__ __launch_bounds__(256) void k_scanC(
    const float* __restrict__ xc, const float* __restrict__ dbc,
    const float* __restrict__ dtw, const float* __restrict__ dtb,
    const float* __restrict__ xz,
    const float* __restrict__ A_log, const float* __restrict__ Dp,
    const float* __restrict__ hinit,
    u16* __restrict__ yh, u16* __restrict__ yl)
{
    int bx = blockIdx.x;
    int b    = bx >> 6;
    int half = (bx >> 5) & 1;
    int c    = bx & 31;
    int d = (half << 8) + threadIdx.x;

    float A2[DS], h[DS], wdt[DS];
    const float* hp = hinit + ((size_t)(c * 32 + b) * 512 + d) * DS;
#pragma unroll
    for (int s = 0; s < DS; s++) {
        A2[s] = -__expf(A_log[d * DS + s]) * LOG2E;
        h[s] = hp[s];
        wdt[s] = dtw[d * DS + s];
    }
    float dtbv = dtb[d];
    float Dv = Dp[d];
    float A20 = A2[0];
    float A0nat = A20 * LN2;
    bool geo = true;
#pragma unroll
    for (int s = 0; s < DS; s++)
        geo = geo && (fabsf(A2[s] - (float)(s + 1) * A20) <=
                      1e-5f * fabsf(A2[s]) + 1e-30f);

    __shared__ float BC[SCT][48];
    for (int f = threadIdx.x; f < SCT * 48; f += 256) {
        int tt = f / 48, jj = f - tt * 48;
        BC[tt][jj] = dbc[((size_t)(c * SCT + tt) * 32 + b) * 48 + jj];
    }
    __syncthreads();

    if (geo) {
        for (int tt = 0; tt < SCT; tt++) {
            size_t row = (size_t)(c * SCT + tt) * 32 + b;
            size_t idx = row * DI + d;
            float p0 = 0.f, p1 = 0.f, p2 = 0.f, p3 = 0.f;
#pragma unroll
            for (int k = 0; k < 4; k++) {
                p0 = fmaf(BC[tt][k],      wdt[k],      p0);
                p1 = fmaf(BC[tt][4 + k],  wdt[4 + k],  p1);
                p2 = fmaf(BC[tt][8 + k],  wdt[8 + k],  p2);
                p3 = fmaf(BC[tt][12 + k], wdt[12 + k], p3);
            }
            float s0 = dtbv + ((p0 + p1) + (p2 + p3));
            float u  = __expf(s0);
            float t2 = __log2f(1.f + u);
            if (s0 > 80.f) t2 = s0 * LOG2E;
            float dt = LN2 * t2;
            float x  = xc[idx];
            float z  = xz[(row << 10) + 512 + d];
            float dtx = dt * x;
            float y = 0.f;
            float q  = exp2f(t2 * A0nat);
            float q2 = q * q, q3 = q2 * q, q4 = q2 * q2;
            float pv[4] = { q, q2, q3, q4 };
            float r = 1.f;
#pragma unroll
            for (int g = 0; g < 4; g++) {
#pragma unroll
                for (int j = 0; j < 4; j++) {
                    int s = g * 4 + j;
                    float dA = r * pv[j];
                    h[s] = fmaf(dA, h[s], dtx * BC[tt][16 + s]);
                    y = fmaf(h[s], BC[tt][32 + s], y);
                }
                r *= q4;
            }
            float yact = (y + x * Dv) * (z / (1.f + __expf(-z)));
            unsigned hb = f2bf_u(yact);
            yh[row * DI + d] = (u16)hb;
            yl[row * DI + d] = (u16)f2bf_u(yact - __uint_as_float(hb << 16));
        }
    } else {
        for (int tt = 0; tt < SCT; tt++) {
            size_t row = (size_t)(c * SCT + tt) * 32 + b;
            size_t idx = row * DI + d;
            float s0 = dtbv;
#pragma unroll
            for (int k = 0; k < DS; k++) s0 = fmaf(BC[tt][k], wdt[k], s0);
            float dt = (s0 > 20.f) ? s0 : log1pf(expf(s0));
            float x  = xc[idx];
            float z  = xz[(row << 10) + 512 + d];
            float dtx = dt * x;
            float y = 0.f;
#pragma unroll
            for (int s = 0; s < DS; s++) {
                float dA = exp2f(dt * A2[s]);
                h[s] = fmaf(dA, h[s], dtx * BC[tt][16 + s]);
                y = fmaf(h[s], BC[tt][32 + s], y);
            }
            float yact = (y + x * Dv) * (z / (1.f + __expf(-z)));
            unsigned hb = f2bf_u(yact);
            yh[row * DI + d] = (u16)hb;
            yl[row * DI + d] = (u16)f2bf_u(yact - __uint_as_float(hb << 16));
        }
    }
}

// ---------------------------------------------------------------------------
// mean accumulate (partial over 8 tl-slices) / head (sums 8 partials)
// ---------------------------------------------------------------------------
__global__ __launch_bounds__(256) void k_meanacc(
    const float* __restrict__ mo, float* __restrict__ macc, int first)
{
    int b = blockIdx.x, g = blockIdx.y;
    int m = threadIdx.x;
    float s = 0.f;
    const int TLP = CH / 8;
    for (int t = 0; t < TLP; t++) {
        int tl = g * TLP + t;
        s += mo[((size_t)tl * 32 + b) * 256 + m];
    }
    int i = (b * 8 + g) * 256 + m;
    if (first) macc[i] = s;
    else       macc[i] += s;
}

__global__ __launch_bounds__(128) void k_head(
    const float* __restrict__ macc, const float* __restrict__ xst,
    const float* __restrict__ h1w, const float* __restrict__ h1b,
    const float* __restrict__ h2w, const float* __restrict__ h2b,
    float* __restrict__ out)
{
    int b = blockIdx.x;
    int j = threadIdx.x;
    const float* wr = h1w + j * 261;
    const float* mr = macc + (size_t)b * 8 * 256;
    float s = h1b[j];
    for (int k = 0; k < 256; k++) {
        float mv = 0.f;
#pragma unroll
        for (int g = 0; g < 8; g++) mv += mr[g * 256 + k];
        s = fmaf(mv * (1.f / 1024.f), wr[k], s);
    }
    for (int k = 0; k < 5; k++) s = fmaf(xst[b * 5 + k], wr[256 + k], s);
    float e = (s > 0.f) ? s : expm1f(s);

    __shared__ float sb[128];
    sb[j] = e * h2w[j];
    __syncthreads();
    for (int o = 64; o > 0; o >>= 1) {
        if (j < o) sb[j] += sb[j + o];
        __syncthreads();
    }
    if (j == 0) out[b] = sb[0] + h2b[0];
}

// ---------------------------------------------------------------------------
// host side
// ---------------------------------------------------------------------------
static void run_mamba_chunk(hipStream_t stream,
                            const u16* x1h, const u16* x1l, void* const* P,
                            const u16* wih, const u16* wil,
                            const u16* woh, const u16* wol, int out_pairs,
                            float* xzc, float* xcc, float* dbcc, float* xpartb,
                            float* moc, u16* moh, u16* mol,
                            u16* yh, u16* yl,
                            float* hendb, float* sumdtb, float* halo,
                            float* hstate, int t0, int save_halo)
{
    const float* cw     = (const float*)P[1];
    const float* cb     = (const float*)P[2];
    const float* xpw    = (const float*)P[3];
    const float* dtw    = (const float*)P[4];
    const float* dtbias = (const float*)P[5];
    const float* Alog   = (const float*)P[6];
    const float* Dp     = (const float*)P[7];
    int first = (t0 == 0);

    k_gmfma<0, false><<<dim3(RC / 128, 1024 / 128), 256, 0, stream>>>(
        x1h, x1l, 256, wih, wil, nullptr, xzc, nullptr, 1024, 256);
    k_conv<<<RC * DI / 1024, 256, 0, stream>>>(xzc, halo, cw, cb, xcc, t0);
    if (save_halo)
        k_halo<<<3 * 32 * 512 / 256, 256, 0, stream>>>(xzc, halo);
    k_xpart<<<dim3(RC / 64, 4), 256, 0, stream>>>(xcc, xpw, xpartb, RC, 512, 128);
    k_dbr<<<RC * 48 / 256, 256, 0, stream>>>(xpartb, dbcc, RC);
    k_scanA<<<32 * 2 * NSC, 256, 0, stream>>>(xcc, dbcc, dtw, dtbias, Alog,
                                              hendb, sumdtb);
    k_scanB<<<32 * 512 * DS / 256, 256, 0, stream>>>(sumdtb, hendb, Alog, hstate, first);
    k_scanC<<<32 * 2 * NSC, 256, 0, stream>>>(xcc, dbcc, dtw, dtbias, xzc,
                                              Alog, Dp, hendb, yh, yl);
    if (out_pairs)
        k_gmfma<1, false><<<dim3(RC / 128, 256 / 128), 256, 0, stream>>>(
            yh, yl, 512, woh, wol, nullptr, moh, mol, 256, 512);
    else
        k_gmfma<0, false><<<dim3(RC / 128, 256 / 128), 256, 0, stream>>>(
            yh, yl, 512, woh, wol, nullptr, moc, nullptr, 256, 512);
}

extern "C" void kernel_launch(void* const* d_in, const int* in_sizes, int n_in,
                              void* d_out, int out_size, void* d_ws, size_t ws_size,
                              hipStream_t stream)
{
    const float* xseq = (const float*)d_in[0];
    const float* xst  = (const float*)d_in[1];
    const float* p1w  = (const float*)d_in[2];
    const float* p1b  = (const float*)d_in[3];
    const float* ln1g = (const float*)d_in[4];
    const float* ln1b = (const float*)d_in[5];
    const float* p2w  = (const float*)d_in[6];
    const float* p2b  = (const float*)d_in[7];
    const float* ln2g = (const float*)d_in[8];
    const float* ln2b = (const float*)d_in[9];
    const float* h1w  = (const float*)d_in[10];
    const float* h1b  = (const float*)d_in[11];
    const float* h2w  = (const float*)d_in[12];
    const float* h2b  = (const float*)d_in[13];

    float* ws = (float*)d_ws;
    float* xzc    = ws;                                  // RC*1024 f32
    float* xcc    = xzc  + (size_t)RC * 1024;            // RC*512
    float* dbcc   = xcc  + (size_t)RC * 512;             // RC*48
    float* moc    = dbcc + (size_t)RC * 48;              // RC*256 f32
    u16*   x1h    = (u16*)(moc + (size_t)RC * 256);      // RC*256 u16
    u16*   x1l    = x1h + (size_t)RC * 256;              // RC*256 u16
    // hend aliases [moc | x1h | x1l] = exactly NSC*32*512*DS floats;
    // all three are dead during the scan phase (liveness audited at CH=512).
    float* hendb  = moc;
    float* after  = (float*)(x1l + (size_t)RC * 256);
    u16*   yh     = (u16*)after;                         // RC*512 u16
    u16*   yl     = yh + (size_t)RC * 512;               // RC*512 u16
    u16*   moh    = yl + (size_t)RC * 512;               // RC*256 u16
    u16*   mol    = moh + (size_t)RC * 256;              // RC*256 u16
    float* sumdtb = (float*)(mol + (size_t)RC * 256);    // NSC*32*512
    float* halo1  = sumdtb + NSC * 32 * 512;             // 3*32*512
    float* halo2  = halo1 + 3 * 32 * 512;
    float* hs1    = halo2 + 3 * 32 * 512;                // 32*512*16
    float* hs2    = hs1  + 32 * 512 * DS;
    float* macc   = hs2  + 32 * 512 * DS;                // 32*8*256
    u16*   wm1ih  = (u16*)(macc + 32 * 8 * 256);         // 1024*256 u16 each
    u16*   wm1il  = wm1ih + 262144;
    u16*   wm1oh  = wm1il + 262144;                      // 256*512 u16 each
    u16*   wm1ol  = wm1oh + 131072;
    u16*   wm2ih  = wm1ol + 131072;
    u16*   wm2il  = wm2ih + 262144;
    u16*   wm2oh  = wm2il + 262144;
    u16*   wm2ol  = wm2oh + 131072;
    u16*   wp2h   = wm2ol + 131072;                      // 256*256 u16 each
    u16*   wp2l   = wp2h + 65536;
    float* xpartb = (float*)(wp2l + 65536);              // 4*RC*48 f32
    size_t need = (size_t)((char*)(xpartb + 4 * (size_t)RC * 48) - (char*)ws);
    if (ws_size < need) return;   // tripwire: fail cleanly, don't fault

    // weight bf16 hi/lo plane conversion (once per launch)
    k_wcvt<<<262144 / 256, 256, 0, stream>>>((const float*)d_in[14], wm1ih, wm1il, 262144);
    k_wcvt<<<131072 / 256, 256, 0, stream>>>((const float*)d_in[22], wm1oh, wm1ol, 131072);
    k_wcvt<<<262144 / 256, 256, 0, stream>>>((const float*)d_in[23], wm2ih, wm2il, 262144);
    k_wcvt<<<131072 / 256, 256, 0, stream>>>((const float*)d_in[31], wm2oh, wm2ol, 131072);
    k_wcvt<<<65536 / 256, 256, 0, stream>>>(p2w, wp2h, wp2l, 65536);

    for (int c = 0; c < NCH; c++) {
        int t0 = c * CH;
        int first = (c == 0);
        int save_halo = (c != NCH - 1);

        k_p1_ln<<<RC, 256, 0, stream>>>(xseq, p1w, p1b, ln1g, ln1b, x1h, x1l, t0);

        // mamba 1 (params d_in[14..22]); out_proj emits hi/lo planes for p2
        run_mamba_chunk(stream, x1h, x1l, d_in + 14, wm1ih, wm1il, wm1oh, wm1ol, 1,
                        xzc, xcc, dbcc, xpartb, moc, moh, mol, yh, yl,
                        hendb, sumdtb, halo1, hs1, t0, save_halo);

        // p2 + LN2
        k_gmfma<0, true><<<dim3(RC / 128, 256 / 128), 256, 0, stream>>>(
            moh, mol, 256, wp2h, wp2l, p2b, xzc, nullptr, 256, 256);
        k_ln<<<RC, 256, 0, stream>>>(xzc, ln2g, ln2b, x1h, x1l);

        // mamba 2 (params d_in[23..31]); out_proj emits f32 for meanacc
        run_mamba_chunk(stream, x1h, x1l, d_in + 23, wm2ih, wm2il, wm2oh, wm2ol, 0,
                        xzc, xcc, dbcc, xpartb, moc, moh, mol, yh, yl,
                        hendb, sumdtb, halo2, hs2, t0, save_halo);

        k_meanacc<<<dim3(NB, 8), 256, 0, stream>>>(moc, macc, first);
    }

    k_head<<<NB, 128, 0, stream>>>(macc, xst, h1w, h1b, h2w, h2b, (float*)d_out);
}

// Round 14
// 839.890 us; speedup vs baseline: 2.4020x; 1.0245x over previous
//
#include <hip/hip_runtime.h>
#include <math.h>

#define NB 32
#define L  1024
#define CH 512                 // timesteps per chunk
#define NCH (L / CH)           // 2 chunks
#define RC (NB * CH)           // 16384 rows per chunk
#define DM 256
#define DI 512
#define DS 16
#define SCT 16                 // sub-chunk timesteps (scan)
#define NSC (CH / SCT)         // 32 sub-chunks
#define LOG2E 1.44269504f
#define LN2   0.69314718f

typedef short short8 __attribute__((ext_vector_type(8)));
typedef float f32x4 __attribute__((ext_vector_type(4)));
typedef unsigned short u16;

// bf16 split helpers: x ~= hi + lo, both bf16 (rne).
__device__ inline unsigned f2bf_u(float x) {
    unsigned u = __float_as_uint(x);
    return (u + 0x7fffu + ((u >> 16) & 1u)) >> 16;
}

// Layout: per-chunk activations use (t_local, b, feat): row r = t_local*32 + b.

// ---------------------------------------------------------------------------
// p1 (K=4) + bias + LayerNorm; emits bf16 hi/lo PLANES for MFMA in_proj.
// ---------------------------------------------------------------------------
__global__ __launch_bounds__(256) void k_p1_ln(
    const float* __restrict__ xseq, const float* __restrict__ w,
    const float* __restrict__ bias, const float* __restrict__ g,
    const float* __restrict__ bb, u16* __restrict__ outh, u16* __restrict__ outl,
    int t0)
{
    int r  = blockIdx.x;
    int b  = r & 31;
    int tl = r >> 5;
    int m  = threadIdx.x;
    const float* xr = xseq + ((size_t)b * L + t0 + tl) * 4;
    float x0 = xr[0], x1 = xr[1], x2 = xr[2], x3 = xr[3];
    const float* wr = w + m * 4;
    float v = bias[m] + x0 * wr[0] + x1 * wr[1] + x2 * wr[2] + x3 * wr[3];

    __shared__ float s1[4], s2[4];
    float a = v, bq = v * v;
    for (int o = 32; o > 0; o >>= 1) { a += __shfl_down(a, o); bq += __shfl_down(bq, o); }
    int wid = m >> 6, lane = m & 63;
    if (lane == 0) { s1[wid] = a; s2[wid] = bq; }
    __syncthreads();
    if (m == 0) {
        s1[0] = s1[0] + s1[1] + s1[2] + s1[3];
        s2[0] = s2[0] + s2[1] + s2[2] + s2[3];
    }
    __syncthreads();
    float mu  = s1[0] * (1.f / 256.f);
    float var = s2[0] * (1.f / 256.f) - mu * mu;
    float o2 = (v - mu) * rsqrtf(var + 1e-5f) * g[m] + bb[m];
    unsigned hb = f2bf_u(o2);
    outh[(size_t)r * 256 + m] = (u16)hb;
    outl[(size_t)r * 256 + m] = (u16)f2bf_u(o2 - __uint_as_float(hb << 16));
}

// ---------------------------------------------------------------------------
// LayerNorm over 256; fp32 in, bf16 hi/lo planes out.
// ---------------------------------------------------------------------------
__global__ __launch_bounds__(256) void k_ln(
    const float* __restrict__ in, const float* __restrict__ g,
    const float* __restrict__ bb, u16* __restrict__ outh, u16* __restrict__ outl)
{
    int r = blockIdx.x;
    int m = threadIdx.x;
    float v = in[(size_t)r * 256 + m];

    __shared__ float s1[4], s2[4];
    float a = v, bq = v * v;
    for (int o = 32; o > 0; o >>= 1) { a += __shfl_down(a, o); bq += __shfl_down(bq, o); }
    int wid = m >> 6, lane = m & 63;
    if (lane == 0) { s1[wid] = a; s2[wid] = bq; }
    __syncthreads();
    if (m == 0) {
        s1[0] = s1[0] + s1[1] + s1[2] + s1[3];
        s2[0] = s2[0] + s2[1] + s2[2] + s2[3];
    }
    __syncthreads();
    float mu  = s1[0] * (1.f / 256.f);
    float var = s2[0] * (1.f / 256.f) - mu * mu;
    float o2 = (v - mu) * rsqrtf(var + 1e-5f) * g[m] + bb[m];
    unsigned hb = f2bf_u(o2);
    outh[(size_t)r * 256 + m] = (u16)hb;
    outl[(size_t)r * 256 + m] = (u16)f2bf_u(o2 - __uint_as_float(hb << 16));
}

// ---------------------------------------------------------------------------
// fused weight conversion: all 5 weight matrices -> hi/lo planes, 1 launch.
// total elems = 262144+131072+262144+131072+65536 = 852992 = 256*3332.
// ---------------------------------------------------------------------------
__global__ __launch_bounds__(256) void k_wcvt_all(
    const float* __restrict__ w1i, const float* __restrict__ w1o,
    const float* __restrict__ w2i, const float* __restrict__ w2o,
    const float* __restrict__ p2,
    u16* __restrict__ o1ih, u16* __restrict__ o1il,
    u16* __restrict__ o1oh, u16* __restrict__ o1ol,
    u16* __restrict__ o2ih, u16* __restrict__ o2il,
    u16* __restrict__ o2oh, u16* __restrict__ o2ol,
    u16* __restrict__ op2h, u16* __restrict__ op2l)
{
    int i = blockIdx.x * 256 + threadIdx.x;
    const float* src; u16 *oh, *ol; int j;
    if (i < 262144)      { src = w1i; oh = o1ih; ol = o1il; j = i; }
    else if (i < 393216) { src = w1o; oh = o1oh; ol = o1ol; j = i - 262144; }
    else if (i < 655360) { src = w2i; oh = o2ih; ol = o2il; j = i - 393216; }
    else if (i < 786432) { src = w2o; oh = o2oh; ol = o2ol; j = i - 655360; }
    else                 { src = p2;  oh = op2h; ol = op2l; j = i - 786432; }
    float v = src[j];
    unsigned hb = f2bf_u(v);
    oh[j] = (u16)hb;
    ol[j] = (u16)f2bf_u(v - __uint_as_float(hb << 16));
}

// ---------------------------------------------------------------------------
// split-bf16 MFMA GEMM (3-term): C[M,N] = A[M,K]*W[N,K]^T (+bias).
// A,W as separate hi/lo bf16 planes -> staging is pure load/store.
// 128x128 tile, BK=32, 4 waves x 64x64 quadrant.
// OUTK: 0 = fp32 out (C0), 1 = hi/lo plane out (C0=hi, C1=lo).
// ---------------------------------------------------------------------------
template <int OUTK, bool BIAS>
__global__ __launch_bounds__(256) void k_gmfma(
    const u16* __restrict__ Ahg, const u16* __restrict__ Alg, int lda,
    const u16* __restrict__ Whg, const u16* __restrict__ Wlg,
    const float* __restrict__ bias, void* __restrict__ C0, void* __restrict__ C1,
    int N, int K)
{
    __shared__ u16 Ah[128 * 40], Al[128 * 40];
    __shared__ u16 Wh[128 * 40], Wl[128 * 40];

    int tid = threadIdx.x;
    int wv = tid >> 6, ln = tid & 63;
    int wr = wv >> 1, wc = wv & 1;
    int m0 = blockIdx.x * 128, n0 = blockIdx.y * 128;
    int sr = tid >> 1, sk = (tid & 1) << 4;
    int frow = ln & 15, fk = (ln >> 4) << 3;

    f32x4 acc[4][4] = {};

    for (int k0 = 0; k0 < K; k0 += 32) {
        const u16* ah = Ahg + (size_t)(m0 + sr) * lda + k0 + sk;
        const u16* al = Alg + (size_t)(m0 + sr) * lda + k0 + sk;
        const u16* wh = Whg + (size_t)(n0 + sr) * K + k0 + sk;
        const u16* wl = Wlg + (size_t)(n0 + sr) * K + k0 + sk;
        short8 vah0 = *(const short8*)ah, vah1 = *(const short8*)(ah + 8);
        short8 val0 = *(const short8*)al, val1 = *(const short8*)(al + 8);
        short8 vwh0 = *(const short8*)wh, vwh1 = *(const short8*)(wh + 8);
        short8 vwl0 = *(const short8*)wl, vwl1 = *(const short8*)(wl + 8);

        __syncthreads();   // previous iteration's frag reads done

        *(short8*)&Ah[sr * 40 + sk]     = vah0;
        *(short8*)&Ah[sr * 40 + sk + 8] = vah1;
        *(short8*)&Al[sr * 40 + sk]     = val0;
        *(short8*)&Al[sr * 40 + sk + 8] = val1;
        *(short8*)&Wh[sr * 40 + sk]     = vwh0;
        *(short8*)&Wh[sr * 40 + sk + 8] = vwh1;
        *(short8*)&Wl[sr * 40 + sk]     = vwl0;
        *(short8*)&Wl[sr * 40 + sk + 8] = vwl1;

        __syncthreads();

        short8 afh[4], afl[4], wfh[4], wfl[4];
#pragma unroll
        for (int g = 0; g < 4; g++) {
            int ra = (wr * 64 + g * 16 + frow) * 40 + fk;
            int rw = (wc * 64 + g * 16 + frow) * 40 + fk;
            afh[g] = *(const short8*)&Ah[ra];
            afl[g] = *(const short8*)&Al[ra];
            wfh[g] = *(const short8*)&Wh[rw];
            wfl[g] = *(const short8*)&Wl[rw];
        }
#pragma unroll
        for (int mg = 0; mg < 4; mg++)
#pragma unroll
            for (int ng = 0; ng < 4; ng++) {
                acc[mg][ng] = __builtin_amdgcn_mfma_f32_16x16x32_bf16(afh[mg], wfh[ng], acc[mg][ng], 0, 0, 0);
                acc[mg][ng] = __builtin_amdgcn_mfma_f32_16x16x32_bf16(afh[mg], wfl[ng], acc[mg][ng], 0, 0, 0);
                acc[mg][ng] = __builtin_amdgcn_mfma_f32_16x16x32_bf16(afl[mg], wfh[ng], acc[mg][ng], 0, 0, 0);
            }
    }

    // C layout: col=lane&15, row=(lane>>4)*4+reg  [verified m89]
#pragma unroll
    for (int ng = 0; ng < 4; ng++) {
        int col = n0 + wc * 64 + ng * 16 + frow;
        float bv = BIAS ? bias[col] : 0.f;
#pragma unroll
        for (int mg = 0; mg < 4; mg++)
#pragma unroll
            for (int r = 0; r < 4; r++) {
                int row = m0 + wr * 64 + mg * 16 + (ln >> 4) * 4 + r;
                float v = acc[mg][ng][r] + bv;
                if (OUTK == 0) {
                    ((float*)C0)[(size_t)row * N + col] = v;
                } else {
                    unsigned hb = f2bf_u(v);
                    ((u16*)C0)[(size_t)row * N + col] = (u16)hb;
                    ((u16*)C1)[(size_t)row * N + col] =
                        (u16)f2bf_u(v - __uint_as_float(hb << 16));
                }
            }
    }
}

// ---------------------------------------------------------------------------
// xproj K-split partial GEMM: Cpart[slice][M][48] = A[:, ks..ks+128) * W^T.
// grid (M/64, 4). Partials summed inside the scans (exact dbr order).
// ---------------------------------------------------------------------------
__global__ __launch_bounds__(256) void k_xpart(
    const float* __restrict__ A, const float* __restrict__ W,
    float* __restrict__ Cpart, int M, int K, int kcnt)
{
    const int BM = 64, BK = 16;
    __shared__ float As[BK][BM];
    __shared__ float Ws[BK][64];

    int m0   = blockIdx.x * BM;
    int kbeg = blockIdx.y * kcnt;
    int tid = threadIdx.x;
    int tx  = tid & 15, ty = tid >> 4;
    int lr  = tid >> 2;
    int lc  = (tid & 3) * 4;

    float acc[4][4] = {};

    for (int k0 = kbeg; k0 < kbeg + kcnt; k0 += BK) {
        float4 av = *(const float4*)(A + (size_t)(m0 + lr) * K + k0 + lc);
        As[lc + 0][lr] = av.x; As[lc + 1][lr] = av.y;
        As[lc + 2][lr] = av.z; As[lc + 3][lr] = av.w;
        float4 wv = make_float4(0.f, 0.f, 0.f, 0.f);
        if (lr < 48) wv = *(const float4*)(W + (size_t)lr * K + k0 + lc);
        Ws[lc + 0][lr] = wv.x; Ws[lc + 1][lr] = wv.y;
        Ws[lc + 2][lr] = wv.z; Ws[lc + 3][lr] = wv.w;
        __syncthreads();
#pragma unroll
        for (int k = 0; k < BK; k++) {
            float a[4], bv[4];
            *(float4*)a  = *(const float4*)&As[k][ty * 4];
            *(float4*)bv = *(const float4*)&Ws[k][tx * 4];
#pragma unroll
            for (int i = 0; i < 4; i++)
#pragma unroll
                for (int j = 0; j < 4; j++)
                    acc[i][j] = fmaf(a[i], bv[j], acc[i][j]);
        }
        __syncthreads();
    }

    int n = tx * 4;
    if (n < 48) {
        float* cp = Cpart + (size_t)blockIdx.y * M * 48;
#pragma unroll
        for (int i = 0; i < 4; i++) {
            float4 v = make_float4(acc[i][0], acc[i][1], acc[i][2], acc[i][3]);
            *(float4*)(cp + (size_t)(m0 + ty * 4 + i) * 48 + n) = v;
        }
    }
}

// ---------------------------------------------------------------------------
// depthwise causal conv1d (k=4) + SiLU, float4-vectorized, with fused
// halo-save (thread at row tl>=CH-3 stores its own tap). At NCH=2 chunk0
// only writes halo and chunk1 only reads it -> race-free.
// ---------------------------------------------------------------------------
__global__ __launch_bounds__(256) void k_conv(
    const float* __restrict__ xz, float* __restrict__ halo,
    const float* __restrict__ cw, const float* __restrict__ cb,
    float* __restrict__ xc, int t0, int save_halo)
{
    size_t i4 = ((size_t)blockIdx.x * 256 + threadIdx.x) * 4;   // over RC*512
    int d  = (int)(i4 & 511);
    int r  = (int)(i4 >> 9);
    int b  = r & 31;
    int tl = r >> 5;

    float4 w0 = *(const float4*)(cw + (d + 0) * 4);
    float4 w1 = *(const float4*)(cw + (d + 1) * 4);
    float4 w2 = *(const float4*)(cw + (d + 2) * 4);
    float4 w3 = *(const float4*)(cw + (d + 3) * 4);
    float4 acc = *(const float4*)(cb + d);
    float4 vlast = make_float4(0.f, 0.f, 0.f, 0.f);

#pragma unroll
    for (int k = 0; k < 4; k++) {
        int tsl = tl - 3 + k;
        float4 v;
        if (tsl >= 0)
            v = *(const float4*)(xz + ((size_t)tsl * 32 + b) * 1024 + d);
        else if (t0 + tsl >= 0)
            v = *(const float4*)(halo + ((size_t)(tsl + 3) * 32 + b) * 512 + d);
        else
            continue;
        if (k == 3) vlast = v;
        acc.x = fmaf((&w0.x)[k], v.x, acc.x);
        acc.y = fmaf((&w1.x)[k], v.y, acc.y);
        acc.z = fmaf((&w2.x)[k], v.z, acc.z);
        acc.w = fmaf((&w3.x)[k], v.w, acc.w);
    }
    float4 o;
    o.x = acc.x / (1.f + __expf(-acc.x));
    o.y = acc.y / (1.f + __expf(-acc.y));
    o.z = acc.z / (1.f + __expf(-acc.z));
    o.w = acc.w / (1.f + __expf(-acc.w));
    *(float4*)(xc + i4) = o;

    if (save_halo && tl >= CH - 3)
        *(float4*)(halo + ((size_t)(tl - (CH - 3)) * 32 + b) * 512 + d) = vlast;
}

// ---------------------------------------------------------------------------
// scan pass A (fused dt-proj + partial-reduce, geometric-dA fast path).
// Stages Bs by summing the 4 xpart slices (exact dbr order).
// grid: b(32) x half(2) x subchunk(32) = 2048 blocks.
// ---------------------------------------------------------------------------
__global__ __launch_bounds__(256) void k_scanA(
    const float* __restrict__ xc, const float* __restrict__ part,
    const float* __restrict__ dtw, const float* __restrict__ dtb,
    const float* __restrict__ A_log,
    float* __restrict__ hend, float* __restrict__ sumdt)
{
    int bx = blockIdx.x;
    int b    = bx >> 6;
    int half = (bx >> 5) & 1;
    int c    = bx & 31;
    int d = (half << 8) + threadIdx.x;

    float A2[DS], h[DS], wdt[DS];
#pragma unroll
    for (int s = 0; s < DS; s++) {
        A2[s] = -__expf(A_log[d * DS + s]) * LOG2E;
        h[s] = 0.f;
        wdt[s] = dtw[d * DS + s];
    }
    float dtbv = dtb[d];
    float A20 = A2[0];
    float A0nat = A20 * LN2;
    bool geo = true;
#pragma unroll
    for (int s = 0; s < DS; s++)
        geo = geo && (fabsf(A2[s] - (float)(s + 1) * A20) <=
                      1e-5f * fabsf(A2[s]) + 1e-30f);

    __shared__ float Bs[SCT][48];
    {
        const size_t st = (size_t)RC * 48;
        for (int f = threadIdx.x; f < SCT * 48; f += 256) {
            int tt = f / 48, jj = f - tt * 48;
            size_t base = ((size_t)(c * SCT + tt) * 32 + b) * 48 + jj;
            Bs[tt][jj] = (part[base] + part[st + base]) +
                         (part[2 * st + base] + part[3 * st + base]);
        }
    }
    __syncthreads();

    float cum = 0.f;
    if (geo) {
        for (int tt = 0; tt < SCT; tt++) {
            size_t idx = ((size_t)(c * SCT + tt) * 32 + b) * DI + d;
            float p0 = 0.f, p1 = 0.f, p2 = 0.f, p3 = 0.f;
#pragma unroll
            for (int k = 0; k < 4; k++) {
                p0 = fmaf(Bs[tt][k],      wdt[k],      p0);
                p1 = fmaf(Bs[tt][4 + k],  wdt[4 + k],  p1);
                p2 = fmaf(Bs[tt][8 + k],  wdt[8 + k],  p2);
                p3 = fmaf(Bs[tt][12 + k], wdt[12 + k], p3);
            }
            float s0 = dtbv + ((p0 + p1) + (p2 + p3));
            float u  = __expf(s0);
            float t2 = __log2f(1.f + u);
            if (s0 > 80.f) t2 = s0 * LOG2E;
            float dt = LN2 * t2;
            cum += dt;
            float dtx = dt * xc[idx];
            float q  = exp2f(t2 * A0nat);
            float q2 = q * q, q3 = q2 * q, q4 = q2 * q2;
            float pv[4] = { q, q2, q3, q4 };
            float r = 1.f;
#pragma unroll
            for (int g = 0; g < 4; g++) {
#pragma unroll
                for (int j = 0; j < 4; j++) {
                    int s = g * 4 + j;
                    float dA = r * pv[j];
                    h[s] = fmaf(dA, h[s], dtx * Bs[tt][16 + s]);
                }
                r *= q4;
            }
        }
    } else {
        for (int tt = 0; tt < SCT; tt++) {
            size_t idx = ((size_t)(c * SCT + tt) * 32 + b) * DI + d;
            float s0 = dtbv;
#pragma unroll
            for (int k = 0; k < DS; k++) s0 = fmaf(Bs[tt][k], wdt[k], s0);
            float dt = (s0 > 20.f) ? s0 : log1pf(expf(s0));
            cum += dt;
            float dtx = dt * xc[idx];
#pragma unroll
            for (int s = 0; s < DS; s++) {
                float dA = exp2f(dt * A2[s]);
                h[s] = fmaf(dA, h[s], dtx * Bs[tt][16 + s]);
            }
        }
    }
    float* hp = hend + ((size_t)(c * 32 + b) * 512 + d) * DS;
#pragma unroll
    for (int s = 0; s < DS; s++) hp[s] = h[s];
    sumdt[((size_t)c * 32 + b) * 512 + d] = cum;
}

// ---------------------------------------------------------------------------
// scan pass B: carry across 32 sub-chunks; hend -> h_init, carry -> hs.
// ---------------------------------------------------------------------------
__global__ __launch_bounds__(256) void k_scanB(
    const float* __restrict__ sumdt, float* __restrict__ hend,
    const float* __restrict__ A_log, float* __restrict__ hs, int first)
{
    int id = blockIdx.x * 256 + threadIdx.x;   // 32*512*16 = 262144
    int s = id & 15;
    int d = (id >> 4) & 511;
    int b = id >> 13;
    float A2 = -__expf(A_log[d * DS + s]) * LOG2E;
    size_t hsi = ((size_t)(b << 9) + d) * DS + s;
    float hin = first ? 0.f : hs[hsi];
    for (int c = 0; c < NSC; c++) {
        size_t hi = ((size_t)(c * 32 + b) * 512 + d) * DS + s;
        float he = hend[hi];
        float sd = sumdt[((size_t)c * 32 + b) * 512 + d];
        hend[hi] = hin;
        hin = fmaf(exp2f(A2 * sd), hin, he);
    }
    hs[hsi] = hin;
}

// ---------------------------------------------------------------------------
// scan pass C (fused dt-proj + partial-reduce, geometric-dA, fast softplus):
// rescan seeded with h_init, y inline, epilogue (y+x*D)*silu(z) ->
// bf16 hi/lo planes yh/yl. grid 2048 blocks.
// ---------------------------------------------------------------------------
__global__ __launch_bounds__(256) void k_scanC(
    const float* __restrict__ xc, const float* __restrict__ part,
    const float* __restrict__ dtw, const float* __restrict__ dtb,
    const float* __restrict__ xz,
    const float* __restrict__ A_log, const float* __restrict__ Dp,
    const float* __restrict__ hinit,
    u16* __restrict__ yh, u16* __restrict__ yl)
{
    int bx = blockIdx.x;
    int b    = bx >> 6;
    int half = (bx >> 5) & 1;
    int c    = bx & 31;
    int d = (half << 8) + threadIdx.x;

    float A2[DS], h[DS], wdt[DS];
    const float* hp = hinit + ((size_t)(c * 32 + b) * 512 + d) * DS;
#pragma unroll
    for (int s = 0; s < DS; s++) {
        A2[s] = -__expf(A_log[d * DS + s]) * LOG2E;
        h[s] = hp[s];
        wdt[s] = dtw[d * DS + s];
    }
    float dtbv = dtb[d];
    float Dv = Dp[d];
    float A20 = A2[0];
    float A0nat = A20 * LN2;
    bool geo = true;
#pragma unroll
    for (int s = 0; s < DS; s++)
        geo = geo && (fabsf(A2[s] - (float)(s + 1) * A20) <=
                      1e-5f * fabsf(A2[s]) + 1e-30f);

    __shared__ float BC[SCT][48];
    {
        const size_t st = (size_t)RC * 48;
        for (int f = threadIdx.x; f < SCT * 48; f += 256) {
            int tt = f / 48, jj = f - tt * 48;
            size_t base = ((size_t)(c * SCT + tt) * 32 + b) * 48 + jj;
            BC[tt][jj] = (part[base] + part[st + base]) +
                         (part[2 * st + base] + part[3 * st + base]);
        }
    }
    __syncthreads();

    if (geo) {
        for (int tt = 0; tt < SCT; tt++) {
            size_t row = (size_t)(c * SCT + tt) * 32 + b;
            size_t idx = row * DI + d;
            float p0 = 0.f, p1 = 0.f, p2 = 0.f, p3 = 0.f;
#pragma unroll
            for (int k = 0; k < 4; k++) {
                p0 = fmaf(BC[tt][k],      wdt[k],      p0);
                p1 = fmaf(BC[tt][4 + k],  wdt[4 + k],  p1);
                p2 = fmaf(BC[tt][8 + k],  wdt[8 + k],  p2);
                p3 = fmaf(BC[tt][12 + k], wdt[12 + k], p3);
            }
            float s0 = dtbv + ((p0 + p1) + (p2 + p3));
            float u  = __expf(s0);
            float t2 = __log2f(1.f + u);
            if (s0 > 80.f) t2 = s0 * LOG2E;
            float dt = LN2 * t2;
            float x  = xc[idx];
            float z  = xz[(row << 10) + 512 + d];
            float dtx = dt * x;
            float y = 0.f;
            float q  = exp2f(t2 * A0nat);
            float q2 = q * q, q3 = q2 * q, q4 = q2 * q2;
            float pv[4] = { q, q2, q3, q4 };
            float r = 1.f;
#pragma unroll
            for (int g = 0; g < 4; g++) {
#pragma unroll
                for (int j = 0; j < 4; j++) {
                    int s = g * 4 + j;
                    float dA = r * pv[j];
                    h[s] = fmaf(dA, h[s], dtx * BC[tt][16 + s]);
                    y = fmaf(h[s], BC[tt][32 + s], y);
                }
                r *= q4;
            }
            float yact = (y + x * Dv) * (z / (1.f + __expf(-z)));
            unsigned hb = f2bf_u(yact);
            yh[row * DI + d] = (u16)hb;
            yl[row * DI + d] = (u16)f2bf_u(yact - __uint_as_float(hb << 16));
        }
    } else {
        for (int tt = 0; tt < SCT; tt++) {
            size_t row = (size_t)(c * SCT + tt) * 32 + b;
            size_t idx = row * DI + d;
            float s0 = dtbv;
#pragma unroll
            for (int k = 0; k < DS; k++) s0 = fmaf(BC[tt][k], wdt[k], s0);
            float dt = (s0 > 20.f) ? s0 : log1pf(expf(s0));
            float x  = xc[idx];
            float z  = xz[(row << 10) + 512 + d];
            float dtx = dt * x;
            float y = 0.f;
#pragma unroll
            for (int s = 0; s < DS; s++) {
                float dA = exp2f(dt * A2[s]);
                h[s] = fmaf(dA, h[s], dtx * BC[tt][16 + s]);
                y = fmaf(h[s], BC[tt][32 + s], y);
            }
            float yact = (y + x * Dv) * (z / (1.f + __expf(-z)));
            unsigned hb = f2bf_u(yact);
            yh[row * DI + d] = (u16)hb;
            yl[row * DI + d] = (u16)f2bf_u(yact - __uint_as_float(hb << 16));
        }
    }
}

// ---------------------------------------------------------------------------
// mean accumulate (partial over 8 tl-slices) / head (sums 8 partials)
// ---------------------------------------------------------------------------
__global__ __launch_bounds__(256) void k_meanacc(
    const float* __restrict__ mo, float* __restrict__ macc, int first)
{
    int b = blockIdx.x, g = blockIdx.y;
    int m = threadIdx.x;
    float s = 0.f;
    const int TLP = CH / 8;
    for (int t = 0; t < TLP; t++) {
        int tl = g * TLP + t;
        s += mo[((size_t)tl * 32 + b) * 256 + m];
    }
    int i = (b * 8 + g) * 256 + m;
    if (first) macc[i] = s;
    else       macc[i] += s;
}

__global__ __launch_bounds__(128) void k_head(
    const float* __restrict__ macc, const float* __restrict__ xst,
    const float* __restrict__ h1w, const float* __restrict__ h1b,
    const float* __restrict__ h2w, const float* __restrict__ h2b,
    float* __restrict__ out)
{
    int b = blockIdx.x;
    int j = threadIdx.x;
    const float* wr = h1w + j * 261;
    const float* mr = macc + (size_t)b * 8 * 256;
    float s = h1b[j];
    for (int k = 0; k < 256; k++) {
        float mv = 0.f;
#pragma unroll
        for (int g = 0; g < 8; g++) mv += mr[g * 256 + k];
        s = fmaf(mv * (1.f / 1024.f), wr[k], s);
    }
    for (int k = 0; k < 5; k++) s = fmaf(xst[b * 5 + k], wr[256 + k], s);
    float e = (s > 0.f) ? s : expm1f(s);

    __shared__ float sb[128];
    sb[j] = e * h2w[j];
    __syncthreads();
    for (int o = 64; o > 0; o >>= 1) {
        if (j < o) sb[j] += sb[j + o];
        __syncthreads();
    }
    if (j == 0) out[b] = sb[0] + h2b[0];
}

// ---------------------------------------------------------------------------
// host side
// ---------------------------------------------------------------------------
static void run_mamba_chunk(hipStream_t stream,
                            const u16* x1h, const u16* x1l, void* const* P,
                            const u16* wih, const u16* wil,
                            const u16* woh, const u16* wol, int out_pairs,
                            float* xzc, float* xcc, float* xpartb,
                            float* moc, u16* moh, u16* mol,
                            u16* yh, u16* yl,
                            float* hendb, float* sumdtb, float* halo,
                            float* hstate, int t0, int save_halo)
{
    const float* cw     = (const float*)P[1];
    const float* cb     = (const float*)P[2];
    const float* xpw    = (const float*)P[3];
    const float* dtw    = (const float*)P[4];
    const float* dtbias = (const float*)P[5];
    const float* Alog   = (const float*)P[6];
    const float* Dp     = (const float*)P[7];
    int first = (t0 == 0);

    k_gmfma<0, false><<<dim3(RC / 128, 1024 / 128), 256, 0, stream>>>(
        x1h, x1l, 256, wih, wil, nullptr, xzc, nullptr, 1024, 256);
    k_conv<<<RC * DI / 1024, 256, 0, stream>>>(xzc, halo, cw, cb, xcc, t0, save_halo);
    k_xpart<<<dim3(RC / 64, 4), 256, 0, stream>>>(xcc, xpw, xpartb, RC, 512, 128);
    k_scanA<<<32 * 2 * NSC, 256, 0, stream>>>(xcc, xpartb, dtw, dtbias, Alog,
                                              hendb, sumdtb);
    k_scanB<<<32 * 512 * DS / 256, 256, 0, stream>>>(sumdtb, hendb, Alog, hstate, first);
    k_scanC<<<32 * 2 * NSC, 256, 0, stream>>>(xcc, xpartb, dtw, dtbias, xzc,
                                              Alog, Dp, hendb, yh, yl);
    if (out_pairs)
        k_gmfma<1, false><<<dim3(RC / 128, 256 / 128), 256, 0, stream>>>(
            yh, yl, 512, woh, wol, nullptr, moh, mol, 256, 512);
    else
        k_gmfma<0, false><<<dim3(RC / 128, 256 / 128), 256, 0, stream>>>(
            yh, yl, 512, woh, wol, nullptr, moc, nullptr, 256, 512);
}

extern "C" void kernel_launch(void* const* d_in, const int* in_sizes, int n_in,
                              void* d_out, int out_size, void* d_ws, size_t ws_size,
                              hipStream_t stream)
{
    const float* xseq = (const float*)d_in[0];
    const float* xst  = (const float*)d_in[1];
    const float* p1w  = (const float*)d_in[2];
    const float* p1b  = (const float*)d_in[3];
    const float* ln1g = (const float*)d_in[4];
    const float* ln1b = (const float*)d_in[5];
    const float* p2w  = (const float*)d_in[6];
    const float* p2b  = (const float*)d_in[7];
    const float* ln2g = (const float*)d_in[8];
    const float* ln2b = (const float*)d_in[9];
    const float* h1w  = (const float*)d_in[10];
    const float* h1b  = (const float*)d_in[11];
    const float* h2w  = (const float*)d_in[12];
    const float* h2b  = (const float*)d_in[13];

    float* ws = (float*)d_ws;
    float* xzc    = ws;                                  // RC*1024 f32
    float* xcc    = xzc  + (size_t)RC * 1024;            // RC*512
    float* moc    = xcc  + (size_t)RC * 512;             // RC*256 f32
    u16*   x1h    = (u16*)(moc + (size_t)RC * 256);      // RC*256 u16
    u16*   x1l    = x1h + (size_t)RC * 256;              // RC*256 u16
    // hend aliases [moc | x1h | x1l] = exactly NSC*32*512*DS floats;
    // all three are dead during the scan phase (liveness audited at CH=512).
    float* hendb  = moc;
    float* after  = (float*)(x1l + (size_t)RC * 256);
    u16*   yh     = (u16*)after;                         // RC*512 u16
    u16*   yl     = yh + (size_t)RC * 512;               // RC*512 u16
    u16*   moh    = yl + (size_t)RC * 512;               // RC*256 u16
    u16*   mol    = moh + (size_t)RC * 256;              // RC*256 u16
    float* sumdtb = (float*)(mol + (size_t)RC * 256);    // NSC*32*512
    float* halo1  = sumdtb + NSC * 32 * 512;             // 3*32*512
    float* halo2  = halo1 + 3 * 32 * 512;
    float* hs1    = halo2 + 3 * 32 * 512;                // 32*512*16
    float* hs2    = hs1  + 32 * 512 * DS;
    float* macc   = hs2  + 32 * 512 * DS;                // 32*8*256
    u16*   wm1ih  = (u16*)(macc + 32 * 8 * 256);         // 1024*256 u16 each
    u16*   wm1il  = wm1ih + 262144;
    u16*   wm1oh  = wm1il + 262144;                      // 256*512 u16 each
    u16*   wm1ol  = wm1oh + 131072;
    u16*   wm2ih  = wm1ol + 131072;
    u16*   wm2il  = wm2ih + 262144;
    u16*   wm2oh  = wm2il + 262144;
    u16*   wm2ol  = wm2oh + 131072;
    u16*   wp2h   = wm2ol + 131072;                      // 256*256 u16 each
    u16*   wp2l   = wp2h + 65536;
    float* xpartb = (float*)(wp2l + 65536);              // 4*RC*48 f32
    size_t need = (size_t)((char*)(xpartb + 4 * (size_t)RC * 48) - (char*)ws);
    if (ws_size < need) return;   // tripwire: fail cleanly, don't fault

    // weight bf16 hi/lo plane conversion (single fused launch)
    k_wcvt_all<<<3332, 256, 0, stream>>>(
        (const float*)d_in[14], (const float*)d_in[22],
        (const float*)d_in[23], (const float*)d_in[31], p2w,
        wm1ih, wm1il, wm1oh, wm1ol, wm2ih, wm2il, wm2oh, wm2ol, wp2h, wp2l);

    for (int c = 0; c < NCH; c++) {
        int t0 = c * CH;
        int first = (c == 0);
        int save_halo = (c != NCH - 1);

        k_p1_ln<<<RC, 256, 0, stream>>>(xseq, p1w, p1b, ln1g, ln1b, x1h, x1l, t0);

        // mamba 1 (params d_in[14..22]); out_proj emits hi/lo planes for p2
        run_mamba_chunk(stream, x1h, x1l, d_in + 14, wm1ih, wm1il, wm1oh, wm1ol, 1,
                        xzc, xcc, xpartb, moc, moh, mol, yh, yl,
                        hendb, sumdtb, halo1, hs1, t0, save_halo);

        // p2 + LN2
        k_gmfma<0, true><<<dim3(RC / 128, 256 / 128), 256, 0, stream>>>(
            moh, mol, 256, wp2h, wp2l, p2b, xzc, nullptr, 256, 256);
        k_ln<<<RC, 256, 0, stream>>>(xzc, ln2g, ln2b, x1h, x1l);

        // mamba 2 (params d_in[23..31]); out_proj emits f32 for meanacc
        run_mamba_chunk(stream, x1h, x1l, d_in + 23, wm2ih, wm2il, wm2oh, wm2ol, 0,
                        xzc, xcc, xpartb, moc, moh, mol, yh, yl,
                        hendb, sumdtb, halo2, hs2, t0, save_halo);

        k_meanacc<<<dim3(NB, 8), 256, 0, stream>>>(moc, macc, first);
    }

    k_head<<<NB, 128, 0, stream>>>(macc, xst, h1w, h1b, h2w, h2b, (float*)d_out);
}

// Round 15
// 780.316 us; speedup vs baseline: 2.5854x; 1.0763x over previous
//
#include <hip/hip_runtime.h>
#include <math.h>

#define NB 32
#define L  1024
#define CH 512                 // timesteps per chunk
#define NCH (L / CH)           // 2 chunks
#define RC (NB * CH)           // 16384 rows per chunk
#define DM 256
#define DI 512
#define DS 16
#define SCT 16                 // sub-chunk timesteps (scan)
#define NSC (CH / SCT)         // 32 sub-chunks
#define LOG2E 1.44269504f
#define LN2   0.69314718f

typedef short short8 __attribute__((ext_vector_type(8)));
typedef float f32x4 __attribute__((ext_vector_type(4)));
typedef unsigned short u16;

// bf16 split helpers: x ~= hi + lo, both bf16 (rne).
__device__ inline unsigned f2bf_u(float x) {
    unsigned u = __float_as_uint(x);
    return (u + 0x7fffu + ((u >> 16) & 1u)) >> 16;
}

// Layout: per-chunk activations use (t_local, b, feat): row r = t_local*32 + b.

// ---------------------------------------------------------------------------
// p1 (K=4) + bias + LayerNorm; emits bf16 hi/lo PLANES for MFMA in_proj.
// ---------------------------------------------------------------------------
__global__ __launch_bounds__(256) void k_p1_ln(
    const float* __restrict__ xseq, const float* __restrict__ w,
    const float* __restrict__ bias, const float* __restrict__ g,
    const float* __restrict__ bb, u16* __restrict__ outh, u16* __restrict__ outl,
    int t0)
{
    int r  = blockIdx.x;
    int b  = r & 31;
    int tl = r >> 5;
    int m  = threadIdx.x;
    const float* xr = xseq + ((size_t)b * L + t0 + tl) * 4;
    float x0 = xr[0], x1 = xr[1], x2 = xr[2], x3 = xr[3];
    const float* wr = w + m * 4;
    float v = bias[m] + x0 * wr[0] + x1 * wr[1] + x2 * wr[2] + x3 * wr[3];

    __shared__ float s1[4], s2[4];
    float a = v, bq = v * v;
    for (int o = 32; o > 0; o >>= 1) { a += __shfl_down(a, o); bq += __shfl_down(bq, o); }
    int wid = m >> 6, lane = m & 63;
    if (lane == 0) { s1[wid] = a; s2[wid] = bq; }
    __syncthreads();
    if (m == 0) {
        s1[0] = s1[0] + s1[1] + s1[2] + s1[3];
        s2[0] = s2[0] + s2[1] + s2[2] + s2[3];
    }
    __syncthreads();
    float mu  = s1[0] * (1.f / 256.f);
    float var = s2[0] * (1.f / 256.f) - mu * mu;
    float o2 = (v - mu) * rsqrtf(var + 1e-5f) * g[m] + bb[m];
    unsigned hb = f2bf_u(o2);
    outh[(size_t)r * 256 + m] = (u16)hb;
    outl[(size_t)r * 256 + m] = (u16)f2bf_u(o2 - __uint_as_float(hb << 16));
}

// ---------------------------------------------------------------------------
// LayerNorm over 256; fp32 in, bf16 hi/lo planes out.
// ---------------------------------------------------------------------------
__global__ __launch_bounds__(256) void k_ln(
    const float* __restrict__ in, const float* __restrict__ g,
    const float* __restrict__ bb, u16* __restrict__ outh, u16* __restrict__ outl)
{
    int r = blockIdx.x;
    int m = threadIdx.x;
    float v = in[(size_t)r * 256 + m];

    __shared__ float s1[4], s2[4];
    float a = v, bq = v * v;
    for (int o = 32; o > 0; o >>= 1) { a += __shfl_down(a, o); bq += __shfl_down(bq, o); }
    int wid = m >> 6, lane = m & 63;
    if (lane == 0) { s1[wid] = a; s2[wid] = bq; }
    __syncthreads();
    if (m == 0) {
        s1[0] = s1[0] + s1[1] + s1[2] + s1[3];
        s2[0] = s2[0] + s2[1] + s2[2] + s2[3];
    }
    __syncthreads();
    float mu  = s1[0] * (1.f / 256.f);
    float var = s2[0] * (1.f / 256.f) - mu * mu;
    float o2 = (v - mu) * rsqrtf(var + 1e-5f) * g[m] + bb[m];
    unsigned hb = f2bf_u(o2);
    outh[(size_t)r * 256 + m] = (u16)hb;
    outl[(size_t)r * 256 + m] = (u16)f2bf_u(o2 - __uint_as_float(hb << 16));
}

// ---------------------------------------------------------------------------
// in_proj weight conversion (2 matrices) -> hi/lo planes, 1 launch.
// ---------------------------------------------------------------------------
__global__ __launch_bounds__(256) void k_wcvt2(
    const float* __restrict__ w1i, const float* __restrict__ w2i,
    u16* __restrict__ o1h, u16* __restrict__ o1l,
    u16* __restrict__ o2h, u16* __restrict__ o2l)
{
    int i = blockIdx.x * 256 + threadIdx.x;     // 524288, grid 2048
    const float* src; u16 *oh, *ol; int j;
    if (i < 262144) { src = w1i; oh = o1h; ol = o1l; j = i; }
    else            { src = w2i; oh = o2h; ol = o2l; j = i - 262144; }
    float v = src[j];
    unsigned hb = f2bf_u(v);
    oh[j] = (u16)hb;
    ol[j] = (u16)f2bf_u(v - __uint_as_float(hb << 16));
}

// ---------------------------------------------------------------------------
// combined weight Wc = Wp2 @ Wo1  ([256,256]x[256,512] -> [256,512]),
// packed to hi/lo planes.  (y@Wo1^T)@Wp2^T + b == y@Wc^T + b  (exact algebra)
// ---------------------------------------------------------------------------
__global__ __launch_bounds__(256) void k_wcomb(
    const float* __restrict__ p2w, const float* __restrict__ outw,
    u16* __restrict__ och, u16* __restrict__ ocl)
{
    int idx = blockIdx.x * 256 + threadIdx.x;   // 131072, grid 512
    int n = idx >> 9, k = idx & 511;
    const float* pr = p2w + n * 256;
    float s = 0.f;
    for (int j = 0; j < 256; j++)
        s = fmaf(pr[j], outw[(size_t)j * 512 + k], s);
    unsigned hb = f2bf_u(s);
    och[idx] = (u16)hb;
    ocl[idx] = (u16)f2bf_u(s - __uint_as_float(hb << 16));
}

// ---------------------------------------------------------------------------
// split-bf16 MFMA GEMM (3-term): C[M,N] = A[M,K]*W[N,K]^T (+bias).
// A,W as separate hi/lo bf16 planes. 128x128 tile, BK=32.
// fp32 output only (plane-out no longer needed).
// ---------------------------------------------------------------------------
template <bool BIAS>
__global__ __launch_bounds__(256) void k_gmfma(
    const u16* __restrict__ Ahg, const u16* __restrict__ Alg, int lda,
    const u16* __restrict__ Whg, const u16* __restrict__ Wlg,
    const float* __restrict__ bias, float* __restrict__ C0,
    int N, int K)
{
    __shared__ u16 Ah[128 * 40], Al[128 * 40];
    __shared__ u16 Wh[128 * 40], Wl[128 * 40];

    int tid = threadIdx.x;
    int wv = tid >> 6, ln = tid & 63;
    int wr = wv >> 1, wc = wv & 1;
    int m0 = blockIdx.x * 128, n0 = blockIdx.y * 128;
    int sr = tid >> 1, sk = (tid & 1) << 4;
    int frow = ln & 15, fk = (ln >> 4) << 3;

    f32x4 acc[4][4] = {};

    for (int k0 = 0; k0 < K; k0 += 32) {
        const u16* ah = Ahg + (size_t)(m0 + sr) * lda + k0 + sk;
        const u16* al = Alg + (size_t)(m0 + sr) * lda + k0 + sk;
        const u16* wh = Whg + (size_t)(n0 + sr) * K + k0 + sk;
        const u16* wl = Wlg + (size_t)(n0 + sr) * K + k0 + sk;
        short8 vah0 = *(const short8*)ah, vah1 = *(const short8*)(ah + 8);
        short8 val0 = *(const short8*)al, val1 = *(const short8*)(al + 8);
        short8 vwh0 = *(const short8*)wh, vwh1 = *(const short8*)(wh + 8);
        short8 vwl0 = *(const short8*)wl, vwl1 = *(const short8*)(wl + 8);

        __syncthreads();   // previous iteration's frag reads done

        *(short8*)&Ah[sr * 40 + sk]     = vah0;
        *(short8*)&Ah[sr * 40 + sk + 8] = vah1;
        *(short8*)&Al[sr * 40 + sk]     = val0;
        *(short8*)&Al[sr * 40 + sk + 8] = val1;
        *(short8*)&Wh[sr * 40 + sk]     = vwh0;
        *(short8*)&Wh[sr * 40 + sk + 8] = vwh1;
        *(short8*)&Wl[sr * 40 + sk]     = vwl0;
        *(short8*)&Wl[sr * 40 + sk + 8] = vwl1;

        __syncthreads();

        short8 afh[4], afl[4], wfh[4], wfl[4];
#pragma unroll
        for (int g = 0; g < 4; g++) {
            int ra = (wr * 64 + g * 16 + frow) * 40 + fk;
            int rw = (wc * 64 + g * 16 + frow) * 40 + fk;
            afh[g] = *(const short8*)&Ah[ra];
            afl[g] = *(const short8*)&Al[ra];
            wfh[g] = *(const short8*)&Wh[rw];
            wfl[g] = *(const short8*)&Wl[rw];
        }
#pragma unroll
        for (int mg = 0; mg < 4; mg++)
#pragma unroll
            for (int ng = 0; ng < 4; ng++) {
                acc[mg][ng] = __builtin_amdgcn_mfma_f32_16x16x32_bf16(afh[mg], wfh[ng], acc[mg][ng], 0, 0, 0);
                acc[mg][ng] = __builtin_amdgcn_mfma_f32_16x16x32_bf16(afh[mg], wfl[ng], acc[mg][ng], 0, 0, 0);
                acc[mg][ng] = __builtin_amdgcn_mfma_f32_16x16x32_bf16(afl[mg], wfh[ng], acc[mg][ng], 0, 0, 0);
            }
    }

    // C layout: col=lane&15, row=(lane>>4)*4+reg  [verified m89]
#pragma unroll
    for (int ng = 0; ng < 4; ng++) {
        int col = n0 + wc * 64 + ng * 16 + frow;
        float bv = BIAS ? bias[col] : 0.f;
#pragma unroll
        for (int mg = 0; mg < 4; mg++)
#pragma unroll
            for (int r = 0; r < 4; r++) {
                int row = m0 + wr * 64 + mg * 16 + (ln >> 4) * 4 + r;
                C0[(size_t)row * N + col] = acc[mg][ng][r] + bv;
            }
    }
}

// ---------------------------------------------------------------------------
// xproj K-split partial GEMM: Cpart[slice][M][48] = A[:, ks..ks+128) * W^T.
// grid (M/64, 4). Partials summed inside the scans (exact dbr order).
// ---------------------------------------------------------------------------
__global__ __launch_bounds__(256) void k_xpart(
    const float* __restrict__ A, const float* __restrict__ W,
    float* __restrict__ Cpart, int M, int K, int kcnt)
{
    const int BM = 64, BK = 16;
    __shared__ float As[BK][BM];
    __shared__ float Ws[BK][64];

    int m0   = blockIdx.x * BM;
    int kbeg = blockIdx.y * kcnt;
    int tid = threadIdx.x;
    int tx  = tid & 15, ty = tid >> 4;
    int lr  = tid >> 2;
    int lc  = (tid & 3) * 4;

    float acc[4][4] = {};

    for (int k0 = kbeg; k0 < kbeg + kcnt; k0 += BK) {
        float4 av = *(const float4*)(A + (size_t)(m0 + lr) * K + k0 + lc);
        As[lc + 0][lr] = av.x; As[lc + 1][lr] = av.y;
        As[lc + 2][lr] = av.z; As[lc + 3][lr] = av.w;
        float4 wv = make_float4(0.f, 0.f, 0.f, 0.f);
        if (lr < 48) wv = *(const float4*)(W + (size_t)lr * K + k0 + lc);
        Ws[lc + 0][lr] = wv.x; Ws[lc + 1][lr] = wv.y;
        Ws[lc + 2][lr] = wv.z; Ws[lc + 3][lr] = wv.w;
        __syncthreads();
#pragma unroll
        for (int k = 0; k < BK; k++) {
            float a[4], bv[4];
            *(float4*)a  = *(const float4*)&As[k][ty * 4];
            *(float4*)bv = *(const float4*)&Ws[k][tx * 4];
#pragma unroll
            for (int i = 0; i < 4; i++)
#pragma unroll
                for (int j = 0; j < 4; j++)
                    acc[i][j] = fmaf(a[i], bv[j], acc[i][j]);
        }
        __syncthreads();
    }

    int n = tx * 4;
    if (n < 48) {
        float* cp = Cpart + (size_t)blockIdx.y * M * 48;
#pragma unroll
        for (int i = 0; i < 4; i++) {
            float4 v = make_float4(acc[i][0], acc[i][1], acc[i][2], acc[i][3]);
            *(float4*)(cp + (size_t)(m0 + ty * 4 + i) * 48 + n) = v;
        }
    }
}

// ---------------------------------------------------------------------------
// depthwise causal conv1d (k=4) + SiLU, float4-vectorized, fused halo-save.
// ---------------------------------------------------------------------------
__global__ __launch_bounds__(256) void k_conv(
    const float* __restrict__ xz, float* __restrict__ halo,
    const float* __restrict__ cw, const float* __restrict__ cb,
    float* __restrict__ xc, int t0, int save_halo)
{
    size_t i4 = ((size_t)blockIdx.x * 256 + threadIdx.x) * 4;   // over RC*512
    int d  = (int)(i4 & 511);
    int r  = (int)(i4 >> 9);
    int b  = r & 31;
    int tl = r >> 5;

    float4 w0 = *(const float4*)(cw + (d + 0) * 4);
    float4 w1 = *(const float4*)(cw + (d + 1) * 4);
    float4 w2 = *(const float4*)(cw + (d + 2) * 4);
    float4 w3 = *(const float4*)(cw + (d + 3) * 4);
    float4 acc = *(const float4*)(cb + d);
    float4 vlast = make_float4(0.f, 0.f, 0.f, 0.f);

#pragma unroll
    for (int k = 0; k < 4; k++) {
        int tsl = tl - 3 + k;
        float4 v;
        if (tsl >= 0)
            v = *(const float4*)(xz + ((size_t)tsl * 32 + b) * 1024 + d);
        else if (t0 + tsl >= 0)
            v = *(const float4*)(halo + ((size_t)(tsl + 3) * 32 + b) * 512 + d);
        else
            continue;
        if (k == 3) vlast = v;
        acc.x = fmaf((&w0.x)[k], v.x, acc.x);
        acc.y = fmaf((&w1.x)[k], v.y, acc.y);
        acc.z = fmaf((&w2.x)[k], v.z, acc.z);
        acc.w = fmaf((&w3.x)[k], v.w, acc.w);
    }
    float4 o;
    o.x = acc.x / (1.f + __expf(-acc.x));
    o.y = acc.y / (1.f + __expf(-acc.y));
    o.z = acc.z / (1.f + __expf(-acc.z));
    o.w = acc.w / (1.f + __expf(-acc.w));
    *(float4*)(xc + i4) = o;

    if (save_halo && tl >= CH - 3)
        *(float4*)(halo + ((size_t)(tl - (CH - 3)) * 32 + b) * 512 + d) = vlast;
}

// ---------------------------------------------------------------------------
// scan pass A (fused dt-proj + partial-reduce, geometric-dA fast path).
// ---------------------------------------------------------------------------
__global__ __launch_bounds__(256) void k_scanA(
    const float* __restrict__ xc, const float* __restrict__ part,
    const float* __restrict__ dtw, const float* __restrict__ dtb,
    const float* __restrict__ A_log,
    float* __restrict__ hend, float* __restrict__ sumdt)
{
    int bx = blockIdx.x;
    int b    = bx >> 6;
    int half = (bx >> 5) & 1;
    int c    = bx & 31;
    int d = (half << 8) + threadIdx.x;

    float A2[DS], h[DS], wdt[DS];
#pragma unroll
    for (int s = 0; s < DS; s++) {
        A2[s] = -__expf(A_log[d * DS + s]) * LOG2E;
        h[s] = 0.f;
        wdt[s] = dtw[d * DS + s];
    }
    float dtbv = dtb[d];
    float A20 = A2[0];
    float A0nat = A20 * LN2;
    bool geo = true;
#pragma unroll
    for (int s = 0; s < DS; s++)
        geo = geo && (fabsf(A2[s] - (float)(s + 1) * A20) <=
                      1e-5f * fabsf(A2[s]) + 1e-30f);

    __shared__ float Bs[SCT][48];
    {
        const size_t st = (size_t)RC * 48;
        for (int f = threadIdx.x; f < SCT * 48; f += 256) {
            int tt = f / 48, jj = f - tt * 48;
            size_t base = ((size_t)(c * SCT + tt) * 32 + b) * 48 + jj;
            Bs[tt][jj] = (part[base] + part[st + base]) +
                         (part[2 * st + base] + part[3 * st + base]);
        }
    }
    __syncthreads();

    float cum = 0.f;
    if (geo) {
        for (int tt = 0; tt < SCT; tt++) {
            size_t idx = ((size_t)(c * SCT + tt) * 32 + b) * DI + d;
            float p0 = 0.f, p1 = 0.f, p2 = 0.f, p3 = 0.f;
#pragma unroll
            for (int k = 0; k < 4; k++) {
                p0 = fmaf(Bs[tt][k],      wdt[k],      p0);
                p1 = fmaf(Bs[tt][4 + k],  wdt[4 + k],  p1);
                p2 = fmaf(Bs[tt][8 + k],  wdt[8 + k],  p2);
                p3 = fmaf(Bs[tt][12 + k], wdt[12 + k], p3);
            }
            float s0 = dtbv + ((p0 + p1) + (p2 + p3));
            float u  = __expf(s0);
            float t2 = __log2f(1.f + u);
            if (s0 > 80.f) t2 = s0 * LOG2E;
            float dt = LN2 * t2;
            cum += dt;
            float dtx = dt * xc[idx];
            float q  = exp2f(t2 * A0nat);
            float q2 = q * q, q3 = q2 * q, q4 = q2 * q2;
            float pv[4] = { q, q2, q3, q4 };
            float r = 1.f;
#pragma unroll
            for (int g = 0; g < 4; g++) {
#pragma unroll
                for (int j = 0; j < 4; j++) {
                    int s = g * 4 + j;
                    float dA = r * pv[j];
                    h[s] = fmaf(dA, h[s], dtx * Bs[tt][16 + s]);
                }
                r *= q4;
            }
        }
    } else {
        for (int tt = 0; tt < SCT; tt++) {
            size_t idx = ((size_t)(c * SCT + tt) * 32 + b) * DI + d;
            float s0 = dtbv;
#pragma unroll
            for (int k = 0; k < DS; k++) s0 = fmaf(Bs[tt][k], wdt[k], s0);
            float dt = (s0 > 20.f) ? s0 : log1pf(expf(s0));
            cum += dt;
            float dtx = dt * xc[idx];
#pragma unroll
            for (int s = 0; s < DS; s++) {
                float dA = exp2f(dt * A2[s]);
                h[s] = fmaf(dA, h[s], dtx * Bs[tt][16 + s]);
            }
        }
    }
    float* hp = hend + ((size_t)(c * 32 + b) * 512 + d) * DS;
#pragma unroll
    for (int s = 0; s < DS; s++) hp[s] = h[s];
    sumdt[((size_t)c * 32 + b) * 512 + d] = cum;
}

// ---------------------------------------------------------------------------
// scan pass B: carry across 32 sub-chunks; hend -> h_init, carry -> hs.
// ---------------------------------------------------------------------------
__global__ __launch_bounds__(256) void k_scanB(
    const float* __restrict__ sumdt, float* __restrict__ hend,
    const float* __restrict__ A_log, float* __restrict__ hs, int first)
{
    int id = blockIdx.x * 256 + threadIdx.x;   // 32*512*16 = 262144
    int s = id & 15;
    int d = (id >> 4) & 511;
    int b = id >> 13;
    float A2 = -__expf(A_log[d * DS + s]) * LOG2E;
    size_t hsi = ((size_t)(b << 9) + d) * DS + s;
    float hin = first ? 0.f : hs[hsi];
    for (int c = 0; c < NSC; c++) {
        size_t hi = ((size_t)(c * 32 + b) * 512 + d) * DS + s;
        float he = hend[hi];
        float sd = sumdt[((size_t)c * 32 + b) * 512 + d];
        hend[hi] = hin;
        hin = fmaf(exp2f(A2 * sd), hin, he);
    }
    hs[hsi] = hin;
}

// ---------------------------------------------------------------------------
// scan pass C (fused dt-proj + partial-reduce, geometric-dA, fast softplus):
// rescan seeded with h_init, y inline, epilogue (y+x*D)*silu(z) ->
// bf16 hi/lo planes yh/yl. grid 2048 blocks.
// ---------------------------------------------------------------------------
__global__ __launch_bounds__(256) void k_scanC(
    const float* __restrict__ xc, const float* __restrict__ part,
    const float* __restrict__ dtw, const float* __restrict__ dtb,
    const float* __restrict__ xz,
    const float* __restrict__ A_log, const float* __restrict__ Dp,
    const float* __restrict__ hinit,
    u16* __restrict__ yh, u16* __restrict__ yl)
{
    int bx = blockIdx.x;
    int b    = bx >> 6;
    int half = (bx >> 5) & 1;
    int c    = bx & 31;
    int d = (half << 8) + threadIdx.x;

    float A2[DS], h[DS], wdt[DS];
    const float* hp = hinit + ((size_t)(c * 32 + b) * 512 + d) * DS;
#pragma unroll
    for (int s = 0; s < DS; s++) {
        A2[s] = -__expf(A_log[d * DS + s]) * LOG2E;
        h[s] = hp[s];
        wdt[s] = dtw[d * DS + s];
    }
    float dtbv = dtb[d];
    float Dv = Dp[d];
    float A20 = A2[0];
    float A0nat = A20 * LN2;
    bool geo = true;
#pragma unroll
    for (int s = 0; s < DS; s++)
        geo = geo && (fabsf(A2[s] - (float)(s + 1) * A20) <=
                      1e-5f * fabsf(A2[s]) + 1e-30f);

    __shared__ float BC[SCT][48];
    {
        const size_t st = (size_t)RC * 48;
        for (int f = threadIdx.x; f < SCT * 48; f += 256) {
            int tt = f / 48, jj = f - tt * 48;
            size_t base = ((size_t)(c * SCT + tt) * 32 + b) * 48 + jj;
            BC[tt][jj] = (part[base] + part[st + base]) +
                         (part[2 * st + base] + part[3 * st + base]);
        }
    }
    __syncthreads();

    if (geo) {
        for (int tt = 0; tt < SCT; tt++) {
            size_t row = (size_t)(c * SCT + tt) * 32 + b;
            size_t idx = row * DI + d;
            float p0 = 0.f, p1 = 0.f, p2 = 0.f, p3 = 0.f;
#pragma unroll
            for (int k = 0; k < 4; k++) {
                p0 = fmaf(BC[tt][k],      wdt[k],      p0);
                p1 = fmaf(BC[tt][4 + k],  wdt[4 + k],  p1);
                p2 = fmaf(BC[tt][8 + k],  wdt[8 + k],  p2);
                p3 = fmaf(BC[tt][12 + k], wdt[12 + k], p3);
            }
            float s0 = dtbv + ((p0 + p1) + (p2 + p3));
            float u  = __expf(s0);
            float t2 = __log2f(1.f + u);
            if (s0 > 80.f) t2 = s0 * LOG2E;
            float dt = LN2 * t2;
            float x  = xc[idx];
            float z  = xz[(row << 10) + 512 + d];
            float dtx = dt * x;
            float y = 0.f;
            float q  = exp2f(t2 * A0nat);
            float q2 = q * q, q3 = q2 * q, q4 = q2 * q2;
            float pv[4] = { q, q2, q3, q4 };
            float r = 1.f;
#pragma unroll
            for (int g = 0; g < 4; g++) {
#pragma unroll
                for (int j = 0; j < 4; j++) {
                    int s = g * 4 + j;
                    float dA = r * pv[j];
                    h[s] = fmaf(dA, h[s], dtx * BC[tt][16 + s]);
                    y = fmaf(h[s], BC[tt][32 + s], y);
                }
                r *= q4;
            }
            float yact = (y + x * Dv) * (z / (1.f + __expf(-z)));
            unsigned hb = f2bf_u(yact);
            yh[row * DI + d] = (u16)hb;
            yl[row * DI + d] = (u16)f2bf_u(yact - __uint_as_float(hb << 16));
        }
    } else {
        for (int tt = 0; tt < SCT; tt++) {
            size_t row = (size_t)(c * SCT + tt) * 32 + b;
            size_t idx = row * DI + d;
            float s0 = dtbv;
#pragma unroll
            for (int k = 0; k < DS; k++) s0 = fmaf(BC[tt][k], wdt[k], s0);
            float dt = (s0 > 20.f) ? s0 : log1pf(expf(s0));
            float x  = xc[idx];
            float z  = xz[(row << 10) + 512 + d];
            float dtx = dt * x;
            float y = 0.f;
#pragma unroll
            for (int s = 0; s < DS; s++) {
                float dA = exp2f(dt * A2[s]);
                h[s] = fmaf(dA, h[s], dtx * BC[tt][16 + s]);
                y = fmaf(h[s], BC[tt][32 + s], y);
            }
            float yact = (y + x * Dv) * (z / (1.f + __expf(-z)));
            unsigned hb = f2bf_u(yact);
            yh[row * DI + d] = (u16)hb;
            yl[row * DI + d] = (u16)f2bf_u(yact - __uint_as_float(hb << 16));
        }
    }
}

// ---------------------------------------------------------------------------
// mean accumulate over y planes (512-dim), partial over 8 tl-slices.
// mean_t(y @ Wo2^T) == mean_t(y) @ Wo2^T  -> out_proj2 folded into k_prehead.
// ---------------------------------------------------------------------------
__global__ __launch_bounds__(512) void k_meanacc(
    const u16* __restrict__ yh, const u16* __restrict__ yl,
    float* __restrict__ macc, int first)
{
    int b = blockIdx.x, g = blockIdx.y;
    int q = threadIdx.x;                    // 0..511
    float s = 0.f;
    const int TLP = CH / 8;                 // 64
    for (int t = 0; t < TLP; t++) {
        size_t i = ((size_t)(g * TLP + t) * 32 + b) * 512 + q;
        s += __uint_as_float((unsigned)yh[i] << 16) +
             __uint_as_float((unsigned)yl[i] << 16);
    }
    int i = (b * 8 + g) * 512 + q;
    if (first) macc[i] = s;
    else       macc[i] += s;
}

// prehead: mm[b][n] = (1/1024) * sum_q Wo2[n][q] * (sum_g macc[b][g][q])
__global__ __launch_bounds__(256) void k_prehead(
    const float* __restrict__ macc, const float* __restrict__ wo2,
    float* __restrict__ mm)
{
    int b = blockIdx.x;
    int n = threadIdx.x;
    __shared__ float ys[512];
    for (int q = threadIdx.x; q < 512; q += 256) {
        float s = 0.f;
#pragma unroll
        for (int g = 0; g < 8; g++) s += macc[(b * 8 + g) * 512 + q];
        ys[q] = s;
    }
    __syncthreads();
    const float* wr = wo2 + (size_t)n * 512;
    float s = 0.f;
    for (int q = 0; q < 512; q += 4) {
        float4 w = *(const float4*)(wr + q);
        s = fmaf(w.x, ys[q + 0], s);
        s = fmaf(w.y, ys[q + 1], s);
        s = fmaf(w.z, ys[q + 2], s);
        s = fmaf(w.w, ys[q + 3], s);
    }
    mm[b * 256 + n] = s * (1.f / 1024.f);
}

__global__ __launch_bounds__(128) void k_head(
    const float* __restrict__ mm, const float* __restrict__ xst,
    const float* __restrict__ h1w, const float* __restrict__ h1b,
    const float* __restrict__ h2w, const float* __restrict__ h2b,
    float* __restrict__ out)
{
    int b = blockIdx.x;
    int j = threadIdx.x;
    const float* wr = h1w + j * 261;
    const float* mr = mm + b * 256;
    float s = h1b[j];
    for (int k = 0; k < 256; k++) s = fmaf(mr[k], wr[k], s);
    for (int k = 0; k < 5; k++) s = fmaf(xst[b * 5 + k], wr[256 + k], s);
    float e = (s > 0.f) ? s : expm1f(s);

    __shared__ float sb[128];
    sb[j] = e * h2w[j];
    __syncthreads();
    for (int o = 64; o > 0; o >>= 1) {
        if (j < o) sb[j] += sb[j + o];
        __syncthreads();
    }
    if (j == 0) out[b] = sb[0] + h2b[0];
}

// ---------------------------------------------------------------------------
// host side
// ---------------------------------------------------------------------------
static void run_mamba_core(hipStream_t stream,
                           const u16* x1h, const u16* x1l, void* const* P,
                           const u16* wih, const u16* wil,
                           float* xzc, float* xcc, float* xpartb,
                           u16* yh, u16* yl,
                           float* hendb, float* sumdtb, float* halo,
                           float* hstate, int t0, int save_halo)
{
    const float* cw     = (const float*)P[1];
    const float* cb     = (const float*)P[2];
    const float* xpw    = (const float*)P[3];
    const float* dtw    = (const float*)P[4];
    const float* dtbias = (const float*)P[5];
    const float* Alog   = (const float*)P[6];
    const float* Dp     = (const float*)P[7];
    int first = (t0 == 0);

    k_gmfma<false><<<dim3(RC / 128, 1024 / 128), 256, 0, stream>>>(
        x1h, x1l, 256, wih, wil, nullptr, xzc, 1024, 256);
    k_conv<<<RC * DI / 1024, 256, 0, stream>>>(xzc, halo, cw, cb, xcc, t0, save_halo);
    k_xpart<<<dim3(RC / 64, 4), 256, 0, stream>>>(xcc, xpw, xpartb, RC, 512, 128);
    k_scanA<<<32 * 2 * NSC, 256, 0, stream>>>(xcc, xpartb, dtw, dtbias, Alog,
                                              hendb, sumdtb);
    k_scanB<<<32 * 512 * DS / 256, 256, 0, stream>>>(sumdtb, hendb, Alog, hstate, first);
    k_scanC<<<32 * 2 * NSC, 256, 0, stream>>>(xcc, xpartb, dtw, dtbias, xzc,
                                              Alog, Dp, hendb, yh, yl);
}

extern "C" void kernel_launch(void* const* d_in, const int* in_sizes, int n_in,
                              void* d_out, int out_size, void* d_ws, size_t ws_size,
                              hipStream_t stream)
{
    const float* xseq = (const float*)d_in[0];
    const float* xst  = (const float*)d_in[1];
    const float* p1w  = (const float*)d_in[2];
    const float* p1b  = (const float*)d_in[3];
    const float* ln1g = (const float*)d_in[4];
    const float* ln1b = (const float*)d_in[5];
    const float* p2w  = (const float*)d_in[6];
    const float* p2b  = (const float*)d_in[7];
    const float* ln2g = (const float*)d_in[8];
    const float* ln2b = (const float*)d_in[9];
    const float* h1w  = (const float*)d_in[10];
    const float* h1b  = (const float*)d_in[11];
    const float* h2w  = (const float*)d_in[12];
    const float* h2b  = (const float*)d_in[13];
    const float* wo1  = (const float*)d_in[22];   // m1 out_w [256,512]
    const float* wo2  = (const float*)d_in[31];   // m2 out_w [256,512]

    float* ws = (float*)d_ws;
    float* xzc    = ws;                                  // RC*1024 f32
    float* xcc    = xzc  + (size_t)RC * 1024;            // RC*512
    // hend region: RC*512 floats; x1 planes (dead during scans) alias its head
    float* hendb  = xcc  + (size_t)RC * 512;
    u16*   x1h    = (u16*)hendb;                         // RC*256 u16
    u16*   x1l    = x1h + (size_t)RC * 256;              // RC*256 u16
    u16*   yh     = (u16*)(hendb + (size_t)RC * 512);    // RC*512 u16
    u16*   yl     = yh + (size_t)RC * 512;               // RC*512 u16
    float* sumdtb = (float*)(yl + (size_t)RC * 512);     // NSC*32*512
    float* halo1  = sumdtb + NSC * 32 * 512;             // 3*32*512
    float* halo2  = halo1 + 3 * 32 * 512;
    float* hs1    = halo2 + 3 * 32 * 512;                // 32*512*16
    float* hs2    = hs1  + 32 * 512 * DS;
    float* macc   = hs2  + 32 * 512 * DS;                // 32*8*512
    float* mm     = macc + 32 * 8 * 512;                 // 32*256
    u16*   wm1ih  = (u16*)(mm + 32 * 256);               // 1024*256 u16 each
    u16*   wm1il  = wm1ih + 262144;
    u16*   wm2ih  = wm1il + 262144;
    u16*   wm2il  = wm2ih + 262144;
    u16*   wch    = wm2il + 262144;                      // 256*512 u16 each
    u16*   wcl    = wch + 131072;
    float* xpartb = (float*)(wcl + 131072);              // 4*RC*48 f32
    size_t need = (size_t)((char*)(xpartb + 4 * (size_t)RC * 48) - (char*)ws);
    if (ws_size < need) return;   // tripwire: fail cleanly, don't fault

    // weight prep (2 launches total)
    k_wcvt2<<<2048, 256, 0, stream>>>(
        (const float*)d_in[14], (const float*)d_in[23],
        wm1ih, wm1il, wm2ih, wm2il);
    k_wcomb<<<512, 256, 0, stream>>>(p2w, wo1, wch, wcl);

    for (int c = 0; c < NCH; c++) {
        int t0 = c * CH;
        int first = (c == 0);
        int save_halo = (c != NCH - 1);

        k_p1_ln<<<RC, 256, 0, stream>>>(xseq, p1w, p1b, ln1g, ln1b, x1h, x1l, t0);

        // mamba 1 core (params d_in[14..22])
        run_mamba_core(stream, x1h, x1l, d_in + 14, wm1ih, wm1il,
                       xzc, xcc, xpartb, yh, yl,
                       hendb, sumdtb, halo1, hs1, t0, save_halo);

        // fused out_proj1+p2 (y @ Wc^T + p2b) -> LN2
        k_gmfma<true><<<dim3(RC / 128, 256 / 128), 256, 0, stream>>>(
            yh, yl, 512, wch, wcl, p2b, xzc, 256, 512);
        k_ln<<<RC, 256, 0, stream>>>(xzc, ln2g, ln2b, x1h, x1l);

        // mamba 2 core (params d_in[23..31]); out_proj folded into prehead
        run_mamba_core(stream, x1h, x1l, d_in + 23, wm2ih, wm2il,
                       xzc, xcc, xpartb, yh, yl,
                       hendb, sumdtb, halo2, hs2, t0, save_halo);

        k_meanacc<<<dim3(NB, 8), 512, 0, stream>>>(yh, yl, macc, first);
    }

    k_prehead<<<NB, 256, 0, stream>>>(macc, wo2, mm);
    k_head<<<NB, 128, 0, stream>>>(mm, xst, h1w, h1b, h2w, h2b, (float*)d_out);
}

// Round 16
// 750.688 us; speedup vs baseline: 2.6874x; 1.0395x over previous
//
#include <hip/hip_runtime.h>
#include <math.h>

#define NB 32
#define L  1024
#define CH 512                 // timesteps per chunk
#define NCH (L / CH)           // 2 chunks
#define RC (NB * CH)           // 16384 rows per chunk
#define DM 256
#define DI 512
#define DS 16
#define SCT 16                 // sub-chunk timesteps (scan)
#define NSC (CH / SCT)         // 32 sub-chunks
#define LOG2E 1.44269504f
#define LN2   0.69314718f

typedef short short8 __attribute__((ext_vector_type(8)));
typedef float f32x4 __attribute__((ext_vector_type(4)));
typedef unsigned short u16;

// bf16 split helpers: x ~= hi + lo, both bf16 (rne).
__device__ inline unsigned f2bf_u(float x) {
    unsigned u = __float_as_uint(x);
    return (u + 0x7fffu + ((u >> 16) & 1u)) >> 16;
}

// Layout: per-chunk activations use (t_local, b, feat): row r = t_local*32 + b.

// ---------------------------------------------------------------------------
// p1 (K=4) + bias + LayerNorm; emits bf16 hi/lo PLANES for MFMA in_proj.
// ---------------------------------------------------------------------------
__global__ __launch_bounds__(256) void k_p1_ln(
    const float* __restrict__ xseq, const float* __restrict__ w,
    const float* __restrict__ bias, const float* __restrict__ g,
    const float* __restrict__ bb, u16* __restrict__ outh, u16* __restrict__ outl,
    int t0)
{
    int r  = blockIdx.x;
    int b  = r & 31;
    int tl = r >> 5;
    int m  = threadIdx.x;
    const float* xr = xseq + ((size_t)b * L + t0 + tl) * 4;
    float x0 = xr[0], x1 = xr[1], x2 = xr[2], x3 = xr[3];
    const float* wr = w + m * 4;
    float v = bias[m] + x0 * wr[0] + x1 * wr[1] + x2 * wr[2] + x3 * wr[3];

    __shared__ float s1[4], s2[4];
    float a = v, bq = v * v;
    for (int o = 32; o > 0; o >>= 1) { a += __shfl_down(a, o); bq += __shfl_down(bq, o); }
    int wid = m >> 6, lane = m & 63;
    if (lane == 0) { s1[wid] = a; s2[wid] = bq; }
    __syncthreads();
    if (m == 0) {
        s1[0] = s1[0] + s1[1] + s1[2] + s1[3];
        s2[0] = s2[0] + s2[1] + s2[2] + s2[3];
    }
    __syncthreads();
    float mu  = s1[0] * (1.f / 256.f);
    float var = s2[0] * (1.f / 256.f) - mu * mu;
    float o2 = (v - mu) * rsqrtf(var + 1e-5f) * g[m] + bb[m];
    unsigned hb = f2bf_u(o2);
    outh[(size_t)r * 256 + m] = (u16)hb;
    outl[(size_t)r * 256 + m] = (u16)f2bf_u(o2 - __uint_as_float(hb << 16));
}

// ---------------------------------------------------------------------------
// LayerNorm over 256; fp32 in, bf16 hi/lo planes out.
// ---------------------------------------------------------------------------
__global__ __launch_bounds__(256) void k_ln(
    const float* __restrict__ in, const float* __restrict__ g,
    const float* __restrict__ bb, u16* __restrict__ outh, u16* __restrict__ outl)
{
    int r = blockIdx.x;
    int m = threadIdx.x;
    float v = in[(size_t)r * 256 + m];

    __shared__ float s1[4], s2[4];
    float a = v, bq = v * v;
    for (int o = 32; o > 0; o >>= 1) { a += __shfl_down(a, o); bq += __shfl_down(bq, o); }
    int wid = m >> 6, lane = m & 63;
    if (lane == 0) { s1[wid] = a; s2[wid] = bq; }
    __syncthreads();
    if (m == 0) {
        s1[0] = s1[0] + s1[1] + s1[2] + s1[3];
        s2[0] = s2[0] + s2[1] + s2[2] + s2[3];
    }
    __syncthreads();
    float mu  = s1[0] * (1.f / 256.f);
    float var = s2[0] * (1.f / 256.f) - mu * mu;
    float o2 = (v - mu) * rsqrtf(var + 1e-5f) * g[m] + bb[m];
    unsigned hb = f2bf_u(o2);
    outh[(size_t)r * 256 + m] = (u16)hb;
    outl[(size_t)r * 256 + m] = (u16)f2bf_u(o2 - __uint_as_float(hb << 16));
}

// ---------------------------------------------------------------------------
// in_proj weight conversion (2 matrices) -> hi/lo planes, 1 launch.
// ---------------------------------------------------------------------------
__global__ __launch_bounds__(256) void k_wcvt2(
    const float* __restrict__ w1i, const float* __restrict__ w2i,
    u16* __restrict__ o1h, u16* __restrict__ o1l,
    u16* __restrict__ o2h, u16* __restrict__ o2l)
{
    int i = blockIdx.x * 256 + threadIdx.x;     // 524288, grid 2048
    const float* src; u16 *oh, *ol; int j;
    if (i < 262144) { src = w1i; oh = o1h; ol = o1l; j = i; }
    else            { src = w2i; oh = o2h; ol = o2l; j = i - 262144; }
    float v = src[j];
    unsigned hb = f2bf_u(v);
    oh[j] = (u16)hb;
    ol[j] = (u16)f2bf_u(v - __uint_as_float(hb << 16));
}

// ---------------------------------------------------------------------------
// combined weight Wc = Wp2 @ Wo1  ([256,256]x[256,512] -> [256,512]),
// packed to hi/lo planes.  (y@Wo1^T)@Wp2^T + b == y@Wc^T + b  (exact algebra)
// ---------------------------------------------------------------------------
__global__ __launch_bounds__(256) void k_wcomb(
    const float* __restrict__ p2w, const float* __restrict__ outw,
    u16* __restrict__ och, u16* __restrict__ ocl)
{
    int idx = blockIdx.x * 256 + threadIdx.x;   // 131072, grid 512
    int n = idx >> 9, k = idx & 511;
    const float* pr = p2w + n * 256;
    float s = 0.f;
    for (int j = 0; j < 256; j++)
        s = fmaf(pr[j], outw[(size_t)j * 512 + k], s);
    unsigned hb = f2bf_u(s);
    och[idx] = (u16)hb;
    ocl[idx] = (u16)f2bf_u(s - __uint_as_float(hb << 16));
}

// ---------------------------------------------------------------------------
// split-bf16 MFMA GEMM (3-term): C[M,N] = A[M,K]*W[N,K]^T (+bias).
// A,W as separate hi/lo bf16 planes. 128x128 tile, BK=32. fp32 output.
// ---------------------------------------------------------------------------
template <bool BIAS>
__global__ __launch_bounds__(256) void k_gmfma(
    const u16* __restrict__ Ahg, const u16* __restrict__ Alg, int lda,
    const u16* __restrict__ Whg, const u16* __restrict__ Wlg,
    const float* __restrict__ bias, float* __restrict__ C0,
    int N, int K)
{
    __shared__ u16 Ah[128 * 40], Al[128 * 40];
    __shared__ u16 Wh[128 * 40], Wl[128 * 40];

    int tid = threadIdx.x;
    int wv = tid >> 6, ln = tid & 63;
    int wr = wv >> 1, wc = wv & 1;
    int m0 = blockIdx.x * 128, n0 = blockIdx.y * 128;
    int sr = tid >> 1, sk = (tid & 1) << 4;
    int frow = ln & 15, fk = (ln >> 4) << 3;

    f32x4 acc[4][4] = {};

    for (int k0 = 0; k0 < K; k0 += 32) {
        const u16* ah = Ahg + (size_t)(m0 + sr) * lda + k0 + sk;
        const u16* al = Alg + (size_t)(m0 + sr) * lda + k0 + sk;
        const u16* wh = Whg + (size_t)(n0 + sr) * K + k0 + sk;
        const u16* wl = Wlg + (size_t)(n0 + sr) * K + k0 + sk;
        short8 vah0 = *(const short8*)ah, vah1 = *(const short8*)(ah + 8);
        short8 val0 = *(const short8*)al, val1 = *(const short8*)(al + 8);
        short8 vwh0 = *(const short8*)wh, vwh1 = *(const short8*)(wh + 8);
        short8 vwl0 = *(const short8*)wl, vwl1 = *(const short8*)(wl + 8);

        __syncthreads();   // previous iteration's frag reads done

        *(short8*)&Ah[sr * 40 + sk]     = vah0;
        *(short8*)&Ah[sr * 40 + sk + 8] = vah1;
        *(short8*)&Al[sr * 40 + sk]     = val0;
        *(short8*)&Al[sr * 40 + sk + 8] = val1;
        *(short8*)&Wh[sr * 40 + sk]     = vwh0;
        *(short8*)&Wh[sr * 40 + sk + 8] = vwh1;
        *(short8*)&Wl[sr * 40 + sk]     = vwl0;
        *(short8*)&Wl[sr * 40 + sk + 8] = vwl1;

        __syncthreads();

        short8 afh[4], afl[4], wfh[4], wfl[4];
#pragma unroll
        for (int g = 0; g < 4; g++) {
            int ra = (wr * 64 + g * 16 + frow) * 40 + fk;
            int rw = (wc * 64 + g * 16 + frow) * 40 + fk;
            afh[g] = *(const short8*)&Ah[ra];
            afl[g] = *(const short8*)&Al[ra];
            wfh[g] = *(const short8*)&Wh[rw];
            wfl[g] = *(const short8*)&Wl[rw];
        }
#pragma unroll
        for (int mg = 0; mg < 4; mg++)
#pragma unroll
            for (int ng = 0; ng < 4; ng++) {
                acc[mg][ng] = __builtin_amdgcn_mfma_f32_16x16x32_bf16(afh[mg], wfh[ng], acc[mg][ng], 0, 0, 0);
                acc[mg][ng] = __builtin_amdgcn_mfma_f32_16x16x32_bf16(afh[mg], wfl[ng], acc[mg][ng], 0, 0, 0);
                acc[mg][ng] = __builtin_amdgcn_mfma_f32_16x16x32_bf16(afl[mg], wfh[ng], acc[mg][ng], 0, 0, 0);
            }
    }

    // C layout: col=lane&15, row=(lane>>4)*4+reg  [verified m89]
#pragma unroll
    for (int ng = 0; ng < 4; ng++) {
        int col = n0 + wc * 64 + ng * 16 + frow;
        float bv = BIAS ? bias[col] : 0.f;
#pragma unroll
        for (int mg = 0; mg < 4; mg++)
#pragma unroll
            for (int r = 0; r < 4; r++) {
                int row = m0 + wr * 64 + mg * 16 + (ln >> 4) * 4 + r;
                C0[(size_t)row * N + col] = acc[mg][ng][r] + bv;
            }
    }
}

// ---------------------------------------------------------------------------
// xproj K-split partial GEMM: Cpart[slice][M][48] = A[:, ks..ks+128) * W^T.
// grid (M/64, 4). Partials summed inside the scans (exact dbr order).
// ---------------------------------------------------------------------------
__global__ __launch_bounds__(256) void k_xpart(
    const float* __restrict__ A, const float* __restrict__ W,
    float* __restrict__ Cpart, int M, int K, int kcnt)
{
    const int BM = 64, BK = 16;
    __shared__ float As[BK][BM];
    __shared__ float Ws[BK][64];

    int m0   = blockIdx.x * BM;
    int kbeg = blockIdx.y * kcnt;
    int tid = threadIdx.x;
    int tx  = tid & 15, ty = tid >> 4;
    int lr  = tid >> 2;
    int lc  = (tid & 3) * 4;

    float acc[4][4] = {};

    for (int k0 = kbeg; k0 < kbeg + kcnt; k0 += BK) {
        float4 av = *(const float4*)(A + (size_t)(m0 + lr) * K + k0 + lc);
        As[lc + 0][lr] = av.x; As[lc + 1][lr] = av.y;
        As[lc + 2][lr] = av.z; As[lc + 3][lr] = av.w;
        float4 wv = make_float4(0.f, 0.f, 0.f, 0.f);
        if (lr < 48) wv = *(const float4*)(W + (size_t)lr * K + k0 + lc);
        Ws[lc + 0][lr] = wv.x; Ws[lc + 1][lr] = wv.y;
        Ws[lc + 2][lr] = wv.z; Ws[lc + 3][lr] = wv.w;
        __syncthreads();
#pragma unroll
        for (int k = 0; k < BK; k++) {
            float a[4], bv[4];
            *(float4*)a  = *(const float4*)&As[k][ty * 4];
            *(float4*)bv = *(const float4*)&Ws[k][tx * 4];
#pragma unroll
            for (int i = 0; i < 4; i++)
#pragma unroll
                for (int j = 0; j < 4; j++)
                    acc[i][j] = fmaf(a[i], bv[j], acc[i][j]);
        }
        __syncthreads();
    }

    int n = tx * 4;
    if (n < 48) {
        float* cp = Cpart + (size_t)blockIdx.y * M * 48;
#pragma unroll
        for (int i = 0; i < 4; i++) {
            float4 v = make_float4(acc[i][0], acc[i][1], acc[i][2], acc[i][3]);
            *(float4*)(cp + (size_t)(m0 + ty * 4 + i) * 48 + n) = v;
        }
    }
}

// ---------------------------------------------------------------------------
// depthwise causal conv1d (k=4) + SiLU, float4-vectorized, fused halo-save.
// ---------------------------------------------------------------------------
__global__ __launch_bounds__(256) void k_conv(
    const float* __restrict__ xz, float* __restrict__ halo,
    const float* __restrict__ cw, const float* __restrict__ cb,
    float* __restrict__ xc, int t0, int save_halo)
{
    size_t i4 = ((size_t)blockIdx.x * 256 + threadIdx.x) * 4;   // over RC*512
    int d  = (int)(i4 & 511);
    int r  = (int)(i4 >> 9);
    int b  = r & 31;
    int tl = r >> 5;

    float4 w0 = *(const float4*)(cw + (d + 0) * 4);
    float4 w1 = *(const float4*)(cw + (d + 1) * 4);
    float4 w2 = *(const float4*)(cw + (d + 2) * 4);
    float4 w3 = *(const float4*)(cw + (d + 3) * 4);
    float4 acc = *(const float4*)(cb + d);
    float4 vlast = make_float4(0.f, 0.f, 0.f, 0.f);

#pragma unroll
    for (int k = 0; k < 4; k++) {
        int tsl = tl - 3 + k;
        float4 v;
        if (tsl >= 0)
            v = *(const float4*)(xz + ((size_t)tsl * 32 + b) * 1024 + d);
        else if (t0 + tsl >= 0)
            v = *(const float4*)(halo + ((size_t)(tsl + 3) * 32 + b) * 512 + d);
        else
            continue;
        if (k == 3) vlast = v;
        acc.x = fmaf((&w0.x)[k], v.x, acc.x);
        acc.y = fmaf((&w1.x)[k], v.y, acc.y);
        acc.z = fmaf((&w2.x)[k], v.z, acc.z);
        acc.w = fmaf((&w3.x)[k], v.w, acc.w);
    }
    float4 o;
    o.x = acc.x / (1.f + __expf(-acc.x));
    o.y = acc.y / (1.f + __expf(-acc.y));
    o.z = acc.z / (1.f + __expf(-acc.z));
    o.w = acc.w / (1.f + __expf(-acc.w));
    *(float4*)(xc + i4) = o;

    if (save_halo && tl >= CH - 3)
        *(float4*)(halo + ((size_t)(tl - (CH - 3)) * 32 + b) * 512 + d) = vlast;
}

// ---------------------------------------------------------------------------
// scan pass A (fused dt-proj + partial-reduce, geometric-dA fast path).
// ---------------------------------------------------------------------------
__global__ __launch_bounds__(256) void k_scanA(
    const float* __restrict__ xc, const float* __restrict__ part,
    const float* __restrict__ dtw, const float* __restrict__ dtb,
    const float* __restrict__ A_log,
    float* __restrict__ hend, float* __restrict__ sumdt)
{
    int bx = blockIdx.x;
    int b    = bx >> 6;
    int half = (bx >> 5) & 1;
    int c    = bx & 31;
    int d = (half << 8) + threadIdx.x;

    float A2[DS], h[DS], wdt[DS];
#pragma unroll
    for (int s = 0; s < DS; s++) {
        A2[s] = -__expf(A_log[d * DS + s]) * LOG2E;
        h[s] = 0.f;
        wdt[s] = dtw[d * DS + s];
    }
    float dtbv = dtb[d];
    float A20 = A2[0];
    float A0nat = A20 * LN2;
    bool geo = true;
#pragma unroll
    for (int s = 0; s < DS; s++)
        geo = geo && (fabsf(A2[s] - (float)(s + 1) * A20) <=
                      1e-5f * fabsf(A2[s]) + 1e-30f);

    __shared__ float Bs[SCT][48];
    {
        const size_t st = (size_t)RC * 48;
        for (int f = threadIdx.x; f < SCT * 48; f += 256) {
            int tt = f / 48, jj = f - tt * 48;
            size_t base = ((size_t)(c * SCT + tt) * 32 + b) * 48 + jj;
            Bs[tt][jj] = (part[base] + part[st + base]) +
                         (part[2 * st + base] + part[3 * st + base]);
        }
    }
    __syncthreads();

    float cum = 0.f;
    if (geo) {
        for (int tt = 0; tt < SCT; tt++) {
            size_t idx = ((size_t)(c * SCT + tt) * 32 + b) * DI + d;
            float p0 = 0.f, p1 = 0.f, p2 = 0.f, p3 = 0.f;
#pragma unroll
            for (int k = 0; k < 4; k++) {
                p0 = fmaf(Bs[tt][k],      wdt[k],      p0);
                p1 = fmaf(Bs[tt][4 + k],  wdt[4 + k],  p1);
                p2 = fmaf(Bs[tt][8 + k],  wdt[8 + k],  p2);
                p3 = fmaf(Bs[tt][12 + k], wdt[12 + k], p3);
            }
            float s0 = dtbv + ((p0 + p1) + (p2 + p3));
            float u  = __expf(s0);
            float t2 = __log2f(1.f + u);
            if (s0 > 80.f) t2 = s0 * LOG2E;
            float dt = LN2 * t2;
            cum += dt;
            float dtx = dt * xc[idx];
            float q  = exp2f(t2 * A0nat);
            float q2 = q * q, q3 = q2 * q, q4 = q2 * q2;
            float pv[4] = { q, q2, q3, q4 };
            float r = 1.f;
#pragma unroll
            for (int g = 0; g < 4; g++) {
#pragma unroll
                for (int j = 0; j < 4; j++) {
                    int s = g * 4 + j;
                    float dA = r * pv[j];
                    h[s] = fmaf(dA, h[s], dtx * Bs[tt][16 + s]);
                }
                r *= q4;
            }
        }
    } else {
        for (int tt = 0; tt < SCT; tt++) {
            size_t idx = ((size_t)(c * SCT + tt) * 32 + b) * DI + d;
            float s0 = dtbv;
#pragma unroll
            for (int k = 0; k < DS; k++) s0 = fmaf(Bs[tt][k], wdt[k], s0);
            float dt = (s0 > 20.f) ? s0 : log1pf(expf(s0));
            cum += dt;
            float dtx = dt * xc[idx];
#pragma unroll
            for (int s = 0; s < DS; s++) {
                float dA = exp2f(dt * A2[s]);
                h[s] = fmaf(dA, h[s], dtx * Bs[tt][16 + s]);
            }
        }
    }
    float* hp = hend + ((size_t)(c * 32 + b) * 512 + d) * DS;
#pragma unroll
    for (int s = 0; s < DS; s++) hp[s] = h[s];
    sumdt[((size_t)c * 32 + b) * 512 + d] = cum;
}

// ---------------------------------------------------------------------------
// scan pass B: carry across 32 sub-chunks; hend -> h_init, carry -> hs.
// ---------------------------------------------------------------------------
__global__ __launch_bounds__(256) void k_scanB(
    const float* __restrict__ sumdt, float* __restrict__ hend,
    const float* __restrict__ A_log, float* __restrict__ hs, int first)
{
    int id = blockIdx.x * 256 + threadIdx.x;   // 32*512*16 = 262144
    int s = id & 15;
    int d = (id >> 4) & 511;
    int b = id >> 13;
    float A2 = -__expf(A_log[d * DS + s]) * LOG2E;
    size_t hsi = ((size_t)(b << 9) + d) * DS + s;
    float hin = first ? 0.f : hs[hsi];
    for (int c = 0; c < NSC; c++) {
        size_t hi = ((size_t)(c * 32 + b) * 512 + d) * DS + s;
        float he = hend[hi];
        float sd = sumdt[((size_t)c * 32 + b) * 512 + d];
        hend[hi] = hin;
        hin = fmaf(exp2f(A2 * sd), hin, he);
    }
    hs[hsi] = hin;
}

// ---------------------------------------------------------------------------
// scan pass C (fused dt-proj + partial-reduce, geometric-dA, fast softplus):
// rescan seeded with h_init, y inline, epilogue (y+x*D)*silu(z).
// ACC=0: emit y as bf16 hi/lo planes (consumed by fused out1+p2 GEMM).
// ACC=1: skip plane stores; accumulate t-sum of y into macc2[b][c][d]
//        (out_proj2 is folded through the mean into k_prehead).
// ---------------------------------------------------------------------------
template <int ACC>
__global__ __launch_bounds__(256) void k_scanC(
    const float* __restrict__ xc, const float* __restrict__ part,
    const float* __restrict__ dtw, const float* __restrict__ dtb,
    const float* __restrict__ xz,
    const float* __restrict__ A_log, const float* __restrict__ Dp,
    const float* __restrict__ hinit,
    u16* __restrict__ yh, u16* __restrict__ yl,
    float* __restrict__ macc2, int first)
{
    int bx = blockIdx.x;
    int b    = bx >> 6;
    int half = (bx >> 5) & 1;
    int c    = bx & 31;
    int d = (half << 8) + threadIdx.x;

    float A2[DS], h[DS], wdt[DS];
    const float* hp = hinit + ((size_t)(c * 32 + b) * 512 + d) * DS;
#pragma unroll
    for (int s = 0; s < DS; s++) {
        A2[s] = -__expf(A_log[d * DS + s]) * LOG2E;
        h[s] = hp[s];
        wdt[s] = dtw[d * DS + s];
    }
    float dtbv = dtb[d];
    float Dv = Dp[d];
    float A20 = A2[0];
    float A0nat = A20 * LN2;
    bool geo = true;
#pragma unroll
    for (int s = 0; s < DS; s++)
        geo = geo && (fabsf(A2[s] - (float)(s + 1) * A20) <=
                      1e-5f * fabsf(A2[s]) + 1e-30f);

    __shared__ float BC[SCT][48];
    {
        const size_t st = (size_t)RC * 48;
        for (int f = threadIdx.x; f < SCT * 48; f += 256) {
            int tt = f / 48, jj = f - tt * 48;
            size_t base = ((size_t)(c * SCT + tt) * 32 + b) * 48 + jj;
            BC[tt][jj] = (part[base] + part[st + base]) +
                         (part[2 * st + base] + part[3 * st + base]);
        }
    }
    __syncthreads();

    float ysum = 0.f;
    if (geo) {
        for (int tt = 0; tt < SCT; tt++) {
            size_t row = (size_t)(c * SCT + tt) * 32 + b;
            size_t idx = row * DI + d;
            float p0 = 0.f, p1 = 0.f, p2 = 0.f, p3 = 0.f;
#pragma unroll
            for (int k = 0; k < 4; k++) {
                p0 = fmaf(BC[tt][k],      wdt[k],      p0);
                p1 = fmaf(BC[tt][4 + k],  wdt[4 + k],  p1);
                p2 = fmaf(BC[tt][8 + k],  wdt[8 + k],  p2);
                p3 = fmaf(BC[tt][12 + k], wdt[12 + k], p3);
            }
            float s0 = dtbv + ((p0 + p1) + (p2 + p3));
            float u  = __expf(s0);
            float t2 = __log2f(1.f + u);
            if (s0 > 80.f) t2 = s0 * LOG2E;
            float dt = LN2 * t2;
            float x  = xc[idx];
            float z  = xz[(row << 10) + 512 + d];
            float dtx = dt * x;
            float y = 0.f;
            float q  = exp2f(t2 * A0nat);
            float q2 = q * q, q3 = q2 * q, q4 = q2 * q2;
            float pv[4] = { q, q2, q3, q4 };
            float r = 1.f;
#pragma unroll
            for (int g = 0; g < 4; g++) {
#pragma unroll
                for (int j = 0; j < 4; j++) {
                    int s = g * 4 + j;
                    float dA = r * pv[j];
                    h[s] = fmaf(dA, h[s], dtx * BC[tt][16 + s]);
                    y = fmaf(h[s], BC[tt][32 + s], y);
                }
                r *= q4;
            }
            float yact = (y + x * Dv) * (z / (1.f + __expf(-z)));
            if (ACC) {
                ysum += yact;
            } else {
                unsigned hb = f2bf_u(yact);
                yh[row * DI + d] = (u16)hb;
                yl[row * DI + d] = (u16)f2bf_u(yact - __uint_as_float(hb << 16));
            }
        }
    } else {
        for (int tt = 0; tt < SCT; tt++) {
            size_t row = (size_t)(c * SCT + tt) * 32 + b;
            size_t idx = row * DI + d;
            float s0 = dtbv;
#pragma unroll
            for (int k = 0; k < DS; k++) s0 = fmaf(BC[tt][k], wdt[k], s0);
            float dt = (s0 > 20.f) ? s0 : log1pf(expf(s0));
            float x  = xc[idx];
            float z  = xz[(row << 10) + 512 + d];
            float dtx = dt * x;
            float y = 0.f;
#pragma unroll
            for (int s = 0; s < DS; s++) {
                float dA = exp2f(dt * A2[s]);
                h[s] = fmaf(dA, h[s], dtx * BC[tt][16 + s]);
                y = fmaf(h[s], BC[tt][32 + s], y);
            }
            float yact = (y + x * Dv) * (z / (1.f + __expf(-z)));
            if (ACC) {
                ysum += yact;
            } else {
                unsigned hb = f2bf_u(yact);
                yh[row * DI + d] = (u16)hb;
                yl[row * DI + d] = (u16)f2bf_u(yact - __uint_as_float(hb << 16));
            }
        }
    }

    if (ACC) {
        size_t mi = ((size_t)(b * NSC + c) * 512) + d;
        if (first) macc2[mi] = ysum;
        else       macc2[mi] += ysum;
    }
}

// ---------------------------------------------------------------------------
// prehead: mm[b][n] = (1/1024) * sum_q Wo2[n][q] * (sum_c macc2[b][c][q])
// ---------------------------------------------------------------------------
__global__ __launch_bounds__(256) void k_prehead(
    const float* __restrict__ macc2, const float* __restrict__ wo2,
    float* __restrict__ mm)
{
    int b = blockIdx.x;
    int n = threadIdx.x;
    __shared__ float ys[512];
    for (int q = threadIdx.x; q < 512; q += 256) {
        float s = 0.f;
        for (int c = 0; c < NSC; c++)
            s += macc2[((size_t)(b * NSC + c) * 512) + q];
        ys[q] = s;
    }
    __syncthreads();
    const float* wr = wo2 + (size_t)n * 512;
    float s = 0.f;
    for (int q = 0; q < 512; q += 4) {
        float4 w = *(const float4*)(wr + q);
        s = fmaf(w.x, ys[q + 0], s);
        s = fmaf(w.y, ys[q + 1], s);
        s = fmaf(w.z, ys[q + 2], s);
        s = fmaf(w.w, ys[q + 3], s);
    }
    mm[b * 256 + n] = s * (1.f / 1024.f);
}

__global__ __launch_bounds__(128) void k_head(
    const float* __restrict__ mm, const float* __restrict__ xst,
    const float* __restrict__ h1w, const float* __restrict__ h1b,
    const float* __restrict__ h2w, const float* __restrict__ h2b,
    float* __restrict__ out)
{
    int b = blockIdx.x;
    int j = threadIdx.x;
    const float* wr = h1w + j * 261;
    const float* mr = mm + b * 256;
    float s = h1b[j];
    for (int k = 0; k < 256; k++) s = fmaf(mr[k], wr[k], s);
    for (int k = 0; k < 5; k++) s = fmaf(xst[b * 5 + k], wr[256 + k], s);
    float e = (s > 0.f) ? s : expm1f(s);

    __shared__ float sb[128];
    sb[j] = e * h2w[j];
    __syncthreads();
    for (int o = 64; o > 0; o >>= 1) {
        if (j < o) sb[j] += sb[j + o];
        __syncthreads();
    }
    if (j == 0) out[b] = sb[0] + h2b[0];
}

// ---------------------------------------------------------------------------
// host side
// ---------------------------------------------------------------------------
static void run_mamba_core(hipStream_t stream,
                           const u16* x1h, const u16* x1l, void* const* P,
                           const u16* wih, const u16* wil,
                           float* xzc, float* xcc, float* xpartb,
                           u16* yh, u16* yl,
                           float* hendb, float* sumdtb, float* halo,
                           float* hstate, float* macc2, int acc,
                           int t0, int save_halo)
{
    const float* cw     = (const float*)P[1];
    const float* cb     = (const float*)P[2];
    const float* xpw    = (const float*)P[3];
    const float* dtw    = (const float*)P[4];
    const float* dtbias = (const float*)P[5];
    const float* Alog   = (const float*)P[6];
    const float* Dp     = (const float*)P[7];
    int first = (t0 == 0);

    k_gmfma<false><<<dim3(RC / 128, 1024 / 128), 256, 0, stream>>>(
        x1h, x1l, 256, wih, wil, nullptr, xzc, 1024, 256);
    k_conv<<<RC * DI / 1024, 256, 0, stream>>>(xzc, halo, cw, cb, xcc, t0, save_halo);
    k_xpart<<<dim3(RC / 64, 4), 256, 0, stream>>>(xcc, xpw, xpartb, RC, 512, 128);
    k_scanA<<<32 * 2 * NSC, 256, 0, stream>>>(xcc, xpartb, dtw, dtbias, Alog,
                                              hendb, sumdtb);
    k_scanB<<<32 * 512 * DS / 256, 256, 0, stream>>>(sumdtb, hendb, Alog, hstate, first);
    if (acc)
        k_scanC<1><<<32 * 2 * NSC, 256, 0, stream>>>(
            xcc, xpartb, dtw, dtbias, xzc, Alog, Dp, hendb,
            nullptr, nullptr, macc2, first);
    else
        k_scanC<0><<<32 * 2 * NSC, 256, 0, stream>>>(
            xcc, xpartb, dtw, dtbias, xzc, Alog, Dp, hendb,
            yh, yl, nullptr, 0);
}

extern "C" void kernel_launch(void* const* d_in, const int* in_sizes, int n_in,
                              void* d_out, int out_size, void* d_ws, size_t ws_size,
                              hipStream_t stream)
{
    const float* xseq = (const float*)d_in[0];
    const float* xst  = (const float*)d_in[1];
    const float* p1w  = (const float*)d_in[2];
    const float* p1b  = (const float*)d_in[3];
    const float* ln1g = (const float*)d_in[4];
    const float* ln1b = (const float*)d_in[5];
    const float* p2w  = (const float*)d_in[6];
    const float* p2b  = (const float*)d_in[7];
    const float* ln2g = (const float*)d_in[8];
    const float* ln2b = (const float*)d_in[9];
    const float* h1w  = (const float*)d_in[10];
    const float* h1b  = (const float*)d_in[11];
    const float* h2w  = (const float*)d_in[12];
    const float* h2b  = (const float*)d_in[13];
    const float* wo1  = (const float*)d_in[22];   // m1 out_w [256,512]
    const float* wo2  = (const float*)d_in[31];   // m2 out_w [256,512]

    float* ws = (float*)d_ws;
    float* xzc    = ws;                                  // RC*1024 f32
    float* xcc    = xzc  + (size_t)RC * 1024;            // RC*512
    // hend region: RC*512 floats; x1 planes (dead during scans) alias its head
    float* hendb  = xcc  + (size_t)RC * 512;
    u16*   x1h    = (u16*)hendb;                         // RC*256 u16
    u16*   x1l    = x1h + (size_t)RC * 256;              // RC*256 u16
    u16*   yh     = (u16*)(hendb + (size_t)RC * 512);    // RC*512 u16
    u16*   yl     = yh + (size_t)RC * 512;               // RC*512 u16
    float* sumdtb = (float*)(yl + (size_t)RC * 512);     // NSC*32*512
    float* halo1  = sumdtb + NSC * 32 * 512;             // 3*32*512
    float* halo2  = halo1 + 3 * 32 * 512;
    float* hs1    = halo2 + 3 * 32 * 512;                // 32*512*16
    float* hs2    = hs1  + 32 * 512 * DS;
    float* macc2  = hs2  + 32 * 512 * DS;                // 32*NSC*512 (2 MB)
    float* mm     = macc2 + 32 * NSC * 512;              // 32*256
    u16*   wm1ih  = (u16*)(mm + 32 * 256);               // 1024*256 u16 each
    u16*   wm1il  = wm1ih + 262144;
    u16*   wm2ih  = wm1il + 262144;
    u16*   wm2il  = wm2ih + 262144;
    u16*   wch    = wm2il + 262144;                      // 256*512 u16 each
    u16*   wcl    = wch + 131072;
    float* xpartb = (float*)(wcl + 131072);              // 4*RC*48 f32
    size_t need = (size_t)((char*)(xpartb + 4 * (size_t)RC * 48) - (char*)ws);
    if (ws_size < need) return;   // tripwire: fail cleanly, don't fault

    // weight prep (2 launches total)
    k_wcvt2<<<2048, 256, 0, stream>>>(
        (const float*)d_in[14], (const float*)d_in[23],
        wm1ih, wm1il, wm2ih, wm2il);
    k_wcomb<<<512, 256, 0, stream>>>(p2w, wo1, wch, wcl);

    for (int c = 0; c < NCH; c++) {
        int t0 = c * CH;
        int save_halo = (c != NCH - 1);

        k_p1_ln<<<RC, 256, 0, stream>>>(xseq, p1w, p1b, ln1g, ln1b, x1h, x1l, t0);

        // mamba 1 core (params d_in[14..22]) -> y planes
        run_mamba_core(stream, x1h, x1l, d_in + 14, wm1ih, wm1il,
                       xzc, xcc, xpartb, yh, yl,
                       hendb, sumdtb, halo1, hs1, nullptr, 0, t0, save_halo);

        // fused out_proj1+p2 (y @ Wc^T + p2b) -> LN2
        k_gmfma<true><<<dim3(RC / 128, 256 / 128), 256, 0, stream>>>(
            yh, yl, 512, wch, wcl, p2b, xzc, 256, 512);
        k_ln<<<RC, 256, 0, stream>>>(xzc, ln2g, ln2b, x1h, x1l);

        // mamba 2 core (params d_in[23..31]); y accumulated into macc2,
        // out_proj folded into prehead
        run_mamba_core(stream, x1h, x1l, d_in + 23, wm2ih, wm2il,
                       xzc, xcc, xpartb, yh, yl,
                       hendb, sumdtb, halo2, hs2, macc2, 1, t0, save_halo);
    }

    k_prehead<<<NB, 256, 0, stream>>>(macc2, wo2, mm);
    k_head<<<NB, 128, 0, stream>>>(mm, xst, h1w, h1b, h2w, h2b, (float*)d_out);
}

// Round 17
// 743.759 us; speedup vs baseline: 2.7125x; 1.0093x over previous
//
#include <hip/hip_runtime.h>
#include <math.h>

#define NB 32
#define L  1024
#define CH 512                 // timesteps per chunk
#define NCH (L / CH)           // 2 chunks
#define RC (NB * CH)           // 16384 rows per chunk
#define DM 256
#define DI 512
#define DS 16
#define SCT 16                 // sub-chunk timesteps (scan)
#define NSC (CH / SCT)         // 32 sub-chunks
#define LOG2E 1.44269504f
#define LN2   0.69314718f

typedef short short8 __attribute__((ext_vector_type(8)));
typedef float f32x4 __attribute__((ext_vector_type(4)));
typedef unsigned short u16;

// bf16 split helpers: x ~= hi + lo, both bf16 (rne).
__device__ inline unsigned f2bf_u(float x) {
    unsigned u = __float_as_uint(x);
    return (u + 0x7fffu + ((u >> 16) & 1u)) >> 16;
}

// Layout: per-chunk activations use (t_local, b, feat): row r = t_local*32 + b.

// ---------------------------------------------------------------------------
// p1 (K=4) + bias + LayerNorm; emits bf16 hi/lo PLANES for MFMA in_proj.
// ---------------------------------------------------------------------------
__global__ __launch_bounds__(256) void k_p1_ln(
    const float* __restrict__ xseq, const float* __restrict__ w,
    const float* __restrict__ bias, const float* __restrict__ g,
    const float* __restrict__ bb, u16* __restrict__ outh, u16* __restrict__ outl,
    int t0)
{
    int r  = blockIdx.x;
    int b  = r & 31;
    int tl = r >> 5;
    int m  = threadIdx.x;
    const float* xr = xseq + ((size_t)b * L + t0 + tl) * 4;
    float x0 = xr[0], x1 = xr[1], x2 = xr[2], x3 = xr[3];
    const float* wr = w + m * 4;
    float v = bias[m] + x0 * wr[0] + x1 * wr[1] + x2 * wr[2] + x3 * wr[3];

    __shared__ float s1[4], s2[4];
    float a = v, bq = v * v;
    for (int o = 32; o > 0; o >>= 1) { a += __shfl_down(a, o); bq += __shfl_down(bq, o); }
    int wid = m >> 6, lane = m & 63;
    if (lane == 0) { s1[wid] = a; s2[wid] = bq; }
    __syncthreads();
    if (m == 0) {
        s1[0] = s1[0] + s1[1] + s1[2] + s1[3];
        s2[0] = s2[0] + s2[1] + s2[2] + s2[3];
    }
    __syncthreads();
    float mu  = s1[0] * (1.f / 256.f);
    float var = s2[0] * (1.f / 256.f) - mu * mu;
    float o2 = (v - mu) * rsqrtf(var + 1e-5f) * g[m] + bb[m];
    unsigned hb = f2bf_u(o2);
    outh[(size_t)r * 256 + m] = (u16)hb;
    outl[(size_t)r * 256 + m] = (u16)f2bf_u(o2 - __uint_as_float(hb << 16));
}

// ---------------------------------------------------------------------------
// LayerNorm over 256; fp32 in, bf16 hi/lo planes out.
// ---------------------------------------------------------------------------
__global__ __launch_bounds__(256) void k_ln(
    const float* __restrict__ in, const float* __restrict__ g,
    const float* __restrict__ bb, u16* __restrict__ outh, u16* __restrict__ outl)
{
    int r = blockIdx.x;
    int m = threadIdx.x;
    float v = in[(size_t)r * 256 + m];

    __shared__ float s1[4], s2[4];
    float a = v, bq = v * v;
    for (int o = 32; o > 0; o >>= 1) { a += __shfl_down(a, o); bq += __shfl_down(bq, o); }
    int wid = m >> 6, lane = m & 63;
    if (lane == 0) { s1[wid] = a; s2[wid] = bq; }
    __syncthreads();
    if (m == 0) {
        s1[0] = s1[0] + s1[1] + s1[2] + s1[3];
        s2[0] = s2[0] + s2[1] + s2[2] + s2[3];
    }
    __syncthreads();
    float mu  = s1[0] * (1.f / 256.f);
    float var = s2[0] * (1.f / 256.f) - mu * mu;
    float o2 = (v - mu) * rsqrtf(var + 1e-5f) * g[m] + bb[m];
    unsigned hb = f2bf_u(o2);
    outh[(size_t)r * 256 + m] = (u16)hb;
    outl[(size_t)r * 256 + m] = (u16)f2bf_u(o2 - __uint_as_float(hb << 16));
}

// ---------------------------------------------------------------------------
// in_proj weight conversion (2 matrices) -> hi/lo planes, 1 launch.
// ---------------------------------------------------------------------------
__global__ __launch_bounds__(256) void k_wcvt2(
    const float* __restrict__ w1i, const float* __restrict__ w2i,
    u16* __restrict__ o1h, u16* __restrict__ o1l,
    u16* __restrict__ o2h, u16* __restrict__ o2l)
{
    int i = blockIdx.x * 256 + threadIdx.x;     // 524288, grid 2048
    const float* src; u16 *oh, *ol; int j;
    if (i < 262144) { src = w1i; oh = o1h; ol = o1l; j = i; }
    else            { src = w2i; oh = o2h; ol = o2l; j = i - 262144; }
    float v = src[j];
    unsigned hb = f2bf_u(v);
    oh[j] = (u16)hb;
    ol[j] = (u16)f2bf_u(v - __uint_as_float(hb << 16));
}

// ---------------------------------------------------------------------------
// combined weight Wc = Wp2 @ Wo1  ([256,256]x[256,512] -> [256,512]),
// packed to hi/lo planes.  (y@Wo1^T)@Wp2^T + b == y@Wc^T + b  (exact algebra)
// ---------------------------------------------------------------------------
__global__ __launch_bounds__(256) void k_wcomb(
    const float* __restrict__ p2w, const float* __restrict__ outw,
    u16* __restrict__ och, u16* __restrict__ ocl)
{
    int idx = blockIdx.x * 256 + threadIdx.x;   // 131072, grid 512
    int n = idx >> 9, k = idx & 511;
    const float* pr = p2w + n * 256;
    float s = 0.f;
    for (int j = 0; j < 256; j++)
        s = fmaf(pr[j], outw[(size_t)j * 512 + k], s);
    unsigned hb = f2bf_u(s);
    och[idx] = (u16)hb;
    ocl[idx] = (u16)f2bf_u(s - __uint_as_float(hb << 16));
}

// ---------------------------------------------------------------------------
// split-bf16 MFMA GEMM (3-term): C[M,N] = A[M,K]*W[N,K]^T (+bias).
// A,W as separate hi/lo bf16 planes. 128x128 tile, BK=32. fp32 output.
// ---------------------------------------------------------------------------
template <bool BIAS>
__global__ __launch_bounds__(256) void k_gmfma(
    const u16* __restrict__ Ahg, const u16* __restrict__ Alg, int lda,
    const u16* __restrict__ Whg, const u16* __restrict__ Wlg,
    const float* __restrict__ bias, float* __restrict__ C0,
    int N, int K)
{
    __shared__ u16 Ah[128 * 40], Al[128 * 40];
    __shared__ u16 Wh[128 * 40], Wl[128 * 40];

    int tid = threadIdx.x;
    int wv = tid >> 6, ln = tid & 63;
    int wr = wv >> 1, wc = wv & 1;
    int m0 = blockIdx.x * 128, n0 = blockIdx.y * 128;
    int sr = tid >> 1, sk = (tid & 1) << 4;
    int frow = ln & 15, fk = (ln >> 4) << 3;

    f32x4 acc[4][4] = {};

    for (int k0 = 0; k0 < K; k0 += 32) {
        const u16* ah = Ahg + (size_t)(m0 + sr) * lda + k0 + sk;
        const u16* al = Alg + (size_t)(m0 + sr) * lda + k0 + sk;
        const u16* wh = Whg + (size_t)(n0 + sr) * K + k0 + sk;
        const u16* wl = Wlg + (size_t)(n0 + sr) * K + k0 + sk;
        short8 vah0 = *(const short8*)ah, vah1 = *(const short8*)(ah + 8);
        short8 val0 = *(const short8*)al, val1 = *(const short8*)(al + 8);
        short8 vwh0 = *(const short8*)wh, vwh1 = *(const short8*)(wh + 8);
        short8 vwl0 = *(const short8*)wl, vwl1 = *(const short8*)(wl + 8);

        __syncthreads();   // previous iteration's frag reads done

        *(short8*)&Ah[sr * 40 + sk]     = vah0;
        *(short8*)&Ah[sr * 40 + sk + 8] = vah1;
        *(short8*)&Al[sr * 40 + sk]     = val0;
        *(short8*)&Al[sr * 40 + sk + 8] = val1;
        *(short8*)&Wh[sr * 40 + sk]     = vwh0;
        *(short8*)&Wh[sr * 40 + sk + 8] = vwh1;
        *(short8*)&Wl[sr * 40 + sk]     = vwl0;
        *(short8*)&Wl[sr * 40 + sk + 8] = vwl1;

        __syncthreads();

        short8 afh[4], afl[4], wfh[4], wfl[4];
#pragma unroll
        for (int g = 0; g < 4; g++) {
            int ra = (wr * 64 + g * 16 + frow) * 40 + fk;
            int rw = (wc * 64 + g * 16 + frow) * 40 + fk;
            afh[g] = *(const short8*)&Ah[ra];
            afl[g] = *(const short8*)&Al[ra];
            wfh[g] = *(const short8*)&Wh[rw];
            wfl[g] = *(const short8*)&Wl[rw];
        }
#pragma unroll
        for (int mg = 0; mg < 4; mg++)
#pragma unroll
            for (int ng = 0; ng < 4; ng++) {
                acc[mg][ng] = __builtin_amdgcn_mfma_f32_16x16x32_bf16(afh[mg], wfh[ng], acc[mg][ng], 0, 0, 0);
                acc[mg][ng] = __builtin_amdgcn_mfma_f32_16x16x32_bf16(afh[mg], wfl[ng], acc[mg][ng], 0, 0, 0);
                acc[mg][ng] = __builtin_amdgcn_mfma_f32_16x16x32_bf16(afl[mg], wfh[ng], acc[mg][ng], 0, 0, 0);
            }
    }

    // C layout: col=lane&15, row=(lane>>4)*4+reg  [verified m89]
#pragma unroll
    for (int ng = 0; ng < 4; ng++) {
        int col = n0 + wc * 64 + ng * 16 + frow;
        float bv = BIAS ? bias[col] : 0.f;
#pragma unroll
        for (int mg = 0; mg < 4; mg++)
#pragma unroll
            for (int r = 0; r < 4; r++) {
                int row = m0 + wr * 64 + mg * 16 + (ln >> 4) * 4 + r;
                C0[(size_t)row * N + col] = acc[mg][ng][r] + bv;
            }
    }
}

// ---------------------------------------------------------------------------
// xproj K-split partial GEMM: Cpart[slice][M][48] = A[:, ks..ks+128) * W^T.
// grid (M/64, 4). Partials summed inside the scans (exact dbr order).
// ---------------------------------------------------------------------------
__global__ __launch_bounds__(256) void k_xpart(
    const float* __restrict__ A, const float* __restrict__ W,
    float* __restrict__ Cpart, int M, int K, int kcnt)
{
    const int BM = 64, BK = 16;
    __shared__ float As[BK][BM];
    __shared__ float Ws[BK][64];

    int m0   = blockIdx.x * BM;
    int kbeg = blockIdx.y * kcnt;
    int tid = threadIdx.x;
    int tx  = tid & 15, ty = tid >> 4;
    int lr  = tid >> 2;
    int lc  = (tid & 3) * 4;

    float acc[4][4] = {};

    for (int k0 = kbeg; k0 < kbeg + kcnt; k0 += BK) {
        float4 av = *(const float4*)(A + (size_t)(m0 + lr) * K + k0 + lc);
        As[lc + 0][lr] = av.x; As[lc + 1][lr] = av.y;
        As[lc + 2][lr] = av.z; As[lc + 3][lr] = av.w;
        float4 wv = make_float4(0.f, 0.f, 0.f, 0.f);
        if (lr < 48) wv = *(const float4*)(W + (size_t)lr * K + k0 + lc);
        Ws[lc + 0][lr] = wv.x; Ws[lc + 1][lr] = wv.y;
        Ws[lc + 2][lr] = wv.z; Ws[lc + 3][lr] = wv.w;
        __syncthreads();
#pragma unroll
        for (int k = 0; k < BK; k++) {
            float a[4], bv[4];
            *(float4*)a  = *(const float4*)&As[k][ty * 4];
            *(float4*)bv = *(const float4*)&Ws[k][tx * 4];
#pragma unroll
            for (int i = 0; i < 4; i++)
#pragma unroll
                for (int j = 0; j < 4; j++)
                    acc[i][j] = fmaf(a[i], bv[j], acc[i][j]);
        }
        __syncthreads();
    }

    int n = tx * 4;
    if (n < 48) {
        float* cp = Cpart + (size_t)blockIdx.y * M * 48;
#pragma unroll
        for (int i = 0; i < 4; i++) {
            float4 v = make_float4(acc[i][0], acc[i][1], acc[i][2], acc[i][3]);
            *(float4*)(cp + (size_t)(m0 + ty * 4 + i) * 48 + n) = v;
        }
    }
}

// ---------------------------------------------------------------------------
// depthwise causal conv1d (k=4) + SiLU, float4-vectorized, fused halo-save.
// ---------------------------------------------------------------------------
__global__ __launch_bounds__(256) void k_conv(
    const float* __restrict__ xz, float* __restrict__ halo,
    const float* __restrict__ cw, const float* __restrict__ cb,
    float* __restrict__ xc, int t0, int save_halo)
{
    size_t i4 = ((size_t)blockIdx.x * 256 + threadIdx.x) * 4;   // over RC*512
    int d  = (int)(i4 & 511);
    int r  = (int)(i4 >> 9);
    int b  = r & 31;
    int tl = r >> 5;

    float4 w0 = *(const float4*)(cw + (d + 0) * 4);
    float4 w1 = *(const float4*)(cw + (d + 1) * 4);
    float4 w2 = *(const float4*)(cw + (d + 2) * 4);
    float4 w3 = *(const float4*)(cw + (d + 3) * 4);
    float4 acc = *(const float4*)(cb + d);
    float4 vlast = make_float4(0.f, 0.f, 0.f, 0.f);

#pragma unroll
    for (int k = 0; k < 4; k++) {
        int tsl = tl - 3 + k;
        float4 v;
        if (tsl >= 0)
            v = *(const float4*)(xz + ((size_t)tsl * 32 + b) * 1024 + d);
        else if (t0 + tsl >= 0)
            v = *(const float4*)(halo + ((size_t)(tsl + 3) * 32 + b) * 512 + d);
        else
            continue;
        if (k == 3) vlast = v;
        acc.x = fmaf((&w0.x)[k], v.x, acc.x);
        acc.y = fmaf((&w1.x)[k], v.y, acc.y);
        acc.z = fmaf((&w2.x)[k], v.z, acc.z);
        acc.w = fmaf((&w3.x)[k], v.w, acc.w);
    }
    float4 o;
    o.x = acc.x / (1.f + __expf(-acc.x));
    o.y = acc.y / (1.f + __expf(-acc.y));
    o.z = acc.z / (1.f + __expf(-acc.z));
    o.w = acc.w / (1.f + __expf(-acc.w));
    *(float4*)(xc + i4) = o;

    if (save_halo && tl >= CH - 3)
        *(float4*)(halo + ((size_t)(tl - (CH - 3)) * 32 + b) * 512 + d) = vlast;
}

// ---------------------------------------------------------------------------
// scan pass A (fused dt-proj + partial-reduce, geometric-dA fast path).
// 512-thread blocks: one block covers all d for a (b,c) pair -> single
// Bs staging shared by both d-halves. grid: 32*NSC = 1024 blocks.
// ---------------------------------------------------------------------------
__global__ __launch_bounds__(512) void k_scanA(
    const float* __restrict__ xc, const float* __restrict__ part,
    const float* __restrict__ dtw, const float* __restrict__ dtb,
    const float* __restrict__ A_log,
    float* __restrict__ hend, float* __restrict__ sumdt)
{
    int bx = blockIdx.x;
    int b = bx >> 5;
    int c = bx & 31;
    int d = threadIdx.x;

    float A2[DS], h[DS], wdt[DS];
#pragma unroll
    for (int s = 0; s < DS; s++) {
        A2[s] = -__expf(A_log[d * DS + s]) * LOG2E;
        h[s] = 0.f;
        wdt[s] = dtw[d * DS + s];
    }
    float dtbv = dtb[d];
    float A20 = A2[0];
    float A0nat = A20 * LN2;
    bool geo = true;
#pragma unroll
    for (int s = 0; s < DS; s++)
        geo = geo && (fabsf(A2[s] - (float)(s + 1) * A20) <=
                      1e-5f * fabsf(A2[s]) + 1e-30f);

    __shared__ float Bs[SCT][48];
    {
        const size_t st = (size_t)RC * 48;
        for (int f = threadIdx.x; f < SCT * 48; f += 512) {
            int tt = f / 48, jj = f - tt * 48;
            size_t base = ((size_t)(c * SCT + tt) * 32 + b) * 48 + jj;
            Bs[tt][jj] = (part[base] + part[st + base]) +
                         (part[2 * st + base] + part[3 * st + base]);
        }
    }
    __syncthreads();

    float cum = 0.f;
    if (geo) {
        for (int tt = 0; tt < SCT; tt++) {
            size_t idx = ((size_t)(c * SCT + tt) * 32 + b) * DI + d;
            float p0 = 0.f, p1 = 0.f, p2 = 0.f, p3 = 0.f;
#pragma unroll
            for (int k = 0; k < 4; k++) {
                p0 = fmaf(Bs[tt][k],      wdt[k],      p0);
                p1 = fmaf(Bs[tt][4 + k],  wdt[4 + k],  p1);
                p2 = fmaf(Bs[tt][8 + k],  wdt[8 + k],  p2);
                p3 = fmaf(Bs[tt][12 + k], wdt[12 + k], p3);
            }
            float s0 = dtbv + ((p0 + p1) + (p2 + p3));
            float u  = __expf(s0);
            float t2 = __log2f(1.f + u);
            if (s0 > 80.f) t2 = s0 * LOG2E;
            float dt = LN2 * t2;
            cum += dt;
            float dtx = dt * xc[idx];
            float q  = exp2f(t2 * A0nat);
            float q2 = q * q, q3 = q2 * q, q4 = q2 * q2;
            float pv[4] = { q, q2, q3, q4 };
            float r = 1.f;
#pragma unroll
            for (int g = 0; g < 4; g++) {
#pragma unroll
                for (int j = 0; j < 4; j++) {
                    int s = g * 4 + j;
                    float dA = r * pv[j];
                    h[s] = fmaf(dA, h[s], dtx * Bs[tt][16 + s]);
                }
                r *= q4;
            }
        }
    } else {
        for (int tt = 0; tt < SCT; tt++) {
            size_t idx = ((size_t)(c * SCT + tt) * 32 + b) * DI + d;
            float s0 = dtbv;
#pragma unroll
            for (int k = 0; k < DS; k++) s0 = fmaf(Bs[tt][k], wdt[k], s0);
            float dt = (s0 > 20.f) ? s0 : log1pf(expf(s0));
            cum += dt;
            float dtx = dt * xc[idx];
#pragma unroll
            for (int s = 0; s < DS; s++) {
                float dA = exp2f(dt * A2[s]);
                h[s] = fmaf(dA, h[s], dtx * Bs[tt][16 + s]);
            }
        }
    }
    float* hp = hend + ((size_t)(c * 32 + b) * 512 + d) * DS;
#pragma unroll
    for (int s = 0; s < DS; s++) hp[s] = h[s];
    sumdt[((size_t)c * 32 + b) * 512 + d] = cum;
}

// ---------------------------------------------------------------------------
// scan pass B: carry across 32 sub-chunks; hend -> h_init, carry -> hs.
// ---------------------------------------------------------------------------
__global__ __launch_bounds__(256) void k_scanB(
    const float* __restrict__ sumdt, float* __restrict__ hend,
    const float* __restrict__ A_log, float* __restrict__ hs, int first)
{
    int id = blockIdx.x * 256 + threadIdx.x;   // 32*512*16 = 262144
    int s = id & 15;
    int d = (id >> 4) & 511;
    int b = id >> 13;
    float A2 = -__expf(A_log[d * DS + s]) * LOG2E;
    size_t hsi = ((size_t)(b << 9) + d) * DS + s;
    float hin = first ? 0.f : hs[hsi];
    for (int c = 0; c < NSC; c++) {
        size_t hi = ((size_t)(c * 32 + b) * 512 + d) * DS + s;
        float he = hend[hi];
        float sd = sumdt[((size_t)c * 32 + b) * 512 + d];
        hend[hi] = hin;
        hin = fmaf(exp2f(A2 * sd), hin, he);
    }
    hs[hsi] = hin;
}

// ---------------------------------------------------------------------------
// scan pass C (fused dt-proj + partial-reduce, geometric-dA, fast softplus):
// 512-thread blocks (merged d-halves, single Bs staging).
// ACC=0: emit y as bf16 hi/lo planes. ACC=1: accumulate t-sum into macc2.
// grid 1024 blocks.
// ---------------------------------------------------------------------------
template <int ACC>
__global__ __launch_bounds__(512) void k_scanC(
    const float* __restrict__ xc, const float* __restrict__ part,
    const float* __restrict__ dtw, const float* __restrict__ dtb,
    const float* __restrict__ xz,
    const float* __restrict__ A_log, const float* __restrict__ Dp,
    const float* __restrict__ hinit,
    u16* __restrict__ yh, u16* __restrict__ yl,
    float* __restrict__ macc2, int first)
{
    int bx = blockIdx.x;
    int b = bx >> 5;
    int c = bx & 31;
    int d = threadIdx.x;

    float A2[DS], h[DS], wdt[DS];
    const float* hp = hinit + ((size_t)(c * 32 + b) * 512 + d) * DS;
#pragma unroll
    for (int s = 0; s < DS; s++) {
        A2[s] = -__expf(A_log[d * DS + s]) * LOG2E;
        h[s] = hp[s];
        wdt[s] = dtw[d * DS + s];
    }
    float dtbv = dtb[d];
    float Dv = Dp[d];
    float A20 = A2[0];
    float A0nat = A20 * LN2;
    bool geo = true;
#pragma unroll
    for (int s = 0; s < DS; s++)
        geo = geo && (fabsf(A2[s] - (float)(s + 1) * A20) <=
                      1e-5f * fabsf(A2[s]) + 1e-30f);

    __shared__ float BC[SCT][48];
    {
        const size_t st = (size_t)RC * 48;
        for (int f = threadIdx.x; f < SCT * 48; f += 512) {
            int tt = f / 48, jj = f - tt * 48;
            size_t base = ((size_t)(c * SCT + tt) * 32 + b) * 48 + jj;
            BC[tt][jj] = (part[base] + part[st + base]) +
                         (part[2 * st + base] + part[3 * st + base]);
        }
    }
    __syncthreads();

    float ysum = 0.f;
    if (geo) {
        for (int tt = 0; tt < SCT; tt++) {
            size_t row = (size_t)(c * SCT + tt) * 32 + b;
            size_t idx = row * DI + d;
            float p0 = 0.f, p1 = 0.f, p2 = 0.f, p3 = 0.f;
#pragma unroll
            for (int k = 0; k < 4; k++) {
                p0 = fmaf(BC[tt][k],      wdt[k],      p0);
                p1 = fmaf(BC[tt][4 + k],  wdt[4 + k],  p1);
                p2 = fmaf(BC[tt][8 + k],  wdt[8 + k],  p2);
                p3 = fmaf(BC[tt][12 + k], wdt[12 + k], p3);
            }
            float s0 = dtbv + ((p0 + p1) + (p2 + p3));
            float u  = __expf(s0);
            float t2 = __log2f(1.f + u);
            if (s0 > 80.f) t2 = s0 * LOG2E;
            float dt = LN2 * t2;
            float x  = xc[idx];
            float z  = xz[(row << 10) + 512 + d];
            float dtx = dt * x;
            float y = 0.f;
            float q  = exp2f(t2 * A0nat);
            float q2 = q * q, q3 = q2 * q, q4 = q2 * q2;
            float pv[4] = { q, q2, q3, q4 };
            float r = 1.f;
#pragma unroll
            for (int g = 0; g < 4; g++) {
#pragma unroll
                for (int j = 0; j < 4; j++) {
                    int s = g * 4 + j;
                    float dA = r * pv[j];
                    h[s] = fmaf(dA, h[s], dtx * BC[tt][16 + s]);
                    y = fmaf(h[s], BC[tt][32 + s], y);
                }
                r *= q4;
            }
            float yact = (y + x * Dv) * (z / (1.f + __expf(-z)));
            if (ACC) {
                ysum += yact;
            } else {
                unsigned hb = f2bf_u(yact);
                yh[row * DI + d] = (u16)hb;
                yl[row * DI + d] = (u16)f2bf_u(yact - __uint_as_float(hb << 16));
            }
        }
    } else {
        for (int tt = 0; tt < SCT; tt++) {
            size_t row = (size_t)(c * SCT + tt) * 32 + b;
            size_t idx = row * DI + d;
            float s0 = dtbv;
#pragma unroll
            for (int k = 0; k < DS; k++) s0 = fmaf(BC[tt][k], wdt[k], s0);
            float dt = (s0 > 20.f) ? s0 : log1pf(expf(s0));
            float x  = xc[idx];
            float z  = xz[(row << 10) + 512 + d];
            float dtx = dt * x;
            float y = 0.f;
#pragma unroll
            for (int s = 0; s < DS; s++) {
                float dA = exp2f(dt * A2[s]);
                h[s] = fmaf(dA, h[s], dtx * BC[tt][16 + s]);
                y = fmaf(h[s], BC[tt][32 + s], y);
            }
            float yact = (y + x * Dv) * (z / (1.f + __expf(-z)));
            if (ACC) {
                ysum += yact;
            } else {
                unsigned hb = f2bf_u(yact);
                yh[row * DI + d] = (u16)hb;
                yl[row * DI + d] = (u16)f2bf_u(yact - __uint_as_float(hb << 16));
            }
        }
    }

    if (ACC) {
        size_t mi = ((size_t)(b * NSC + c) * 512) + d;
        if (first) macc2[mi] = ysum;
        else       macc2[mi] += ysum;
    }
}

// ---------------------------------------------------------------------------
// prehead: mm[b][n] = (1/1024) * sum_q Wo2[n][q] * (sum_c macc2[b][c][q])
// ---------------------------------------------------------------------------
__global__ __launch_bounds__(256) void k_prehead(
    const float* __restrict__ macc2, const float* __restrict__ wo2,
    float* __restrict__ mm)
{
    int b = blockIdx.x;
    int n = threadIdx.x;
    __shared__ float ys[512];
    for (int q = threadIdx.x; q < 512; q += 256) {
        float s = 0.f;
        for (int c = 0; c < NSC; c++)
            s += macc2[((size_t)(b * NSC + c) * 512) + q];
        ys[q] = s;
    }
    __syncthreads();
    const float* wr = wo2 + (size_t)n * 512;
    float s = 0.f;
    for (int q = 0; q < 512; q += 4) {
        float4 w = *(const float4*)(wr + q);
        s = fmaf(w.x, ys[q + 0], s);
        s = fmaf(w.y, ys[q + 1], s);
        s = fmaf(w.z, ys[q + 2], s);
        s = fmaf(w.w, ys[q + 3], s);
    }
    mm[b * 256 + n] = s * (1.f / 1024.f);
}

__global__ __launch_bounds__(128) void k_head(
    const float* __restrict__ mm, const float* __restrict__ xst,
    const float* __restrict__ h1w, const float* __restrict__ h1b,
    const float* __restrict__ h2w, const float* __restrict__ h2b,
    float* __restrict__ out)
{
    int b = blockIdx.x;
    int j = threadIdx.x;
    const float* wr = h1w + j * 261;
    const float* mr = mm + b * 256;
    float s = h1b[j];
    for (int k = 0; k < 256; k++) s = fmaf(mr[k], wr[k], s);
    for (int k = 0; k < 5; k++) s = fmaf(xst[b * 5 + k], wr[256 + k], s);
    float e = (s > 0.f) ? s : expm1f(s);

    __shared__ float sb[128];
    sb[j] = e * h2w[j];
    __syncthreads();
    for (int o = 64; o > 0; o >>= 1) {
        if (j < o) sb[j] += sb[j + o];
        __syncthreads();
    }
    if (j == 0) out[b] = sb[0] + h2b[0];
}

// ---------------------------------------------------------------------------
// host side
// ---------------------------------------------------------------------------
static void run_mamba_core(hipStream_t stream,
                           const u16* x1h, const u16* x1l, void* const* P,
                           const u16* wih, const u16* wil,
                           float* xzc, float* xcc, float* xpartb,
                           u16* yh, u16* yl,
                           float* hendb, float* sumdtb, float* halo,
                           float* hstate, float* macc2, int acc,
                           int t0, int save_halo)
{
    const float* cw     = (const float*)P[1];
    const float* cb     = (const float*)P[2];
    const float* xpw    = (const float*)P[3];
    const float* dtw    = (const float*)P[4];
    const float* dtbias = (const float*)P[5];
    const float* Alog   = (const float*)P[6];
    const float* Dp     = (const float*)P[7];
    int first = (t0 == 0);

    k_gmfma<false><<<dim3(RC / 128, 1024 / 128), 256, 0, stream>>>(
        x1h, x1l, 256, wih, wil, nullptr, xzc, 1024, 256);
    k_conv<<<RC * DI / 1024, 256, 0, stream>>>(xzc, halo, cw, cb, xcc, t0, save_halo);
    k_xpart<<<dim3(RC / 64, 4), 256, 0, stream>>>(xcc, xpw, xpartb, RC, 512, 128);
    k_scanA<<<32 * NSC, 512, 0, stream>>>(xcc, xpartb, dtw, dtbias, Alog,
                                          hendb, sumdtb);
    k_scanB<<<32 * 512 * DS / 256, 256, 0, stream>>>(sumdtb, hendb, Alog, hstate, first);
    if (acc)
        k_scanC<1><<<32 * NSC, 512, 0, stream>>>(
            xcc, xpartb, dtw, dtbias, xzc, Alog, Dp, hendb,
            nullptr, nullptr, macc2, first);
    else
        k_scanC<0><<<32 * NSC, 512, 0, stream>>>(
            xcc, xpartb, dtw, dtbias, xzc, Alog, Dp, hendb,
            yh, yl, nullptr, 0);
}

extern "C" void kernel_launch(void* const* d_in, const int* in_sizes, int n_in,
                              void* d_out, int out_size, void* d_ws, size_t ws_size,
                              hipStream_t stream)
{
    const float* xseq = (const float*)d_in[0];
    const float* xst  = (const float*)d_in[1];
    const float* p1w  = (const float*)d_in[2];
    const float* p1b  = (const float*)d_in[3];
    const float* ln1g = (const float*)d_in[4];
    const float* ln1b = (const float*)d_in[5];
    const float* p2w  = (const float*)d_in[6];
    const float* p2b  = (const float*)d_in[7];
    const float* ln2g = (const float*)d_in[8];
    const float* ln2b = (const float*)d_in[9];
    const float* h1w  = (const float*)d_in[10];
    const float* h1b  = (const float*)d_in[11];
    const float* h2w  = (const float*)d_in[12];
    const float* h2b  = (const float*)d_in[13];
    const float* wo1  = (const float*)d_in[22];   // m1 out_w [256,512]
    const float* wo2  = (const float*)d_in[31];   // m2 out_w [256,512]

    float* ws = (float*)d_ws;
    float* xzc    = ws;                                  // RC*1024 f32
    float* xcc    = xzc  + (size_t)RC * 1024;            // RC*512
    // hend region: RC*512 floats; x1 planes (dead during scans) alias its head
    float* hendb  = xcc  + (size_t)RC * 512;
    u16*   x1h    = (u16*)hendb;                         // RC*256 u16
    u16*   x1l    = x1h + (size_t)RC * 256;              // RC*256 u16
    u16*   yh     = (u16*)(hendb + (size_t)RC * 512);    // RC*512 u16
    u16*   yl     = yh + (size_t)RC * 512;               // RC*512 u16
    float* sumdtb = (float*)(yl + (size_t)RC * 512);     // NSC*32*512
    float* halo1  = sumdtb + NSC * 32 * 512;             // 3*32*512
    float* halo2  = halo1 + 3 * 32 * 512;
    float* hs1    = halo2 + 3 * 32 * 512;                // 32*512*16
    float* hs2    = hs1  + 32 * 512 * DS;
    float* macc2  = hs2  + 32 * 512 * DS;                // 32*NSC*512 (2 MB)
    float* mm     = macc2 + 32 * NSC * 512;              // 32*256
    u16*   wm1ih  = (u16*)(mm + 32 * 256);               // 1024*256 u16 each
    u16*   wm1il  = wm1ih + 262144;
    u16*   wm2ih  = wm1il + 262144;
    u16*   wm2il  = wm2ih + 262144;
    u16*   wch    = wm2il + 262144;                      // 256*512 u16 each
    u16*   wcl    = wch + 131072;
    float* xpartb = (float*)(wcl + 131072);              // 4*RC*48 f32
    size_t need = (size_t)((char*)(xpartb + 4 * (size_t)RC * 48) - (char*)ws);
    if (ws_size < need) return;   // tripwire: fail cleanly, don't fault

    // weight prep (2 launches total)
    k_wcvt2<<<2048, 256, 0, stream>>>(
        (const float*)d_in[14], (const float*)d_in[23],
        wm1ih, wm1il, wm2ih, wm2il);
    k_wcomb<<<512, 256, 0, stream>>>(p2w, wo1, wch, wcl);

    for (int c = 0; c < NCH; c++) {
        int t0 = c * CH;
        int save_halo = (c != NCH - 1);

        k_p1_ln<<<RC, 256, 0, stream>>>(xseq, p1w, p1b, ln1g, ln1b, x1h, x1l, t0);

        // mamba 1 core (params d_in[14..22]) -> y planes
        run_mamba_core(stream, x1h, x1l, d_in + 14, wm1ih, wm1il,
                       xzc, xcc, xpartb, yh, yl,
                       hendb, sumdtb, halo1, hs1, nullptr, 0, t0, save_halo);

        // fused out_proj1+p2 (y @ Wc^T + p2b) -> LN2
        k_gmfma<true><<<dim3(RC / 128, 256 / 128), 256, 0, stream>>>(
            yh, yl, 512, wch, wcl, p2b, xzc, 256, 512);
        k_ln<<<RC, 256, 0, stream>>>(xzc, ln2g, ln2b, x1h, x1l);

        // mamba 2 core (params d_in[23..31]); y accumulated into macc2,
        // out_proj folded into prehead
        run_mamba_core(stream, x1h, x1l, d_in + 23, wm2ih, wm2il,
                       xzc, xcc, xpartb, yh, yl,
                       hendb, sumdtb, halo2, hs2, macc2, 1, t0, save_halo);
    }

    k_prehead<<<NB, 256, 0, stream>>>(macc2, wo2, mm);
    k_head<<<NB, 128, 0, stream>>>(mm, xst, h1w, h1b, h2w, h2b, (float*)d_out);
}